// Round 2
// baseline (8712.421 us; speedup 1.0000x reference)
//
#include <hip/hip_runtime.h>
#include <cstdint>

// Problem constants
#define BB 128   // batch
#define TT 256   // decode steps / T_CHAR
#define EE 512   // embed
#define NC 128   // n_chars
#define STAG 32  // T_TAG

using bf = unsigned short;  // bf16 storage

static __device__ __forceinline__ float bf_lo(uint32_t u) { return __uint_as_float(u << 16); }
static __device__ __forceinline__ float bf_hi(uint32_t u) { return __uint_as_float(u & 0xFFFF0000u); }
static __device__ __forceinline__ float bfu(bf x) { return __uint_as_float(((uint32_t)x) << 16); }
static __device__ __forceinline__ uint32_t f2bf(float f) {
    uint32_t u = __float_as_uint(f);
    return (u + 0x7FFFu + ((u >> 16) & 1u)) >> 16;  // RNE
}
static __device__ __forceinline__ float sigmoidf_(float x) { return 1.f / (1.f + expf(-x)); }

static __device__ __forceinline__ void bf8exp(const uint4 u, float* f) {
    f[0] = bf_lo(u.x); f[1] = bf_hi(u.x); f[2] = bf_lo(u.y); f[3] = bf_hi(u.y);
    f[4] = bf_lo(u.z); f[5] = bf_hi(u.z); f[6] = bf_lo(u.w); f[7] = bf_hi(u.w);
}

// typed load/store helpers (fp32 math, bf16-at-rest)
static __device__ __forceinline__ float4 ld4f(const float* p) { return *(const float4*)p; }
static __device__ __forceinline__ float4 ld4f(const bf* p) {
    ushort4 u = *(const ushort4*)p;
    return make_float4(bfu(u.x), bfu(u.y), bfu(u.z), bfu(u.w));
}
static __device__ __forceinline__ float ld1f(const float* p) { return *p; }
static __device__ __forceinline__ float ld1f(const bf* p) { return bfu(*p); }
static __device__ __forceinline__ void st1f(float* p, float v) { *p = v; }
static __device__ __forceinline__ void st1f(bf* p, float v) { *p = (bf)f2bf(v); }

// ---------------------------------------------------------------------------
// diagnostic: if workspace is too small, make absmax ~= ws_size in MiB
// ---------------------------------------------------------------------------
__global__ void diag_ws(float* __restrict__ out, float v, int n) {
    int i = blockIdx.x * 256 + threadIdx.x;
    if (i < n) out[i] = v;
}

// ---------------------------------------------------------------------------
// Weight prep for the sequential LSTM.
// WihQ[k][j] = float4{Wih[j][k], Wih[512+j][k], Wih[1024+j][k], Wih[1536+j][k]}
// WhhQ[k2][j] = uint4: gate g word = bf16pair(Whh[g*512+j][2k2], Whh[g*512+j][2k2+1])
// ---------------------------------------------------------------------------
__global__ void prep_wih(const float* __restrict__ Wih, float4* __restrict__ WihQ) {
    int idx = blockIdx.x * 256 + threadIdx.x;           // 128*512
    if (idx >= 128 * 512) return;
    int k = idx >> 9, j = idx & 511;
    WihQ[idx] = make_float4(Wih[(size_t)j * 128 + k],
                            Wih[(size_t)(512 + j) * 128 + k],
                            Wih[(size_t)(1024 + j) * 128 + k],
                            Wih[(size_t)(1536 + j) * 128 + k]);
}

__global__ void prep_whh(const float* __restrict__ Whh, uint4* __restrict__ WhhQ) {
    int idx = blockIdx.x * 256 + threadIdx.x;           // 256*512
    if (idx >= 256 * 512) return;
    int k2 = idx >> 9, j = idx & 511;
    uint32_t w[4];
#pragma unroll
    for (int g = 0; g < 4; ++g) {
        size_t row = (size_t)(g * 512 + j) * 512;
        uint32_t lo = f2bf(Whh[row + 2 * k2]);
        uint32_t hi = f2bf(Whh[row + 2 * k2 + 1]);
        w[g] = (hi << 16) | lo;
    }
    WhhQ[idx] = make_uint4(w[0], w[1], w[2], w[3]);
}

// ---------------------------------------------------------------------------
// Sequential LSTM: one workgroup per batch row b; h in LDS, c in registers.
// H[t][b][e] stored bf16. x@Wih^T exploited as sparse (x is one-hot).
// ---------------------------------------------------------------------------
__global__ __launch_bounds__(512) void lstm_seq(
    const float* __restrict__ hn,     // [2][BB][256]
    const float* __restrict__ cn,     // [2][BB][256]
    const float* __restrict__ tos,    // [BB][TT][NC]
    const float4* __restrict__ WihQ,  // [128][512]
    const uint4* __restrict__ WhhQ,   // [256][512]
    const float* __restrict__ bih, const float* __restrict__ bhh,
    bf* __restrict__ H)               // [TT][BB][EE] bf16
{
    int b = blockIdx.x;
    int j = threadIdx.x;              // 0..511 — owns h column j
    __shared__ __align__(16) float hs[EE];
    __shared__ float xs[NC];

    float hv = (j < 256) ? hn[(size_t)b * 256 + j] : hn[(size_t)(BB + b) * 256 + (j - 256)];
    float cv = (j < 256) ? cn[(size_t)b * 256 + j] : cn[(size_t)(BB + b) * 256 + (j - 256)];
    hs[j] = hv;
    const float bi0 = bih[j] + bhh[j];
    const float bi1 = bih[512 + j] + bhh[512 + j];
    const float bi2 = bih[1024 + j] + bhh[1024 + j];
    const float bi3 = bih[1536 + j] + bhh[1536 + j];
    __syncthreads();

    for (int t = 0; t < TT; ++t) {
        if (j < NC) xs[j] = (t == 0) ? 0.f : tos[((size_t)b * TT + t) * NC + j];
        __syncthreads();   // x ready; previous-step h visible

        float a0 = bi0, a1 = bi1, a2 = bi2, a3 = bi3;

        // input contribution (x one-hot: wave-uniform sparse loop)
        for (int k = 0; k < NC; ++k) {
            float xv = xs[k];
            if (xv != 0.f) {
                float4 w = WihQ[(size_t)k * 512 + j];
                a0 += xv * w.x; a1 += xv * w.y; a2 += xv * w.z; a3 += xv * w.w;
            }
        }
        // recurrent contribution, bf16 weights packed over k-pairs
        const float2* h2 = (const float2*)hs;
#pragma unroll 4
        for (int k2 = 0; k2 < 256; ++k2) {
            float2 hh = h2[k2];
            uint4 w = WhhQ[(size_t)k2 * 512 + j];
            a0 += hh.x * bf_lo(w.x) + hh.y * bf_hi(w.x);
            a1 += hh.x * bf_lo(w.y) + hh.y * bf_hi(w.y);
            a2 += hh.x * bf_lo(w.z) + hh.y * bf_hi(w.z);
            a3 += hh.x * bf_lo(w.w) + hh.y * bf_hi(w.w);
        }

        float ig = sigmoidf_(a0);
        float fg = sigmoidf_(a1);
        float gg = tanhf(a2);
        float og = sigmoidf_(a3);
        cv = fg * cv + ig * gg;
        float hnew = og * tanhf(cv);

        __syncthreads();   // everyone finished reading hs
        hs[j] = hnew;
        H[((size_t)t * BB + b) * EE + j] = (bf)f2bf(hnew);
    }
}

// ---------------------------------------------------------------------------
// Generic GEMM: C = alpha*(A @ W^T + bias). A: AT (fp32 or bf16), W fp32,
// C: CT. Optional relu-on-A-load, accumulate-into-C, (t,b)->(b,t) row remap.
// ---------------------------------------------------------------------------
#define GBM 64
#define GBN 64
#define GBK 16
#define GF_RELU_A   2
#define GF_ACCUM    4

template <typename AT, typename CT>
__global__ __launch_bounds__(256) void gemm_bias(
    const AT* __restrict__ A, const float* __restrict__ W,
    const float* __restrict__ bias, CT* __restrict__ C,
    int M, int N, int K, int lda, int ldw, int wcol, int ldc, int ccol,
    float alpha, int flags, int remapT, int remapB)
{
    __shared__ __align__(16) float As[GBK][GBM + 4];
    __shared__ __align__(16) float Bs[GBK][GBN + 4];
    int bm = blockIdx.y * GBM;
    int bn = blockIdx.x * GBN;
    int tid = threadIdx.x;
    int tx = tid & 15, ty = tid >> 4;
    int lr = tid >> 2;            // 0..63
    int lk = (tid & 3) << 2;      // 0,4,8,12
    float acc[4][4] = {};

    for (int k0 = 0; k0 < K; k0 += GBK) {
        {
            int row = bm + lr;
            float4 v = make_float4(0.f, 0.f, 0.f, 0.f);
            if (row < M) v = ld4f(A + (size_t)row * lda + k0 + lk);
            if (flags & GF_RELU_A) {
                v.x = fmaxf(v.x, 0.f); v.y = fmaxf(v.y, 0.f);
                v.z = fmaxf(v.z, 0.f); v.w = fmaxf(v.w, 0.f);
            }
            As[lk + 0][lr] = v.x; As[lk + 1][lr] = v.y;
            As[lk + 2][lr] = v.z; As[lk + 3][lr] = v.w;
        }
        {
            int n = bn + lr;
            float4 v = make_float4(0.f, 0.f, 0.f, 0.f);
            if (n < N) v = *(const float4*)(W + (size_t)n * ldw + wcol + k0 + lk);
            Bs[lk + 0][lr] = v.x; Bs[lk + 1][lr] = v.y;
            Bs[lk + 2][lr] = v.z; Bs[lk + 3][lr] = v.w;
        }
        __syncthreads();
#pragma unroll
        for (int kk = 0; kk < GBK; ++kk) {
            float a[4], bvv[4];
#pragma unroll
            for (int i = 0; i < 4; ++i) a[i] = As[kk][ty * 4 + i];
#pragma unroll
            for (int jj = 0; jj < 4; ++jj) bvv[jj] = Bs[kk][tx * 4 + jj];
#pragma unroll
            for (int i = 0; i < 4; ++i)
#pragma unroll
                for (int jj = 0; jj < 4; ++jj) acc[i][jj] += a[i] * bvv[jj];
        }
        __syncthreads();
    }

#pragma unroll
    for (int i = 0; i < 4; ++i) {
        int r = bm + ty * 4 + i;
        if (r >= M) continue;
        size_t orow;
        if (remapT > 0) { int t = r / remapB, bb_ = r % remapB; orow = (size_t)bb_ * remapT + t; }
        else orow = (size_t)r;
#pragma unroll
        for (int jj = 0; jj < 4; ++jj) {
            int n = bn + tx * 4 + jj;
            if (n >= N) continue;
            float bv = bias ? bias[n] : 0.f;
            float v = (acc[i][jj] + bv) * alpha;
            CT* cp = C + orow * ldc + ccol + n;
            if (flags & GF_ACCUM) v += ld1f(cp);
            st1f(cp, v);
        }
    }
}

// ---------------------------------------------------------------------------
// Fused attention (bf16 Q/K/V/ctx, fp32 math): per (b, 16-step tile):
// scores = q @ K^T, softmax, ctx = p @ V. ctx aliases Q (tile read first).
// ---------------------------------------------------------------------------
template <int S>
__global__ __launch_bounds__(256) void attn_kernel(
    const bf* __restrict__ Q,    // [TT*BB][EE], pre-scaled by 1/sqrt(E)
    const bf* __restrict__ Km,   // [BB][S][EE]
    const bf* __restrict__ Vm,   // [BB][S][EE]
    bf* __restrict__ ctx)        // [TT*BB][EE]
{
    constexpr int RT = 16;  // t-tile
    int t0 = blockIdx.x * RT;
    int b = blockIdx.y;
    int tid = threadIdx.x;

    __shared__ __align__(16) float qs[RT][EE];   // 32 KB
    __shared__ float ps[RT][S];
    __shared__ float red[RT][17];
    __shared__ float rowsum[RT];

    // load Q tile: RT*EE bf16 = 1024 uint4 loads over 256 threads
#pragma unroll
    for (int i = 0; i < RT * EE / (256 * 8); ++i) {
        int x = (i * 256 + tid) * 8;
        int r = x / EE, e = x % EE;
        uint4 u = *(const uint4*)&Q[((size_t)(t0 + r) * BB + b) * EE + e];
        float f[8]; bf8exp(u, f);
#pragma unroll
        for (int q = 0; q < 8; ++q) qs[r][e + q] = f[q];
    }
    __syncthreads();

    // scores
    if constexpr (S >= 256) {
        int s = tid;
        float acc[RT] = {};
        const uint4* kp = (const uint4*)&Km[((size_t)b * S + s) * EE];
        for (int e8 = 0; e8 < EE / 8; ++e8) {
            float kf[8]; bf8exp(kp[e8], kf);
#pragma unroll
            for (int r = 0; r < RT; ++r) {
                float a = 0.f;
#pragma unroll
                for (int q = 0; q < 8; ++q) a += qs[r][e8 * 8 + q] * kf[q];
                acc[r] += a;
            }
        }
#pragma unroll
        for (int r = 0; r < RT; ++r) ps[r][s] = acc[r];
    } else {
        constexpr int KS = 256 / S;      // k-split ways (8 for S=32)
        constexpr int EC = EE / KS;      // 64
        __shared__ float pp[KS][RT][S];  // 16 KB
        int s = tid & (S - 1);
        int kq = tid / S;
        float acc[RT] = {};
        const uint4* kp = (const uint4*)&Km[((size_t)b * S + s) * EE + kq * EC];
        for (int e8 = 0; e8 < EC / 8; ++e8) {
            float kf[8]; bf8exp(kp[e8], kf);
#pragma unroll
            for (int r = 0; r < RT; ++r) {
                float a = 0.f;
#pragma unroll
                for (int q = 0; q < 8; ++q) a += qs[r][kq * EC + e8 * 8 + q] * kf[q];
                acc[r] += a;
            }
        }
#pragma unroll
        for (int r = 0; r < RT; ++r) pp[kq][r][s] = acc[r];
        __syncthreads();
        for (int x = tid; x < RT * S; x += 256) {
            int r = x / S, ss = x % S;
            float v = 0.f;
#pragma unroll
            for (int q = 0; q < KS; ++q) v += pp[q][r][ss];
            ps[r][ss] = v;
        }
    }
    __syncthreads();

    // softmax (16 threads per row)
    {
        int r = tid >> 4, l = tid & 15;
        float m = -1e30f;
        for (int s = l; s < S; s += 16) m = fmaxf(m, ps[r][s]);
        red[r][l] = m;
        __syncthreads();
        for (int w = 8; w >= 1; w >>= 1) {
            if (l < w) red[r][l] = fmaxf(red[r][l], red[r][l + w]);
            __syncthreads();
        }
        float mm = red[r][0];
        float sum = 0.f;
        for (int s = l; s < S; s += 16) {
            float e = expf(ps[r][s] - mm);
            ps[r][s] = e;
            sum += e;
        }
        __syncthreads();
        red[r][l] = sum;
        __syncthreads();
        for (int w = 8; w >= 1; w >>= 1) {
            if (l < w) red[r][l] += red[r][l + w];
            __syncthreads();
        }
        if (l == 0) rowsum[r] = red[r][0];
    }
    __syncthreads();

    // ctx = (p @ V) / rowsum ; thread owns columns tid and tid+256
    {
        float acc0[RT] = {}, acc1[RT] = {};
        for (int s = 0; s < S; ++s) {
            float v0 = bfu(Vm[((size_t)b * S + s) * EE + tid]);
            float v1 = bfu(Vm[((size_t)b * S + s) * EE + tid + 256]);
#pragma unroll
            for (int r = 0; r < RT; ++r) {
                float p = ps[r][s];
                acc0[r] += p * v0;
                acc1[r] += p * v1;
            }
        }
#pragma unroll
        for (int r = 0; r < RT; ++r) {
            float inv = 1.f / rowsum[r];
            size_t row = (size_t)(t0 + r) * BB + b;
            ctx[row * EE + tid] = (bf)f2bf(acc0[r] * inv);
            ctx[row * EE + tid + 256] = (bf)f2bf(acc1[r] * inv);
        }
    }
}

// ---------------------------------------------------------------------------
extern "C" void kernel_launch(void* const* d_in, const int* in_sizes, int n_in,
                              void* d_out, int out_size, void* d_ws, size_t ws_size,
                              hipStream_t stream) {
    const float* char_enc = (const float*)d_in[0];
    const float* char_hn  = (const float*)d_in[1];
    const float* char_cn  = (const float*)d_in[2];
    const float* tag_enc  = (const float*)d_in[3];
    const float* tos      = (const float*)d_in[4];
    const float* Wih = (const float*)d_in[5];
    const float* Whh = (const float*)d_in[6];
    const float* bih = (const float*)d_in[7];
    const float* bhh = (const float*)d_in[8];
    const float* caWq = (const float*)d_in[9],  *caWk = (const float*)d_in[10], *caWv = (const float*)d_in[11];
    const float* cabq = (const float*)d_in[12], *cabk = (const float*)d_in[13], *cabv = (const float*)d_in[14];
    const float* caWo = (const float*)d_in[15], *cabo = (const float*)d_in[16];
    const float* taWq = (const float*)d_in[17], *taWk = (const float*)d_in[18], *taWv = (const float*)d_in[19];
    const float* tabq = (const float*)d_in[20], *tabk = (const float*)d_in[21], *tabv = (const float*)d_in[22];
    const float* taWo = (const float*)d_in[23], *tabo = (const float*)d_in[24];
    const float* outW = (const float*)d_in[25], *outb = (const float*)d_in[26];
    float* out = (float*)d_out;

    const size_t SZ  = (size_t)TT * BB * EE;       // 16,777,216 elements
    const size_t SZT = (size_t)BB * STAG * EE;     //  2,097,152 elements
    const size_t NEED = 5 * SZ * 2 + 2 * SZT * 2 + 128 * 512 * 16 + 256 * 512 * 16;

    if (ws_size < NEED) {
        // diagnostic: absmax will read ~= ws_size in MiB
        diag_ws<<<dim3((out_size + 255) / 256), dim3(256), 0, stream>>>(
            out, (float)((double)ws_size / 1048576.0), out_size);
        return;
    }

    char* w = (char*)d_ws;
    bf* Hh = (bf*)w;  w += SZ * 2;
    bf* Qc = (bf*)w;  w += SZ * 2;   // becomes ctx_c (in place)
    bf* Qt = (bf*)w;  w += SZ * 2;   // becomes ctx_t (in place)
    bf* Kc = (bf*)w;  w += SZ * 2;   // after attn_c: reused for occ
    bf* Vc = (bf*)w;  w += SZ * 2;   // after attn_c: reused for oct
    bf* Kt = (bf*)w;  w += SZT * 2;
    bf* Vt = (bf*)w;  w += SZT * 2;
    float4* WihQ = (float4*)w;  w += 128 * 512 * 16;
    uint4*  WhhQ = (uint4*)w;   w += 256 * 512 * 16;

    const float QSCALE = 0.044194173824159216f;  // 1/sqrt(512)
    const int M = TT * BB;                        // 32768

    prep_wih<<<dim3(128 * 512 / 256), dim3(256), 0, stream>>>(Wih, WihQ);
    prep_whh<<<dim3(256 * 512 / 256), dim3(256), 0, stream>>>(Whh, WhhQ);

    // K/V projections (step-invariant), fp32 A -> bf16 C
    gemm_bias<float, bf><<<dim3(8, 512), dim3(256), 0, stream>>>(char_enc, caWk, cabk, Kc,
        M, EE, EE, EE, EE, 0, EE, 0, 1.f, 0, 0, 0);
    gemm_bias<float, bf><<<dim3(8, 512), dim3(256), 0, stream>>>(char_enc, caWv, cabv, Vc,
        M, EE, EE, EE, EE, 0, EE, 0, 1.f, 0, 0, 0);
    gemm_bias<float, bf><<<dim3(8, 64), dim3(256), 0, stream>>>(tag_enc, taWk, tabk, Kt,
        BB * STAG, EE, EE, EE, EE, 0, EE, 0, 1.f, 0, 0, 0);
    gemm_bias<float, bf><<<dim3(8, 64), dim3(256), 0, stream>>>(tag_enc, taWv, tabv, Vt,
        BB * STAG, EE, EE, EE, EE, 0, EE, 0, 1.f, 0, 0, 0);

    // sequential LSTM -> H[t][b][e] (bf16)
    lstm_seq<<<dim3(BB), dim3(512), 0, stream>>>(char_hn, char_cn, tos, WihQ, WhhQ, bih, bhh, Hh);

    // Q projections (scaled), bf16 A -> bf16 C
    gemm_bias<bf, bf><<<dim3(8, 512), dim3(256), 0, stream>>>(Hh, caWq, cabq, Qc,
        M, EE, EE, EE, EE, 0, EE, 0, QSCALE, 0, 0, 0);
    gemm_bias<bf, bf><<<dim3(8, 512), dim3(256), 0, stream>>>(Hh, taWq, tabq, Qt,
        M, EE, EE, EE, EE, 0, EE, 0, QSCALE, 0, 0, 0);

    // fused attention (ctx aliases Q)
    attn_kernel<256><<<dim3(TT / 16, BB), dim3(256), 0, stream>>>(Qc, Kc, Vc, Qc);
    attn_kernel<32><<<dim3(TT / 16, BB), dim3(256), 0, stream>>>(Qt, Kt, Vt, Qt);

    // Wo projections: occ -> Kc buffer, oct -> Vc buffer (both dead after attn)
    gemm_bias<bf, bf><<<dim3(8, 512), dim3(256), 0, stream>>>(Qc, caWo, cabo, Kc,
        M, EE, EE, EE, EE, 0, EE, 0, 1.f, 0, 0, 0);
    gemm_bias<bf, bf><<<dim3(8, 512), dim3(256), 0, stream>>>(Qt, taWo, tabo, Vc,
        M, EE, EE, EE, EE, 0, EE, 0, 1.f, 0, 0, 0);

    // out = relu(occ) @ outW[:, :512]^T + outb  (+ relu(oct) @ outW[:, 512:]^T),
    // rows remapped (t,b) -> (b,t)
    gemm_bias<bf, float><<<dim3(2, 512), dim3(256), 0, stream>>>(Kc, outW, outb, out,
        M, NC, EE, EE, 2 * EE, 0, NC, 0, 1.f, GF_RELU_A, TT, BB);
    gemm_bias<bf, float><<<dim3(2, 512), dim3(256), 0, stream>>>(Vc, outW, nullptr, out,
        M, NC, EE, EE, 2 * EE, EE, NC, 0, 1.f, GF_RELU_A | GF_ACCUM, TT, BB);
}

// Round 3
// 6997.611 us; speedup vs baseline: 1.2451x; 1.2451x over previous
//
#include <hip/hip_runtime.h>
#include <cstdint>

// Problem constants
#define BB 128   // batch
#define TT 256   // decode steps / T_CHAR
#define EE 512   // embed
#define NC 128   // n_chars
#define STAG 32  // T_TAG

// LSTM persistent-kernel geometry
#define NWG 64   // workgroups (<< 256 CUs -> co-residency guaranteed)
#define JC 8     // h-columns per WG
#define NCOL 32  // gate-columns per WG = 4*JC

using bf = unsigned short;  // bf16 storage
typedef __attribute__((ext_vector_type(8))) short short8;
typedef __attribute__((ext_vector_type(8))) unsigned short ushort8;
typedef __attribute__((ext_vector_type(16))) float f32x16;

static __device__ __forceinline__ float bf_lo(uint32_t u) { return __uint_as_float(u << 16); }
static __device__ __forceinline__ float bf_hi(uint32_t u) { return __uint_as_float(u & 0xFFFF0000u); }
static __device__ __forceinline__ float bfu(bf x) { return __uint_as_float(((uint32_t)x) << 16); }
static __device__ __forceinline__ uint32_t f2bf(float f) {
    uint32_t u = __float_as_uint(f);
    return (u + 0x7FFFu + ((u >> 16) & 1u)) >> 16;  // RNE
}
static __device__ __forceinline__ float sigmoidf_(float x) { return 1.f / (1.f + expf(-x)); }

static __device__ __forceinline__ void bf8exp(const uint4 u, float* f) {
    f[0] = bf_lo(u.x); f[1] = bf_hi(u.x); f[2] = bf_lo(u.y); f[3] = bf_hi(u.y);
    f[4] = bf_lo(u.z); f[5] = bf_hi(u.z); f[6] = bf_lo(u.w); f[7] = bf_hi(u.w);
}

// typed load/store helpers (fp32 math, bf16-at-rest)
static __device__ __forceinline__ float4 ld4f(const float* p) { return *(const float4*)p; }
static __device__ __forceinline__ float4 ld4f(const bf* p) {
    ushort4 u = *(const ushort4*)p;
    return make_float4(bfu(u.x), bfu(u.y), bfu(u.z), bfu(u.w));
}
static __device__ __forceinline__ float ld1f(const float* p) { return *p; }
static __device__ __forceinline__ float ld1f(const bf* p) { return bfu(*p); }
static __device__ __forceinline__ void st1f(float* p, float v) { *p = v; }
static __device__ __forceinline__ void st1f(bf* p, float v) { *p = (bf)f2bf(v); }

// ---------------------------------------------------------------------------
// diagnostic: if workspace is too small, make absmax ~= ws_size in MiB
// ---------------------------------------------------------------------------
__global__ void diag_ws(float* __restrict__ out, float v, int n) {
    int i = blockIdx.x * 256 + threadIdx.x;
    if (i < n) out[i] = v;
}

// ---------------------------------------------------------------------------
// Prep kernels for the persistent LSTM
// ---------------------------------------------------------------------------
// h0 -> Hext[0][b][e] (bf16)
__global__ void h0_pack(const float* __restrict__ hn, bf* __restrict__ Hext) {
    int id = blockIdx.x * 256 + threadIdx.x;       // 65536
    int b = id >> 9, e = id & 511;
    float v = (e < 256) ? hn[(size_t)b * 256 + e] : hn[(size_t)(BB + b) * 256 + (e - 256)];
    Hext[id] = (bf)f2bf(v);
}

// Btg[(g*NCOL + n)][k] = bf16(Whh[(n&3)*512 + g*JC + (n>>2)][k])
__global__ void bt_prep(const float* __restrict__ Whh, bf* __restrict__ Btg) {
    int id = blockIdx.x * 256 + threadIdx.x;       // 2048*64 = 131072; 8 elems each
    int row = id >> 6, chunk = (id & 63) * 8;
    int g = row >> 5, n = row & 31;
    int r = (n & 3) * 512 + g * JC + (n >> 2);
    const float* src = Whh + (size_t)r * 512 + chunk;
    ushort8 o;
#pragma unroll
    for (int i = 0; i < 8; ++i) o[i] = (bf)f2bf(src[i]);
    *(ushort8*)(Btg + (size_t)row * 512 + chunk) = o;
}

// one-hot extraction: xidx[t][b], xval[t][b]; step 0 is zeros
__global__ void x_prep(const float* __restrict__ tos, int* __restrict__ xidx,
                       float* __restrict__ xval) {
    int id = blockIdx.x * 256 + threadIdx.x;       // TT*BB = 32768
    int t = id >> 7, b = id & 127;
    int idx = 0; float val = 0.f;
    if (t > 0) {
        const float* row = tos + ((size_t)b * TT + t) * NC;
        for (int k = 0; k < NC; ++k) {
            float v = row[k];
            if (v != 0.f) { idx = k; val = v; }
        }
    }
    xidx[(size_t)t * BB + b] = idx;
    xval[(size_t)t * BB + b] = val;
}

// ---------------------------------------------------------------------------
// Persistent MFMA LSTM. 64 WGs x 256 threads (4 waves). WG g owns h-cols
// [g*8, g*8+8) (32 gate-cols). Per step: gates = h @ WhhSlice^T via
// mfma_f32_32x32x16_bf16 (A=h from global, B=prepped slice, L1/L2-hot),
// + one-hot x gather + bias, nonlinearity, h write, grid barrier.
// ---------------------------------------------------------------------------
__global__ __launch_bounds__(256) void lstm_mfma(
    bf* __restrict__ Hext,           // [TT+1][BB][EE]; [0] prefilled, writes [t+1]
    const bf* __restrict__ Btg,      // [NWG*NCOL][EE]
    const float* __restrict__ Wih,   // [4EE][NC]
    const float* __restrict__ bih, const float* __restrict__ bhh,
    const float* __restrict__ cn,    // [2][BB][256]
    const int* __restrict__ xidx, const float* __restrict__ xval,
    int* bar)
{
    __shared__ float gates[BB][NCOL + 4];   // [128][36] fp32, padded
    __shared__ bf    wiht[NC][40];          // WihT slice [k][n], bf16, padded
    __shared__ float biass[NCOL];

    const int g = blockIdx.x, tid = threadIdx.x;

    // ---- prologue: stage WihT + bias, load c0 ----
    for (int x = tid; x < NCOL * NC; x += 256) {      // x = n*128 + k
        int n = x >> 7, k = x & 127;
        int r = (n & 3) * 512 + g * JC + (n >> 2);
        wiht[k][n] = (bf)f2bf(Wih[(size_t)r * NC + k]);
    }
    if (tid < NCOL) {
        int r = (tid & 3) * 512 + g * JC + (tid >> 2);
        biass[tid] = bih[r] + bhh[r];
    }
    const int b_own = tid >> 1, u_own = tid & 1;
    float creg[4];
    {
        int jbase = g * JC + u_own * 4;
        const float* csrc = (jbase < 256) ? (cn + (size_t)b_own * 256 + jbase)
                                          : (cn + (size_t)(BB + b_own) * 256 + (jbase - 256));
#pragma unroll
        for (int i = 0; i < 4; ++i) creg[i] = csrc[i];
    }
    __syncthreads();

    // MFMA lane geometry (32x32x16: A lane m=l&31,k=(l>>5)*8+e; B lane n=l&31)
    const int w = tid >> 6, l = tid & 63;
    const int arow = w * 32 + (l & 31);
    const int koff = (l >> 5) * 8;
    const bf* Bp = Btg + ((size_t)g * NCOL + (l & 31)) * EE + koff;
    const size_t HStep = (size_t)BB * EE;

    for (int t = 0; t < TT; ++t) {
        // ---- gates = h_{t} (Hext[t]) @ WhhSlice^T ----
        const bf* Ap = Hext + (size_t)t * HStep + (size_t)arow * EE + koff;
        f32x16 acc;
#pragma unroll
        for (int i = 0; i < 16; ++i) acc[i] = 0.f;
#pragma unroll 8
        for (int kt = 0; kt < 32; ++kt) {
            short8 av = *(const short8*)(Ap + kt * 16);
            short8 bv = *(const short8*)(Bp + kt * 16);
            acc = __builtin_amdgcn_mfma_f32_32x32x16_bf16(av, bv, acc, 0, 0, 0);
        }
#pragma unroll
        for (int r = 0; r < 16; ++r) {
            int row = (r & 3) + 8 * (r >> 2) + 4 * (l >> 5);   // verified C/D map
            gates[w * 32 + row][l & 31] = acc[r];
        }
        __syncthreads();

        // ---- nonlinearity: thread owns (b_own, jj = u_own*4 + i) ----
        {
            float xv = xval[(size_t)t * BB + b_own];
            int   xi = xidx[(size_t)t * BB + b_own];
            ushort8 w0 = *(const ushort8*)&wiht[xi][u_own * 16];
            ushort8 w1 = *(const ushort8*)&wiht[xi][u_own * 16 + 8];
            ushort4 hout;
#pragma unroll
            for (int i = 0; i < 4; ++i) {
                float4 ga = *(const float4*)&gates[b_own][u_own * 16 + i * 4];
                float4 bb = *(const float4*)&biass[u_own * 16 + i * 4];
                float xw0, xw1, xw2, xw3;
                if (i < 2) {
                    xw0 = bfu(w0[i * 4 + 0]); xw1 = bfu(w0[i * 4 + 1]);
                    xw2 = bfu(w0[i * 4 + 2]); xw3 = bfu(w0[i * 4 + 3]);
                } else {
                    xw0 = bfu(w1[(i - 2) * 4 + 0]); xw1 = bfu(w1[(i - 2) * 4 + 1]);
                    xw2 = bfu(w1[(i - 2) * 4 + 2]); xw3 = bfu(w1[(i - 2) * 4 + 3]);
                }
                float a0 = ga.x + bb.x + xv * xw0;   // i
                float a1 = ga.y + bb.y + xv * xw1;   // f
                float a2 = ga.z + bb.z + xv * xw2;   // g
                float a3 = ga.w + bb.w + xv * xw3;   // o
                float ig = sigmoidf_(a0);
                float fg = sigmoidf_(a1);
                float gg = tanhf(a2);
                float og = sigmoidf_(a3);
                creg[i] = fg * creg[i] + ig * gg;
                float hnew = og * tanhf(creg[i]);
                hout[i] = (bf)f2bf(hnew);
            }
            *(ushort4*)(Hext + (size_t)(t + 1) * HStep + (size_t)b_own * EE
                        + g * JC + u_own * 4) = hout;
        }

        // ---- grid barrier (monotonic counter, device scope) ----
        __threadfence();
        __syncthreads();
        if (tid == 0) {
            __hip_atomic_fetch_add(bar, 1, __ATOMIC_ACQ_REL, __HIP_MEMORY_SCOPE_AGENT);
            int target = NWG * (t + 1);
            while (__hip_atomic_load(bar, __ATOMIC_ACQUIRE, __HIP_MEMORY_SCOPE_AGENT) < target)
                __builtin_amdgcn_s_sleep(2);
        }
        __syncthreads();
    }
}

// ---------------------------------------------------------------------------
// Generic GEMM: C = alpha*(A @ W^T + bias). A: AT (fp32 or bf16), W fp32,
// C: CT. Optional relu-on-A-load, accumulate-into-C, (t,b)->(b,t) row remap.
// ---------------------------------------------------------------------------
#define GBM 64
#define GBN 64
#define GBK 16
#define GF_RELU_A   2
#define GF_ACCUM    4

template <typename AT, typename CT>
__global__ __launch_bounds__(256) void gemm_bias(
    const AT* __restrict__ A, const float* __restrict__ W,
    const float* __restrict__ bias, CT* __restrict__ C,
    int M, int N, int K, int lda, int ldw, int wcol, int ldc, int ccol,
    float alpha, int flags, int remapT, int remapB)
{
    __shared__ __align__(16) float As[GBK][GBM + 4];
    __shared__ __align__(16) float Bs[GBK][GBN + 4];
    int bm = blockIdx.y * GBM;
    int bn = blockIdx.x * GBN;
    int tid = threadIdx.x;
    int tx = tid & 15, ty = tid >> 4;
    int lr = tid >> 2;            // 0..63
    int lk = (tid & 3) << 2;      // 0,4,8,12
    float acc[4][4] = {};

    for (int k0 = 0; k0 < K; k0 += GBK) {
        {
            int row = bm + lr;
            float4 v = make_float4(0.f, 0.f, 0.f, 0.f);
            if (row < M) v = ld4f(A + (size_t)row * lda + k0 + lk);
            if (flags & GF_RELU_A) {
                v.x = fmaxf(v.x, 0.f); v.y = fmaxf(v.y, 0.f);
                v.z = fmaxf(v.z, 0.f); v.w = fmaxf(v.w, 0.f);
            }
            As[lk + 0][lr] = v.x; As[lk + 1][lr] = v.y;
            As[lk + 2][lr] = v.z; As[lk + 3][lr] = v.w;
        }
        {
            int n = bn + lr;
            float4 v = make_float4(0.f, 0.f, 0.f, 0.f);
            if (n < N) v = *(const float4*)(W + (size_t)n * ldw + wcol + k0 + lk);
            Bs[lk + 0][lr] = v.x; Bs[lk + 1][lr] = v.y;
            Bs[lk + 2][lr] = v.z; Bs[lk + 3][lr] = v.w;
        }
        __syncthreads();
#pragma unroll
        for (int kk = 0; kk < GBK; ++kk) {
            float a[4], bvv[4];
#pragma unroll
            for (int i = 0; i < 4; ++i) a[i] = As[kk][ty * 4 + i];
#pragma unroll
            for (int jj = 0; jj < 4; ++jj) bvv[jj] = Bs[kk][tx * 4 + jj];
#pragma unroll
            for (int i = 0; i < 4; ++i)
#pragma unroll
                for (int jj = 0; jj < 4; ++jj) acc[i][jj] += a[i] * bvv[jj];
        }
        __syncthreads();
    }

#pragma unroll
    for (int i = 0; i < 4; ++i) {
        int r = bm + ty * 4 + i;
        if (r >= M) continue;
        size_t orow;
        if (remapT > 0) { int t = r / remapB, bb_ = r % remapB; orow = (size_t)bb_ * remapT + t; }
        else orow = (size_t)r;
#pragma unroll
        for (int jj = 0; jj < 4; ++jj) {
            int n = bn + tx * 4 + jj;
            if (n >= N) continue;
            float bv = bias ? bias[n] : 0.f;
            float v = (acc[i][jj] + bv) * alpha;
            CT* cp = C + orow * ldc + ccol + n;
            if (flags & GF_ACCUM) v += ld1f(cp);
            st1f(cp, v);
        }
    }
}

// ---------------------------------------------------------------------------
// Fused attention (bf16 Q/K/V/ctx, fp32 math): per (b, 16-step tile):
// scores = q @ K^T, softmax, ctx = p @ V. ctx aliases Q (tile read first).
// ---------------------------------------------------------------------------
template <int S>
__global__ __launch_bounds__(256) void attn_kernel(
    const bf* __restrict__ Q,    // [TT*BB][EE], pre-scaled by 1/sqrt(E)
    const bf* __restrict__ Km,   // [BB][S][EE]
    const bf* __restrict__ Vm,   // [BB][S][EE]
    bf* __restrict__ ctx)        // [TT*BB][EE]
{
    constexpr int RT = 16;  // t-tile
    int t0 = blockIdx.x * RT;
    int b = blockIdx.y;
    int tid = threadIdx.x;

    __shared__ __align__(16) float qs[RT][EE];   // 32 KB
    __shared__ float ps[RT][S];
    __shared__ float red[RT][17];
    __shared__ float rowsum[RT];

#pragma unroll
    for (int i = 0; i < RT * EE / (256 * 8); ++i) {
        int x = (i * 256 + tid) * 8;
        int r = x / EE, e = x % EE;
        uint4 u = *(const uint4*)&Q[((size_t)(t0 + r) * BB + b) * EE + e];
        float f[8]; bf8exp(u, f);
#pragma unroll
        for (int q = 0; q < 8; ++q) qs[r][e + q] = f[q];
    }
    __syncthreads();

    if constexpr (S >= 256) {
        int s = tid;
        float acc[RT] = {};
        const uint4* kp = (const uint4*)&Km[((size_t)b * S + s) * EE];
        for (int e8 = 0; e8 < EE / 8; ++e8) {
            float kf[8]; bf8exp(kp[e8], kf);
#pragma unroll
            for (int r = 0; r < RT; ++r) {
                float a = 0.f;
#pragma unroll
                for (int q = 0; q < 8; ++q) a += qs[r][e8 * 8 + q] * kf[q];
                acc[r] += a;
            }
        }
#pragma unroll
        for (int r = 0; r < RT; ++r) ps[r][s] = acc[r];
    } else {
        constexpr int KS = 256 / S;
        constexpr int EC = EE / KS;
        __shared__ float pp[KS][RT][S];
        int s = tid & (S - 1);
        int kq = tid / S;
        float acc[RT] = {};
        const uint4* kp = (const uint4*)&Km[((size_t)b * S + s) * EE + kq * EC];
        for (int e8 = 0; e8 < EC / 8; ++e8) {
            float kf[8]; bf8exp(kp[e8], kf);
#pragma unroll
            for (int r = 0; r < RT; ++r) {
                float a = 0.f;
#pragma unroll
                for (int q = 0; q < 8; ++q) a += qs[r][kq * EC + e8 * 8 + q] * kf[q];
                acc[r] += a;
            }
        }
#pragma unroll
        for (int r = 0; r < RT; ++r) pp[kq][r][s] = acc[r];
        __syncthreads();
        for (int x = tid; x < RT * S; x += 256) {
            int r = x / S, ss = x % S;
            float v = 0.f;
#pragma unroll
            for (int q = 0; q < KS; ++q) v += pp[q][r][ss];
            ps[r][ss] = v;
        }
    }
    __syncthreads();

    {
        int r = tid >> 4, l = tid & 15;
        float m = -1e30f;
        for (int s = l; s < S; s += 16) m = fmaxf(m, ps[r][s]);
        red[r][l] = m;
        __syncthreads();
        for (int w = 8; w >= 1; w >>= 1) {
            if (l < w) red[r][l] = fmaxf(red[r][l], red[r][l + w]);
            __syncthreads();
        }
        float mm = red[r][0];
        float sum = 0.f;
        for (int s = l; s < S; s += 16) {
            float e = expf(ps[r][s] - mm);
            ps[r][s] = e;
            sum += e;
        }
        __syncthreads();
        red[r][l] = sum;
        __syncthreads();
        for (int w = 8; w >= 1; w >>= 1) {
            if (l < w) red[r][l] += red[r][l + w];
            __syncthreads();
        }
        if (l == 0) rowsum[r] = red[r][0];
    }
    __syncthreads();

    {
        float acc0[RT] = {}, acc1[RT] = {};
        for (int s = 0; s < S; ++s) {
            float v0 = bfu(Vm[((size_t)b * S + s) * EE + tid]);
            float v1 = bfu(Vm[((size_t)b * S + s) * EE + tid + 256]);
#pragma unroll
            for (int r = 0; r < RT; ++r) {
                float p = ps[r][s];
                acc0[r] += p * v0;
                acc1[r] += p * v1;
            }
        }
#pragma unroll
        for (int r = 0; r < RT; ++r) {
            float inv = 1.f / rowsum[r];
            size_t row = (size_t)(t0 + r) * BB + b;
            ctx[row * EE + tid] = (bf)f2bf(acc0[r] * inv);
            ctx[row * EE + tid + 256] = (bf)f2bf(acc1[r] * inv);
        }
    }
}

// ---------------------------------------------------------------------------
extern "C" void kernel_launch(void* const* d_in, const int* in_sizes, int n_in,
                              void* d_out, int out_size, void* d_ws, size_t ws_size,
                              hipStream_t stream) {
    const float* char_enc = (const float*)d_in[0];
    const float* char_hn  = (const float*)d_in[1];
    const float* char_cn  = (const float*)d_in[2];
    const float* tag_enc  = (const float*)d_in[3];
    const float* tos      = (const float*)d_in[4];
    const float* Wih = (const float*)d_in[5];
    const float* Whh = (const float*)d_in[6];
    const float* bih = (const float*)d_in[7];
    const float* bhh = (const float*)d_in[8];
    const float* caWq = (const float*)d_in[9],  *caWk = (const float*)d_in[10], *caWv = (const float*)d_in[11];
    const float* cabq = (const float*)d_in[12], *cabk = (const float*)d_in[13], *cabv = (const float*)d_in[14];
    const float* caWo = (const float*)d_in[15], *cabo = (const float*)d_in[16];
    const float* taWq = (const float*)d_in[17], *taWk = (const float*)d_in[18], *taWv = (const float*)d_in[19];
    const float* tabq = (const float*)d_in[20], *tabk = (const float*)d_in[21], *tabv = (const float*)d_in[22];
    const float* taWo = (const float*)d_in[23], *tabo = (const float*)d_in[24];
    const float* outW = (const float*)d_in[25], *outb = (const float*)d_in[26];
    float* out = (float*)d_out;

    const size_t SZ  = (size_t)TT * BB * EE;       // 16,777,216 elements
    const size_t SZT = (size_t)BB * STAG * EE;     //  2,097,152 elements
    const size_t HEXT = SZ + (size_t)BB * EE;      // (TT+1)*BB*EE

    // layout: [bar 256B][Hext][Qc][Qt][Kc][Vc][Kt][Vt][Btg][xidx][xval]
    const size_t NEED = 256 + HEXT * 2 + 4 * SZ * 2 + 2 * SZT * 2
                      + (size_t)NWG * NCOL * EE * 2 + (size_t)TT * BB * 8;
    if (ws_size < NEED) {
        diag_ws<<<dim3((out_size + 255) / 256), dim3(256), 0, stream>>>(
            out, (float)((double)ws_size / 1048576.0), out_size);
        return;
    }

    char* w = (char*)d_ws;
    int* bar = (int*)w;          w += 256;
    bf* Hext = (bf*)w;           w += HEXT * 2;
    bf* Qc = (bf*)w;             w += SZ * 2;   // becomes ctx_c (in place)
    bf* Qt = (bf*)w;             w += SZ * 2;   // becomes ctx_t (in place)
    bf* Kc = (bf*)w;             w += SZ * 2;   // after attn_c: reused for occ
    bf* Vc = (bf*)w;             w += SZ * 2;   // after attn_c: reused for oct
    bf* Kt = (bf*)w;             w += SZT * 2;
    bf* Vt = (bf*)w;             w += SZT * 2;
    bf* Btg = (bf*)w;            w += (size_t)NWG * NCOL * EE * 2;
    int* xidx = (int*)w;         w += (size_t)TT * BB * 4;
    float* xval = (float*)w;     w += (size_t)TT * BB * 4;

    const bf* Hh = Hext + (size_t)BB * EE;        // H[t][b][e] = Hext[t+1]
    const float QSCALE = 0.044194173824159216f;   // 1/sqrt(512)
    const int M = TT * BB;                        // 32768

    // ---- prep (independent, tiny) ----
    hipMemsetAsync(bar, 0, 256, stream);
    h0_pack<<<dim3(256), dim3(256), 0, stream>>>(char_hn, Hext);
    bt_prep<<<dim3(512), dim3(256), 0, stream>>>(Whh, Btg);
    x_prep<<<dim3(128), dim3(256), 0, stream>>>(tos, xidx, xval);

    // ---- K/V projections (step-invariant), fp32 A -> bf16 C ----
    gemm_bias<float, bf><<<dim3(8, 512), dim3(256), 0, stream>>>(char_enc, caWk, cabk, Kc,
        M, EE, EE, EE, EE, 0, EE, 0, 1.f, 0, 0, 0);
    gemm_bias<float, bf><<<dim3(8, 512), dim3(256), 0, stream>>>(char_enc, caWv, cabv, Vc,
        M, EE, EE, EE, EE, 0, EE, 0, 1.f, 0, 0, 0);
    gemm_bias<float, bf><<<dim3(8, 64), dim3(256), 0, stream>>>(tag_enc, taWk, tabk, Kt,
        BB * STAG, EE, EE, EE, EE, 0, EE, 0, 1.f, 0, 0, 0);
    gemm_bias<float, bf><<<dim3(8, 64), dim3(256), 0, stream>>>(tag_enc, taWv, tabv, Vt,
        BB * STAG, EE, EE, EE, EE, 0, EE, 0, 1.f, 0, 0, 0);

    // ---- persistent MFMA LSTM ----
    lstm_mfma<<<dim3(NWG), dim3(256), 0, stream>>>(Hext, Btg, Wih, bih, bhh,
                                                   char_cn, xidx, xval, bar);

    // ---- Q projections (scaled), bf16 A -> bf16 C ----
    gemm_bias<bf, bf><<<dim3(8, 512), dim3(256), 0, stream>>>(Hh, caWq, cabq, Qc,
        M, EE, EE, EE, EE, 0, EE, 0, QSCALE, 0, 0, 0);
    gemm_bias<bf, bf><<<dim3(8, 512), dim3(256), 0, stream>>>(Hh, taWq, tabq, Qt,
        M, EE, EE, EE, EE, 0, EE, 0, QSCALE, 0, 0, 0);

    // ---- fused attention (ctx aliases Q) ----
    attn_kernel<256><<<dim3(TT / 16, BB), dim3(256), 0, stream>>>(Qc, Kc, Vc, Qc);
    attn_kernel<32><<<dim3(TT / 16, BB), dim3(256), 0, stream>>>(Qt, Kt, Vt, Qt);

    // ---- Wo projections: occ -> Kc buffer, oct -> Vc buffer ----
    gemm_bias<bf, bf><<<dim3(8, 512), dim3(256), 0, stream>>>(Qc, caWo, cabo, Kc,
        M, EE, EE, EE, EE, 0, EE, 0, 1.f, 0, 0, 0);
    gemm_bias<bf, bf><<<dim3(8, 512), dim3(256), 0, stream>>>(Qt, taWo, tabo, Vc,
        M, EE, EE, EE, EE, 0, EE, 0, 1.f, 0, 0, 0);

    // ---- out = relu(occ)@outW[:,:512]^T + outb (+ relu(oct)@outW[:,512:]^T) ----
    gemm_bias<bf, float><<<dim3(2, 512), dim3(256), 0, stream>>>(Kc, outW, outb, out,
        M, NC, EE, EE, 2 * EE, 0, NC, 0, 1.f, GF_RELU_A, TT, BB);
    gemm_bias<bf, float><<<dim3(2, 512), dim3(256), 0, stream>>>(Vc, outW, nullptr, out,
        M, NC, EE, EE, 2 * EE, EE, NC, 0, 1.f, GF_RELU_A | GF_ACCUM, TT, BB);
}

// Round 4
// 4887.074 us; speedup vs baseline: 1.7827x; 1.4319x over previous
//
#include <hip/hip_runtime.h>
#include <cstdint>

// Problem constants
#define BB 128   // batch
#define TT 256   // decode steps / T_CHAR
#define EE 512   // embed
#define NC 128   // n_chars
#define STAG 32  // T_TAG

// LSTM persistent-kernel geometry
#define NWG 64   // workgroups (<< 256 CUs -> co-residency guaranteed)
#define JC 8     // h-columns per WG
#define NCOL 32  // gate-columns per WG = 4*JC

using bf = unsigned short;  // bf16 storage
typedef __attribute__((ext_vector_type(8))) short short8;
typedef __attribute__((ext_vector_type(8))) unsigned short ushort8;
typedef __attribute__((ext_vector_type(16))) float f32x16;
typedef unsigned long long u64;

static __device__ __forceinline__ float bf_lo(uint32_t u) { return __uint_as_float(u << 16); }
static __device__ __forceinline__ float bf_hi(uint32_t u) { return __uint_as_float(u & 0xFFFF0000u); }
static __device__ __forceinline__ float bfu(bf x) { return __uint_as_float(((uint32_t)x) << 16); }
static __device__ __forceinline__ uint32_t f2bf(float f) {
    uint32_t u = __float_as_uint(f);
    return (u + 0x7FFFu + ((u >> 16) & 1u)) >> 16;  // RNE
}
static __device__ __forceinline__ float sigmoidf_(float x) { return 1.f / (1.f + expf(-x)); }

static __device__ __forceinline__ void bf8exp(const uint4 u, float* f) {
    f[0] = bf_lo(u.x); f[1] = bf_hi(u.x); f[2] = bf_lo(u.y); f[3] = bf_hi(u.y);
    f[4] = bf_lo(u.z); f[5] = bf_hi(u.z); f[6] = bf_lo(u.w); f[7] = bf_hi(u.w);
}

// typed load/store helpers (fp32 math, bf16-at-rest)
static __device__ __forceinline__ float4 ld4f(const float* p) { return *(const float4*)p; }
static __device__ __forceinline__ float4 ld4f(const bf* p) {
    ushort4 u = *(const ushort4*)p;
    return make_float4(bfu(u.x), bfu(u.y), bfu(u.z), bfu(u.w));
}
static __device__ __forceinline__ float ld1f(const float* p) { return *p; }
static __device__ __forceinline__ float ld1f(const bf* p) { return bfu(*p); }
static __device__ __forceinline__ void st1f(float* p, float v) { *p = v; }
static __device__ __forceinline__ void st1f(bf* p, float v) { *p = (bf)f2bf(v); }

// ---------------------------------------------------------------------------
__global__ void diag_ws(float* __restrict__ out, float v, int n) {
    int i = blockIdx.x * 256 + threadIdx.x;
    if (i < n) out[i] = v;
}

// ---------------------------------------------------------------------------
// conversions
// ---------------------------------------------------------------------------
__global__ void conv_f2b(const float* __restrict__ s, bf* __restrict__ d, int n) {
    int i = (blockIdx.x * 256 + threadIdx.x) * 4;
    if (i >= n) return;
    float4 v = *(const float4*)(s + i);
    ushort4 o = { (bf)f2bf(v.x), (bf)f2bf(v.y), (bf)f2bf(v.z), (bf)f2bf(v.w) };
    *(ushort4*)(d + i) = o;
}

struct W8 { const float* p[8]; };
__global__ void conv_w8(W8 ws, bf* __restrict__ d) {
    int m = blockIdx.y;
    int i = (blockIdx.x * 256 + threadIdx.x) * 4;    // grid.x = 256 -> 262144 elems
    float4 v = *(const float4*)(ws.p[m] + i);
    ushort4 o = { (bf)f2bf(v.x), (bf)f2bf(v.y), (bf)f2bf(v.z), (bf)f2bf(v.w) };
    *(ushort4*)(d + (size_t)m * 262144 + i) = o;
}

// ---------------------------------------------------------------------------
// Prep kernels for the persistent LSTM
// ---------------------------------------------------------------------------
__global__ void h0_pack(const float* __restrict__ hn, bf* __restrict__ Hext) {
    int id = blockIdx.x * 256 + threadIdx.x;       // 65536
    int b = id >> 9, e = id & 511;
    float v = (e < 256) ? hn[(size_t)b * 256 + e] : hn[(size_t)(BB + b) * 256 + (e - 256)];
    Hext[id] = (bf)f2bf(v);
}

// Btg[(g*NCOL + n)][k] = bf16(Whh[(n&3)*512 + g*JC + (n>>2)][k])
__global__ void bt_prep(const float* __restrict__ Whh, bf* __restrict__ Btg) {
    int id = blockIdx.x * 256 + threadIdx.x;       // 2048*64 = 131072; 8 elems each
    int row = id >> 6, chunk = (id & 63) * 8;
    int g = row >> 5, n = row & 31;
    int r = (n & 3) * 512 + g * JC + (n >> 2);
    const float* src = Whh + (size_t)r * 512 + chunk;
    ushort8 o;
#pragma unroll
    for (int i = 0; i < 8; ++i) o[i] = (bf)f2bf(src[i]);
    *(ushort8*)(Btg + (size_t)row * 512 + chunk) = o;
}

// one-hot extraction: xidx[t][b], xval[t][b]; step 0 is zeros
__global__ void x_prep(const float* __restrict__ tos, int* __restrict__ xidx,
                       float* __restrict__ xval) {
    int id = blockIdx.x * 256 + threadIdx.x;       // TT*BB = 32768
    int t = id >> 7, b = id & 127;
    int idx = 0; float val = 0.f;
    if (t > 0) {
        const float* row = tos + ((size_t)b * TT + t) * NC;
        for (int k = 0; k < NC; ++k) {
            float v = row[k];
            if (v != 0.f) { idx = k; val = v; }
        }
    }
    xidx[(size_t)t * BB + b] = idx;
    xval[(size_t)t * BB + b] = val;
}

// ---------------------------------------------------------------------------
// Persistent MFMA LSTM, fence-free. All cross-WG h traffic via relaxed
// agent-scope atomics (sc1 bypass -> coherence point); weights stay cached.
// Sync: vmcnt drain -> per-WG flag store; wave0 polls all 64 flags.
// ---------------------------------------------------------------------------
__global__ __launch_bounds__(256) void lstm_mfma(
    bf* __restrict__ Hext,           // [TT+1][BB][EE]; [0] prefilled, writes [t+1]
    const bf* __restrict__ Btg,      // [NWG*NCOL][EE]
    const float* __restrict__ Wih,   // [4EE][NC]
    const float* __restrict__ bih, const float* __restrict__ bhh,
    const float* __restrict__ cn,    // [2][BB][256]
    const int* __restrict__ xidx, const float* __restrict__ xval,
    int* flags)
{
    __shared__ float gates[BB][NCOL + 4];   // [128][36] fp32, padded
    __shared__ bf    wiht[NC][40];          // WihT slice [k][n], bf16, padded
    __shared__ float biass[NCOL];

    const int g = blockIdx.x, tid = threadIdx.x;

    // ---- prologue: stage WihT + bias, load c0 ----
    for (int x = tid; x < NCOL * NC; x += 256) {      // x = n*128 + k
        int n = x >> 7, k = x & 127;
        int r = (n & 3) * 512 + g * JC + (n >> 2);
        wiht[k][n] = (bf)f2bf(Wih[(size_t)r * NC + k]);
    }
    if (tid < NCOL) {
        int r = (tid & 3) * 512 + g * JC + (tid >> 2);
        biass[tid] = bih[r] + bhh[r];
    }
    const int b_own = tid >> 1, u_own = tid & 1;
    float creg[4];
    {
        int jbase = g * JC + u_own * 4;
        const float* csrc = (jbase < 256) ? (cn + (size_t)b_own * 256 + jbase)
                                          : (cn + (size_t)(BB + b_own) * 256 + (jbase - 256));
#pragma unroll
        for (int i = 0; i < 4; ++i) creg[i] = csrc[i];
    }
    __syncthreads();

    // MFMA lane geometry (32x32x16: A lane m=l&31, k=(l>>5)*8+e; B lane n=l&31)
    const int w = tid >> 6, l = tid & 63;
    const int arow = w * 32 + (l & 31);
    const int koff = (l >> 5) * 8;                 // 0 or 8 elems
    const bf* Bp = Btg + ((size_t)g * NCOL + (l & 31)) * EE + koff;
    const size_t HStep = (size_t)BB * EE;
    // u64 view: 4 bf16 per u64; row stride = 128 u64
    const size_t aoff_u64 = (size_t)arow * 128 + (koff >> 2);
    u64* Hst = (u64*)(Hext) + (size_t)b_own * 128 + g * 2 + u_own;  // within H[t+1]

    for (int t = 0; t < TT; ++t) {
        // ---- gates = h_t (Hext[t]) @ WhhSlice^T ; A via bypass atomics ----
        const u64* Arow = (const u64*)(Hext + (size_t)t * HStep) + aoff_u64;
        f32x16 acc;
#pragma unroll
        for (int i = 0; i < 16; ++i) acc[i] = 0.f;
#pragma unroll 8
        for (int kt = 0; kt < 32; ++kt) {
            union { u64 u[2]; short8 s; } av;
            av.u[0] = __hip_atomic_load(Arow + kt * 4 + 0, __ATOMIC_RELAXED, __HIP_MEMORY_SCOPE_AGENT);
            av.u[1] = __hip_atomic_load(Arow + kt * 4 + 1, __ATOMIC_RELAXED, __HIP_MEMORY_SCOPE_AGENT);
            short8 bv = *(const short8*)(Bp + kt * 16);
            acc = __builtin_amdgcn_mfma_f32_32x32x16_bf16(av.s, bv, acc, 0, 0, 0);
        }
#pragma unroll
        for (int r = 0; r < 16; ++r) {
            int row = (r & 3) + 8 * (r >> 2) + 4 * (l >> 5);   // verified C/D map
            gates[w * 32 + row][l & 31] = acc[r];
        }
        __syncthreads();

        // ---- nonlinearity: thread owns (b_own, jj = u_own*4 + i) ----
        {
            float xv = xval[(size_t)t * BB + b_own];
            int   xi = xidx[(size_t)t * BB + b_own];
            ushort8 w0 = *(const ushort8*)&wiht[xi][u_own * 16];
            ushort8 w1 = *(const ushort8*)&wiht[xi][u_own * 16 + 8];
            union { ushort4 v; u64 u; } hout;
#pragma unroll
            for (int i = 0; i < 4; ++i) {
                float4 ga = *(const float4*)&gates[b_own][u_own * 16 + i * 4];
                float4 bb = *(const float4*)&biass[u_own * 16 + i * 4];
                float xw0, xw1, xw2, xw3;
                if (i < 2) {
                    xw0 = bfu(w0[i * 4 + 0]); xw1 = bfu(w0[i * 4 + 1]);
                    xw2 = bfu(w0[i * 4 + 2]); xw3 = bfu(w0[i * 4 + 3]);
                } else {
                    xw0 = bfu(w1[(i - 2) * 4 + 0]); xw1 = bfu(w1[(i - 2) * 4 + 1]);
                    xw2 = bfu(w1[(i - 2) * 4 + 2]); xw3 = bfu(w1[(i - 2) * 4 + 3]);
                }
                float a0 = ga.x + bb.x + xv * xw0;   // i
                float a1 = ga.y + bb.y + xv * xw1;   // f
                float a2 = ga.z + bb.z + xv * xw2;   // g
                float a3 = ga.w + bb.w + xv * xw3;   // o
                float ig = sigmoidf_(a0);
                float fg = sigmoidf_(a1);
                float gg = tanhf(a2);
                float og = sigmoidf_(a3);
                creg[i] = fg * creg[i] + ig * gg;
                float hnew = og * tanhf(creg[i]);
                hout.v[i] = (bf)f2bf(hnew);
            }
            // bypass store of 4 bf16 into H[t+1]
            __hip_atomic_store(Hst + (size_t)(t + 1) * (HStep >> 2), hout.u,
                               __ATOMIC_RELAXED, __HIP_MEMORY_SCOPE_AGENT);
        }

        if (t + 1 < TT) {
            // ---- fence-free grid barrier ----
            asm volatile("s_waitcnt vmcnt(0)" ::: "memory");   // own stores at coherence point
            __syncthreads();                                   // whole WG drained
            if (tid == 0)
                __hip_atomic_store(&flags[g], t + 1, __ATOMIC_RELAXED, __HIP_MEMORY_SCOPE_AGENT);
            if (tid < 64) {
                while (true) {
                    int v = __hip_atomic_load(&flags[tid], __ATOMIC_RELAXED, __HIP_MEMORY_SCOPE_AGENT);
                    if (__all(v >= t + 1)) break;
                    __builtin_amdgcn_s_sleep(1);
                }
            }
            asm volatile("" ::: "memory");
            __syncthreads();
        }
    }
}

// ---------------------------------------------------------------------------
// MFMA GEMM: C[M x 512] = bf16( alpha * (A[M x 512]bf16 @ W[512 x 512]bf16^T
//            + bias) ).  Tile 128x128, BK=64, 4 waves (2x2), XOR-swizzled LDS.
// M must be a multiple of 128. grid = (4, M/128), block = 256.
// ---------------------------------------------------------------------------
static __device__ __forceinline__ int lds_off(int row, int colbyte) {
    return row * 128 + (colbyte ^ ((row & 7) << 4));
}

__global__ __launch_bounds__(256) void gemm_mfma(
    const bf* __restrict__ A, const bf* __restrict__ Wb,
    const float* __restrict__ bias, bf* __restrict__ C,
    int M, float alpha)
{
    __shared__ __align__(16) bf As[128 * 64];   // 16 KB, swizzled
    __shared__ __align__(16) bf Bs[128 * 64];   // 16 KB
    const int tid = threadIdx.x;
    const int bm = blockIdx.y * 128, bn = blockIdx.x * 128;
    const int w = tid >> 6, l = tid & 63;
    const int wr = (w >> 1) * 64, wc = (w & 1) * 64;

    f32x16 acc[2][2];
#pragma unroll
    for (int i = 0; i < 2; ++i)
#pragma unroll
        for (int j = 0; j < 2; ++j)
#pragma unroll
            for (int r = 0; r < 16; ++r) acc[i][j][r] = 0.f;

    const int srow = tid >> 3;          // 0..31
    const int scolb = (tid & 7) * 16;   // byte col 0..112
    const int scole = (tid & 7) * 8;    // elem col

    for (int k0 = 0; k0 < 512; k0 += 64) {
#pragma unroll
        for (int pass = 0; pass < 4; ++pass) {
            int row = pass * 32 + srow;
            uint4 va = *(const uint4*)(A + (size_t)(bm + row) * 512 + k0 + scole);
            *(uint4*)((char*)As + lds_off(row, scolb)) = va;
            uint4 vb = *(const uint4*)(Wb + (size_t)(bn + row) * 512 + k0 + scole);
            *(uint4*)((char*)Bs + lds_off(row, scolb)) = vb;
        }
        __syncthreads();
#pragma unroll
        for (int kt = 0; kt < 4; ++kt) {
            const int cb = kt * 32 + (l >> 5) * 16;
            short8 af[2], bfr[2];
#pragma unroll
            for (int i = 0; i < 2; ++i) {
                af[i]  = *(const short8*)((char*)As + lds_off(wr + i * 32 + (l & 31), cb));
                bfr[i] = *(const short8*)((char*)Bs + lds_off(wc + i * 32 + (l & 31), cb));
            }
#pragma unroll
            for (int i = 0; i < 2; ++i)
#pragma unroll
                for (int j = 0; j < 2; ++j)
                    acc[i][j] = __builtin_amdgcn_mfma_f32_32x32x16_bf16(af[i], bfr[j], acc[i][j], 0, 0, 0);
        }
        __syncthreads();
    }

    // epilogue: m = (r&3)+8*(r>>2)+4*(l>>5), n = l&31 (verified map)
#pragma unroll
    for (int i = 0; i < 2; ++i)
#pragma unroll
        for (int j = 0; j < 2; ++j) {
            int n = bn + wc + j * 32 + (l & 31);
            float bv = bias ? bias[n] : 0.f;
#pragma unroll
            for (int r = 0; r < 16; ++r) {
                int m = bm + wr + i * 32 + (r & 3) + 8 * (r >> 2) + 4 * (l >> 5);
                C[(size_t)m * 512 + n] = (bf)f2bf((acc[i][j][r] + bv) * alpha);
            }
        }
}

// ---------------------------------------------------------------------------
// fp32 fallback GEMM (used only for the two final out-projections, N=128):
// C = (relu?(A) @ W^T + bias), optional accumulate, (t,b)->(b,t) row remap.
// ---------------------------------------------------------------------------
#define GBM 64
#define GBN 64
#define GBK 16
#define GF_RELU_A   2
#define GF_ACCUM    4

template <typename AT, typename CT>
__global__ __launch_bounds__(256) void gemm_bias(
    const AT* __restrict__ A, const float* __restrict__ W,
    const float* __restrict__ bias, CT* __restrict__ C,
    int M, int N, int K, int lda, int ldw, int wcol, int ldc, int ccol,
    float alpha, int flags, int remapT, int remapB)
{
    __shared__ __align__(16) float As[GBK][GBM + 4];
    __shared__ __align__(16) float Bs[GBK][GBN + 4];
    int bm = blockIdx.y * GBM;
    int bn = blockIdx.x * GBN;
    int tid = threadIdx.x;
    int tx = tid & 15, ty = tid >> 4;
    int lr = tid >> 2;
    int lk = (tid & 3) << 2;
    float acc[4][4] = {};

    for (int k0 = 0; k0 < K; k0 += GBK) {
        {
            int row = bm + lr;
            float4 v = make_float4(0.f, 0.f, 0.f, 0.f);
            if (row < M) v = ld4f(A + (size_t)row * lda + k0 + lk);
            if (flags & GF_RELU_A) {
                v.x = fmaxf(v.x, 0.f); v.y = fmaxf(v.y, 0.f);
                v.z = fmaxf(v.z, 0.f); v.w = fmaxf(v.w, 0.f);
            }
            As[lk + 0][lr] = v.x; As[lk + 1][lr] = v.y;
            As[lk + 2][lr] = v.z; As[lk + 3][lr] = v.w;
        }
        {
            int n = bn + lr;
            float4 v = make_float4(0.f, 0.f, 0.f, 0.f);
            if (n < N) v = *(const float4*)(W + (size_t)n * ldw + wcol + k0 + lk);
            Bs[lk + 0][lr] = v.x; Bs[lk + 1][lr] = v.y;
            Bs[lk + 2][lr] = v.z; Bs[lk + 3][lr] = v.w;
        }
        __syncthreads();
#pragma unroll
        for (int kk = 0; kk < GBK; ++kk) {
            float a[4], bvv[4];
#pragma unroll
            for (int i = 0; i < 4; ++i) a[i] = As[kk][ty * 4 + i];
#pragma unroll
            for (int jj = 0; jj < 4; ++jj) bvv[jj] = Bs[kk][tx * 4 + jj];
#pragma unroll
            for (int i = 0; i < 4; ++i)
#pragma unroll
                for (int jj = 0; jj < 4; ++jj) acc[i][jj] += a[i] * bvv[jj];
        }
        __syncthreads();
    }

#pragma unroll
    for (int i = 0; i < 4; ++i) {
        int r = bm + ty * 4 + i;
        if (r >= M) continue;
        size_t orow;
        if (remapT > 0) { int t = r / remapB, bb_ = r % remapB; orow = (size_t)bb_ * remapT + t; }
        else orow = (size_t)r;
#pragma unroll
        for (int jj = 0; jj < 4; ++jj) {
            int n = bn + tx * 4 + jj;
            if (n >= N) continue;
            float bv = bias ? bias[n] : 0.f;
            float v = (acc[i][jj] + bv) * alpha;
            CT* cp = C + orow * ldc + ccol + n;
            if (flags & GF_ACCUM) v += ld1f(cp);
            st1f(cp, v);
        }
    }
}

// ---------------------------------------------------------------------------
// Fused attention (bf16 Q/K/V/ctx, fp32 math)
// ---------------------------------------------------------------------------
template <int S>
__global__ __launch_bounds__(256) void attn_kernel(
    const bf* __restrict__ Q, const bf* __restrict__ Km,
    const bf* __restrict__ Vm, bf* __restrict__ ctx)
{
    constexpr int RT = 16;
    int t0 = blockIdx.x * RT;
    int b = blockIdx.y;
    int tid = threadIdx.x;

    __shared__ __align__(16) float qs[RT][EE];
    __shared__ float ps[RT][S];
    __shared__ float red[RT][17];
    __shared__ float rowsum[RT];

#pragma unroll
    for (int i = 0; i < RT * EE / (256 * 8); ++i) {
        int x = (i * 256 + tid) * 8;
        int r = x / EE, e = x % EE;
        uint4 u = *(const uint4*)&Q[((size_t)(t0 + r) * BB + b) * EE + e];
        float f[8]; bf8exp(u, f);
#pragma unroll
        for (int q = 0; q < 8; ++q) qs[r][e + q] = f[q];
    }
    __syncthreads();

    if constexpr (S >= 256) {
        int s = tid;
        float acc[RT] = {};
        const uint4* kp = (const uint4*)&Km[((size_t)b * S + s) * EE];
        for (int e8 = 0; e8 < EE / 8; ++e8) {
            float kf[8]; bf8exp(kp[e8], kf);
#pragma unroll
            for (int r = 0; r < RT; ++r) {
                float a = 0.f;
#pragma unroll
                for (int q = 0; q < 8; ++q) a += qs[r][e8 * 8 + q] * kf[q];
                acc[r] += a;
            }
        }
#pragma unroll
        for (int r = 0; r < RT; ++r) ps[r][s] = acc[r];
    } else {
        constexpr int KS = 256 / S;
        constexpr int EC = EE / KS;
        __shared__ float pp[KS][RT][S];
        int s = tid & (S - 1);
        int kq = tid / S;
        float acc[RT] = {};
        const uint4* kp = (const uint4*)&Km[((size_t)b * S + s) * EE + kq * EC];
        for (int e8 = 0; e8 < EC / 8; ++e8) {
            float kf[8]; bf8exp(kp[e8], kf);
#pragma unroll
            for (int r = 0; r < RT; ++r) {
                float a = 0.f;
#pragma unroll
                for (int q = 0; q < 8; ++q) a += qs[r][kq * EC + e8 * 8 + q] * kf[q];
                acc[r] += a;
            }
        }
#pragma unroll
        for (int r = 0; r < RT; ++r) pp[kq][r][s] = acc[r];
        __syncthreads();
        for (int x = tid; x < RT * S; x += 256) {
            int r = x / S, ss = x % S;
            float v = 0.f;
#pragma unroll
            for (int q = 0; q < KS; ++q) v += pp[q][r][ss];
            ps[r][ss] = v;
        }
    }
    __syncthreads();

    {
        int r = tid >> 4, l = tid & 15;
        float m = -1e30f;
        for (int s = l; s < S; s += 16) m = fmaxf(m, ps[r][s]);
        red[r][l] = m;
        __syncthreads();
        for (int w = 8; w >= 1; w >>= 1) {
            if (l < w) red[r][l] = fmaxf(red[r][l], red[r][l + w]);
            __syncthreads();
        }
        float mm = red[r][0];
        float sum = 0.f;
        for (int s = l; s < S; s += 16) {
            float e = expf(ps[r][s] - mm);
            ps[r][s] = e;
            sum += e;
        }
        __syncthreads();
        red[r][l] = sum;
        __syncthreads();
        for (int w = 8; w >= 1; w >>= 1) {
            if (l < w) red[r][l] += red[r][l + w];
            __syncthreads();
        }
        if (l == 0) rowsum[r] = red[r][0];
    }
    __syncthreads();

    {
        float acc0[RT] = {}, acc1[RT] = {};
        for (int s = 0; s < S; ++s) {
            float v0 = bfu(Vm[((size_t)b * S + s) * EE + tid]);
            float v1 = bfu(Vm[((size_t)b * S + s) * EE + tid + 256]);
#pragma unroll
            for (int r = 0; r < RT; ++r) {
                float p = ps[r][s];
                acc0[r] += p * v0;
                acc1[r] += p * v1;
            }
        }
#pragma unroll
        for (int r = 0; r < RT; ++r) {
            float inv = 1.f / rowsum[r];
            size_t row = (size_t)(t0 + r) * BB + b;
            ctx[row * EE + tid] = (bf)f2bf(acc0[r] * inv);
            ctx[row * EE + tid + 256] = (bf)f2bf(acc1[r] * inv);
        }
    }
}

// ---------------------------------------------------------------------------
extern "C" void kernel_launch(void* const* d_in, const int* in_sizes, int n_in,
                              void* d_out, int out_size, void* d_ws, size_t ws_size,
                              hipStream_t stream) {
    const float* char_enc = (const float*)d_in[0];
    const float* char_hn  = (const float*)d_in[1];
    const float* char_cn  = (const float*)d_in[2];
    const float* tag_enc  = (const float*)d_in[3];
    const float* tos      = (const float*)d_in[4];
    const float* Wih = (const float*)d_in[5];
    const float* Whh = (const float*)d_in[6];
    const float* bih = (const float*)d_in[7];
    const float* bhh = (const float*)d_in[8];
    const float* caWq = (const float*)d_in[9],  *caWk = (const float*)d_in[10], *caWv = (const float*)d_in[11];
    const float* cabq = (const float*)d_in[12], *cabk = (const float*)d_in[13], *cabv = (const float*)d_in[14];
    const float* caWo = (const float*)d_in[15], *cabo = (const float*)d_in[16];
    const float* taWq = (const float*)d_in[17], *taWk = (const float*)d_in[18], *taWv = (const float*)d_in[19];
    const float* tabq = (const float*)d_in[20], *tabk = (const float*)d_in[21], *tabv = (const float*)d_in[22];
    const float* taWo = (const float*)d_in[23], *tabo = (const float*)d_in[24];
    const float* outW = (const float*)d_in[25], *outb = (const float*)d_in[26];
    float* out = (float*)d_out;

    const size_t SZ  = (size_t)TT * BB * EE;       // 16,777,216 elements
    const size_t SZT = (size_t)BB * STAG * EE;     //  2,097,152 elements
    const size_t HEXT = SZ + (size_t)BB * EE;

    // layout (bytes): flags | Hext | Kc | Vc | Qc(=Aenc) | Qt(=Atag) | Kt | Vt
    //                 | Btg | xidx | xval | Wbf
    const size_t NEED = 4096 + HEXT * 2 + 4 * SZ * 2 + 2 * SZT * 2
                      + (size_t)NWG * NCOL * EE * 2 + (size_t)TT * BB * 8
                      + 8 * 512 * 512 * 2;
    if (ws_size < NEED) {
        diag_ws<<<dim3((out_size + 255) / 256), dim3(256), 0, stream>>>(
            out, (float)((double)ws_size / 1048576.0), out_size);
        return;
    }

    char* w = (char*)d_ws;
    int* flags = (int*)w;        w += 4096;
    bf* Hext = (bf*)w;           w += HEXT * 2;
    bf* Kc = (bf*)w;             w += SZ * 2;   // after attn_c: reused for occ
    bf* Vc = (bf*)w;             w += SZ * 2;   // after attn_c: reused for oct
    bf* Qc = (bf*)w;             w += SZ * 2;   // first Aenc, then Q_c -> ctx_c
    bf* Qt = (bf*)w;             w += SZ * 2;   // first Atag, then Q_t -> ctx_t
    bf* Kt = (bf*)w;             w += SZT * 2;
    bf* Vt = (bf*)w;             w += SZT * 2;
    bf* Btg = (bf*)w;            w += (size_t)NWG * NCOL * EE * 2;
    int* xidx = (int*)w;         w += (size_t)TT * BB * 4;
    float* xval = (float*)w;     w += (size_t)TT * BB * 4;
    bf* Wbf = (bf*)w;            w += 8 * 512 * 512 * 2;

    bf* Aenc = Qc;               // alias: dead before Q_c written
    bf* Atag = Qt;

    const bf* Hh = Hext + (size_t)BB * EE;        // H[t][b][e] = Hext[t+1]
    const float QSCALE = 0.044194173824159216f;   // 1/sqrt(512)
    const int M = TT * BB;                        // 32768

    // weight slot map: 0 caWk, 1 caWv, 2 caWq, 3 caWo, 4 taWk, 5 taWv, 6 taWq, 7 taWo
    bf* WbcaK = Wbf + 0 * 262144; bf* WbcaV = Wbf + 1 * 262144;
    bf* WbcaQ = Wbf + 2 * 262144; bf* WbcaO = Wbf + 3 * 262144;
    bf* WbtaK = Wbf + 4 * 262144; bf* WbtaV = Wbf + 5 * 262144;
    bf* WbtaQ = Wbf + 6 * 262144; bf* WbtaO = Wbf + 7 * 262144;

    // ---- prep ----
    hipMemsetAsync(flags, 0, 4096, stream);
    h0_pack<<<dim3(256), dim3(256), 0, stream>>>(char_hn, Hext);
    bt_prep<<<dim3(512), dim3(256), 0, stream>>>(Whh, Btg);
    x_prep<<<dim3(128), dim3(256), 0, stream>>>(tos, xidx, xval);
    W8 w8; w8.p[0] = caWk; w8.p[1] = caWv; w8.p[2] = caWq; w8.p[3] = caWo;
    w8.p[4] = taWk; w8.p[5] = taWv; w8.p[6] = taWq; w8.p[7] = taWo;
    conv_w8<<<dim3(256, 8), dim3(256), 0, stream>>>(w8, Wbf);
    conv_f2b<<<dim3(16384), dim3(256), 0, stream>>>(char_enc, Aenc, (int)SZ);
    conv_f2b<<<dim3(2048), dim3(256), 0, stream>>>(tag_enc, Atag, (int)SZT);

    // ---- K/V projections (MFMA) ----
    gemm_mfma<<<dim3(4, 256), dim3(256), 0, stream>>>(Aenc, WbcaK, cabk, Kc, M, 1.f);
    gemm_mfma<<<dim3(4, 256), dim3(256), 0, stream>>>(Aenc, WbcaV, cabv, Vc, M, 1.f);
    gemm_mfma<<<dim3(4, 32), dim3(256), 0, stream>>>(Atag, WbtaK, tabk, Kt, BB * STAG, 1.f);
    gemm_mfma<<<dim3(4, 32), dim3(256), 0, stream>>>(Atag, WbtaV, tabv, Vt, BB * STAG, 1.f);

    // ---- persistent MFMA LSTM (fence-free sync) ----
    lstm_mfma<<<dim3(NWG), dim3(256), 0, stream>>>(Hext, Btg, Wih, bih, bhh,
                                                   char_cn, xidx, xval, flags);

    // ---- Q projections (scaled) ----
    gemm_mfma<<<dim3(4, 256), dim3(256), 0, stream>>>(Hh, WbcaQ, cabq, Qc, M, QSCALE);
    gemm_mfma<<<dim3(4, 256), dim3(256), 0, stream>>>(Hh, WbtaQ, tabq, Qt, M, QSCALE);

    // ---- fused attention (ctx aliases Q) ----
    attn_kernel<256><<<dim3(TT / 16, BB), dim3(256), 0, stream>>>(Qc, Kc, Vc, Qc);
    attn_kernel<32><<<dim3(TT / 16, BB), dim3(256), 0, stream>>>(Qt, Kt, Vt, Qt);

    // ---- Wo projections: occ -> Kc buffer, oct -> Vc buffer ----
    gemm_mfma<<<dim3(4, 256), dim3(256), 0, stream>>>(Qc, WbcaO, cabo, Kc, M, 1.f);
    gemm_mfma<<<dim3(4, 256), dim3(256), 0, stream>>>(Qt, WbtaO, tabo, Vc, M, 1.f);

    // ---- out = relu(occ)@outW[:,:512]^T + outb (+ relu(oct)@outW[:,512:]^T) ----
    gemm_bias<bf, float><<<dim3(2, 512), dim3(256), 0, stream>>>(Kc, outW, outb, out,
        M, NC, EE, EE, 2 * EE, 0, NC, 0, 1.f, GF_RELU_A, TT, BB);
    gemm_bias<bf, float><<<dim3(2, 512), dim3(256), 0, stream>>>(Vc, outW, nullptr, out,
        M, NC, EE, EE, 2 * EE, EE, NC, 0, 1.f, GF_RELU_A | GF_ACCUM, TT, BB);
}

// Round 5
// 3426.596 us; speedup vs baseline: 2.5426x; 1.4262x over previous
//
#include <hip/hip_runtime.h>
#include <cstdint>

// Problem constants
#define BB 128   // batch
#define TT 256   // decode steps / T_CHAR
#define EE 512   // embed
#define NC 128   // n_chars
#define STAG 32  // T_TAG

// LSTM persistent-kernel geometry
#define NWG 64   // workgroups (<< 256 CUs -> co-residency guaranteed)
#define JC 8     // h-columns per WG
#define NCOL 32  // gate-columns per WG = 4*JC

using bf = unsigned short;  // bf16 storage
typedef __attribute__((ext_vector_type(8))) short short8;
typedef __attribute__((ext_vector_type(8))) unsigned short ushort8;
typedef __attribute__((ext_vector_type(16))) float f32x16;
typedef unsigned long long u64;

static __device__ __forceinline__ float bf_lo(uint32_t u) { return __uint_as_float(u << 16); }
static __device__ __forceinline__ float bf_hi(uint32_t u) { return __uint_as_float(u & 0xFFFF0000u); }
static __device__ __forceinline__ float bfu(bf x) { return __uint_as_float(((uint32_t)x) << 16); }
static __device__ __forceinline__ uint32_t f2bf(float f) {
    uint32_t u = __float_as_uint(f);
    return (u + 0x7FFFu + ((u >> 16) & 1u)) >> 16;  // RNE
}
static __device__ __forceinline__ float sigmoidf_(float x) { return 1.f / (1.f + expf(-x)); }

static __device__ __forceinline__ void bf8exp(const uint4 u, float* f) {
    f[0] = bf_lo(u.x); f[1] = bf_hi(u.x); f[2] = bf_lo(u.y); f[3] = bf_hi(u.y);
    f[4] = bf_lo(u.z); f[5] = bf_hi(u.z); f[6] = bf_lo(u.w); f[7] = bf_hi(u.w);
}

// relu on two packed bf16 (clear if sign bit set)
static __device__ __forceinline__ uint32_t relu2bf(uint32_t x) {
    uint32_t lo = x & 0xFFFFu, hi = x >> 16;
    lo = (lo & 0x8000u) ? 0u : lo;
    hi = (hi & 0x8000u) ? 0u : hi;
    return lo | (hi << 16);
}

// ---------------------------------------------------------------------------
__global__ void diag_ws(float* __restrict__ out, float v, int n) {
    int i = blockIdx.x * 256 + threadIdx.x;
    if (i < n) out[i] = v;
}

// ---------------------------------------------------------------------------
// conversions
// ---------------------------------------------------------------------------
__global__ void conv_f2b(const float* __restrict__ s, bf* __restrict__ d, int n) {
    int i = (blockIdx.x * 256 + threadIdx.x) * 4;
    if (i >= n) return;
    float4 v = *(const float4*)(s + i);
    ushort4 o = { (bf)f2bf(v.x), (bf)f2bf(v.y), (bf)f2bf(v.z), (bf)f2bf(v.w) };
    *(ushort4*)(d + i) = o;
}

struct W8 { const float* p[8]; };
__global__ void conv_w8(W8 ws, bf* __restrict__ d) {
    int m = blockIdx.y;
    int i = (blockIdx.x * 256 + threadIdx.x) * 4;    // grid.x = 256 -> 262144 elems
    float4 v = *(const float4*)(ws.p[m] + i);
    ushort4 o = { (bf)f2bf(v.x), (bf)f2bf(v.y), (bf)f2bf(v.z), (bf)f2bf(v.w) };
    *(ushort4*)(d + (size_t)m * 262144 + i) = o;
}

// ---------------------------------------------------------------------------
// Prep kernels for the persistent LSTM
// H2 layout: Hext[t][grp][b][8] with grp = col>>3  (full-line stores/loads)
// ---------------------------------------------------------------------------
__global__ void h0_pack(const float* __restrict__ hn, bf* __restrict__ Hext) {
    int id = blockIdx.x * 256 + threadIdx.x;       // 65536
    int b = id >> 9, e = id & 511;
    float v = (e < 256) ? hn[(size_t)b * 256 + e] : hn[(size_t)(BB + b) * 256 + (e - 256)];
    Hext[((size_t)(e >> 3) * BB + b) * 8 + (e & 7)] = (bf)f2bf(v);
}

// Btg[(g*NCOL + n)][k] = bf16(Whh[(n&3)*512 + g*JC + (n>>2)][k])
__global__ void bt_prep(const float* __restrict__ Whh, bf* __restrict__ Btg) {
    int id = blockIdx.x * 256 + threadIdx.x;       // 2048*64 = 131072; 8 elems each
    int row = id >> 6, chunk = (id & 63) * 8;
    int g = row >> 5, n = row & 31;
    int r = (n & 3) * 512 + g * JC + (n >> 2);
    const float* src = Whh + (size_t)r * 512 + chunk;
    ushort8 o;
#pragma unroll
    for (int i = 0; i < 8; ++i) o[i] = (bf)f2bf(src[i]);
    *(ushort8*)(Btg + (size_t)row * 512 + chunk) = o;
}

// one-hot extraction: xidx[t][b], xval[t][b]; step 0 is zeros
__global__ void x_prep(const float* __restrict__ tos, int* __restrict__ xidx,
                       float* __restrict__ xval) {
    int id = blockIdx.x * 256 + threadIdx.x;       // TT*BB = 32768
    int t = id >> 7, b = id & 127;
    int idx = 0; float val = 0.f;
    if (t > 0) {
        const float* row = tos + ((size_t)b * TT + t) * NC;
        for (int k = 0; k < NC; ++k) {
            float v = row[k];
            if (v != 0.f) { idx = k; val = v; }
        }
    }
    xidx[(size_t)t * BB + b] = idx;
    xval[(size_t)t * BB + b] = val;
}

// ---------------------------------------------------------------------------
// Persistent MFMA LSTM. H cross-WG traffic: relaxed agent atomics on fresh
// addresses (always cold in L2 -> coherent). Barrier flags: SYSTEM scope
// (true L2 bypass) + per-step flag rows (no address reuse -> no stale spin).
// ---------------------------------------------------------------------------
__global__ __launch_bounds__(256) void lstm_mfma(
    bf* __restrict__ Hext,           // H2: [TT+1][64][BB][8]; [0] prefilled
    const bf* __restrict__ Btg,      // [NWG*NCOL][EE]
    const float* __restrict__ Wih,   // [4EE][NC]
    const float* __restrict__ bih, const float* __restrict__ bhh,
    const float* __restrict__ cn,    // [2][BB][256]
    const int* __restrict__ xidx, const float* __restrict__ xval,
    int* flags)                      // [TT][NWG] ints, zeroed
{
    __shared__ float gates[BB][NCOL + 4];   // [128][36] fp32, padded
    __shared__ bf    wiht[NC][40];          // WihT slice [k][n], bf16, padded
    __shared__ float biass[NCOL];

    const int g = blockIdx.x, tid = threadIdx.x;

    // ---- prologue: stage WihT + bias, load c0 ----
    for (int x = tid; x < NCOL * NC; x += 256) {      // x = n*128 + k
        int n = x >> 7, k = x & 127;
        int r = (n & 3) * 512 + g * JC + (n >> 2);
        wiht[k][n] = (bf)f2bf(Wih[(size_t)r * NC + k]);
    }
    if (tid < NCOL) {
        int r = (tid & 3) * 512 + g * JC + (tid >> 2);
        biass[tid] = bih[r] + bhh[r];
    }
    const int b_own = tid >> 1, u_own = tid & 1;
    float creg[4];
    {
        int jbase = g * JC + u_own * 4;
        const float* csrc = (jbase < 256) ? (cn + (size_t)b_own * 256 + jbase)
                                          : (cn + (size_t)(BB + b_own) * 256 + (jbase - 256));
#pragma unroll
        for (int i = 0; i < 4; ++i) creg[i] = csrc[i];
    }
    __syncthreads();

    // MFMA lane geometry (32x32x16: A lane m=l&31, k=(l>>5)*8+e; B lane n=l&31)
    const int w = tid >> 6, l = tid & 63;
    const int arow = w * 32 + (l & 31);            // batch row
    const int khalf = l >> 5;                      // 0/1
    const bf* Bp = Btg + ((size_t)g * NCOL + (l & 31)) * EE + khalf * 8;
    const u64* Hu = (const u64*)Hext;
    u64* Hw = (u64*)Hext;
    const size_t SLAB64 = (size_t)64 * BB * 8 / 4;   // 16384 u64 per t-slab

    for (int t = 0; t < TT; ++t) {
        // ---- gates = h_t @ WhhSlice^T ; A from H2[t] via agent atomics ----
        const u64* At = Hu + (size_t)t * SLAB64 + arow * 2;
        f32x16 acc;
#pragma unroll
        for (int i = 0; i < 16; ++i) acc[i] = 0.f;
#pragma unroll 8
        for (int kt = 0; kt < 32; ++kt) {
            int grp = kt * 2 + khalf;
            union { u64 u[2]; short8 s; } av;
            av.u[0] = __hip_atomic_load(At + (size_t)grp * 256 + 0, __ATOMIC_RELAXED, __HIP_MEMORY_SCOPE_AGENT);
            av.u[1] = __hip_atomic_load(At + (size_t)grp * 256 + 1, __ATOMIC_RELAXED, __HIP_MEMORY_SCOPE_AGENT);
            short8 bv = *(const short8*)(Bp + kt * 16);
            acc = __builtin_amdgcn_mfma_f32_32x32x16_bf16(av.s, bv, acc, 0, 0, 0);
        }
#pragma unroll
        for (int r = 0; r < 16; ++r) {
            int row = (r & 3) + 8 * (r >> 2) + 4 * (l >> 5);   // verified C/D map
            gates[w * 32 + row][l & 31] = acc[r];
        }
        __syncthreads();

        // ---- nonlinearity: thread owns (b_own, jj = u_own*4 + i) ----
        {
            float xv = xval[(size_t)t * BB + b_own];
            int   xi = xidx[(size_t)t * BB + b_own];
            ushort8 w0 = *(const ushort8*)&wiht[xi][u_own * 16];
            ushort8 w1 = *(const ushort8*)&wiht[xi][u_own * 16 + 8];
            union { ushort4 v; u64 u; } hout;
#pragma unroll
            for (int i = 0; i < 4; ++i) {
                float4 ga = *(const float4*)&gates[b_own][u_own * 16 + i * 4];
                float4 bb = *(const float4*)&biass[u_own * 16 + i * 4];
                float xw0, xw1, xw2, xw3;
                if (i < 2) {
                    xw0 = bfu(w0[i * 4 + 0]); xw1 = bfu(w0[i * 4 + 1]);
                    xw2 = bfu(w0[i * 4 + 2]); xw3 = bfu(w0[i * 4 + 3]);
                } else {
                    xw0 = bfu(w1[(i - 2) * 4 + 0]); xw1 = bfu(w1[(i - 2) * 4 + 1]);
                    xw2 = bfu(w1[(i - 2) * 4 + 2]); xw3 = bfu(w1[(i - 2) * 4 + 3]);
                }
                float a0 = ga.x + bb.x + xv * xw0;   // i
                float a1 = ga.y + bb.y + xv * xw1;   // f
                float a2 = ga.z + bb.z + xv * xw2;   // g
                float a3 = ga.w + bb.w + xv * xw3;   // o
                float ig = sigmoidf_(a0);
                float fg = sigmoidf_(a1);
                float gg = tanhf(a2);
                float og = sigmoidf_(a3);
                creg[i] = fg * creg[i] + ig * gg;
                float hnew = og * tanhf(creg[i]);
                hout.v[i] = (bf)f2bf(hnew);
            }
            // contiguous full-line store block: H2[t+1][g][b][u*4..]
            __hip_atomic_store(Hw + (size_t)(t + 1) * SLAB64 + (size_t)g * 256
                               + b_own * 2 + u_own, hout.u,
                               __ATOMIC_RELAXED, __HIP_MEMORY_SCOPE_AGENT);
        }

        if (t + 1 < TT) {
            // ---- grid barrier: system-scope flags, fresh address per step ----
            asm volatile("s_waitcnt vmcnt(0)" ::: "memory");   // h stores drained
            __syncthreads();
            if (tid == 0)
                __hip_atomic_store(&flags[(t + 1) * NWG + g], 1,
                                   __ATOMIC_RELAXED, __HIP_MEMORY_SCOPE_SYSTEM);
            if (tid < 64) {
                const int* fp = flags + (t + 1) * NWG;
                while (true) {
                    int v = __hip_atomic_load(fp + tid, __ATOMIC_RELAXED,
                                              __HIP_MEMORY_SCOPE_SYSTEM);
                    if (__all(v != 0)) break;
                    __builtin_amdgcn_s_sleep(1);
                }
            }
            asm volatile("" ::: "memory");
            __syncthreads();
        }
    }
}

// ---------------------------------------------------------------------------
// MFMA GEMM: C[M x 512] = bf16( alpha*(A @ W^T + bias) ). Tile 128x128, BK=64,
// 4 waves (2x2), XOR-swizzled LDS. AH2: A stored in H2 [t][grp][b][8] layout.
// ---------------------------------------------------------------------------
static __device__ __forceinline__ int lds_off(int row, int colbyte) {
    return row * 128 + (colbyte ^ ((row & 7) << 4));
}

template <bool AH2>
__global__ __launch_bounds__(256) void gemm_mfma(
    const bf* __restrict__ A, const bf* __restrict__ Wb,
    const float* __restrict__ bias, bf* __restrict__ C,
    int M, float alpha)
{
    __shared__ __align__(16) bf As[128 * 64];   // 16 KB, swizzled
    __shared__ __align__(16) bf Bs[128 * 64];   // 16 KB
    const int tid = threadIdx.x;
    const int bm = blockIdx.y * 128, bn = blockIdx.x * 128;
    const int w = tid >> 6, l = tid & 63;
    const int wr = (w >> 1) * 64, wc = (w & 1) * 64;

    f32x16 acc[2][2];
#pragma unroll
    for (int i = 0; i < 2; ++i)
#pragma unroll
        for (int j = 0; j < 2; ++j)
#pragma unroll
            for (int r = 0; r < 16; ++r) acc[i][j][r] = 0.f;

    const int srow = tid >> 3;          // 0..31
    const int scolb = (tid & 7) * 16;   // byte col
    const int scole = (tid & 7) * 8;    // elem col

    for (int k0 = 0; k0 < 512; k0 += 64) {
#pragma unroll
        for (int pass = 0; pass < 4; ++pass) {
            int row = pass * 32 + srow;
            const bf* ap;
            if constexpr (AH2) {
                int m = bm + row; int tt = m >> 7, bb_ = m & 127;
                int grp = (k0 + scole) >> 3;
                ap = A + ((((size_t)tt * 64 + grp) * BB + bb_) << 3);
            } else {
                ap = A + (size_t)(bm + row) * 512 + k0 + scole;
            }
            uint4 va = *(const uint4*)ap;
            *(uint4*)((char*)As + lds_off(row, scolb)) = va;
            uint4 vb = *(const uint4*)(Wb + (size_t)(bn + row) * 512 + k0 + scole);
            *(uint4*)((char*)Bs + lds_off(row, scolb)) = vb;
        }
        __syncthreads();
#pragma unroll
        for (int kt = 0; kt < 4; ++kt) {
            const int cb = kt * 32 + (l >> 5) * 16;
            short8 af[2], bfr[2];
#pragma unroll
            for (int i = 0; i < 2; ++i) {
                af[i]  = *(const short8*)((char*)As + lds_off(wr + i * 32 + (l & 31), cb));
                bfr[i] = *(const short8*)((char*)Bs + lds_off(wc + i * 32 + (l & 31), cb));
            }
#pragma unroll
            for (int i = 0; i < 2; ++i)
#pragma unroll
                for (int j = 0; j < 2; ++j)
                    acc[i][j] = __builtin_amdgcn_mfma_f32_32x32x16_bf16(af[i], bfr[j], acc[i][j], 0, 0, 0);
        }
        __syncthreads();
    }

#pragma unroll
    for (int i = 0; i < 2; ++i)
#pragma unroll
        for (int j = 0; j < 2; ++j) {
            int n = bn + wc + j * 32 + (l & 31);
            float bv = bias ? bias[n] : 0.f;
#pragma unroll
            for (int r = 0; r < 16; ++r) {
                int m = bm + wr + i * 32 + (r & 3) + 8 * (r >> 2) + 4 * (l >> 5);
                C[(size_t)m * 512 + n] = (bf)f2bf((acc[i][j][r] + bv) * alpha);
            }
        }
}

// ---------------------------------------------------------------------------
// Output projection (MFMA): out[b][t][:] = relu(A1[m]) @ Wo[:, :512]^T
//   + relu(A2[m]) @ Wo[:, 512:]^T + bias,  m = t*BB + b. N = 128.
// grid = (M/128), block = 256.
// ---------------------------------------------------------------------------
__global__ __launch_bounds__(256) void gemm_out(
    const bf* __restrict__ A1, const bf* __restrict__ A2,
    const bf* __restrict__ Wo,      // [128][1024] bf16
    const float* __restrict__ bias, float* __restrict__ out)
{
    __shared__ __align__(16) bf As[128 * 64];
    __shared__ __align__(16) bf Bs[128 * 64];
    const int tid = threadIdx.x;
    const int bm = blockIdx.x * 128;
    const int w = tid >> 6, l = tid & 63;
    const int wr = (w >> 1) * 64, wc = (w & 1) * 64;

    f32x16 acc[2][2];
#pragma unroll
    for (int i = 0; i < 2; ++i)
#pragma unroll
        for (int j = 0; j < 2; ++j)
#pragma unroll
            for (int r = 0; r < 16; ++r) acc[i][j][r] = 0.f;

    const int srow = tid >> 3;
    const int scolb = (tid & 7) * 16;
    const int scole = (tid & 7) * 8;

    for (int k0 = 0; k0 < 1024; k0 += 64) {
        const bf* Asrc = (k0 < 512) ? A1 : A2;
        const int kk = k0 & 511;
#pragma unroll
        for (int pass = 0; pass < 4; ++pass) {
            int row = pass * 32 + srow;
            uint4 va = *(const uint4*)(Asrc + (size_t)(bm + row) * 512 + kk + scole);
            va.x = relu2bf(va.x); va.y = relu2bf(va.y);
            va.z = relu2bf(va.z); va.w = relu2bf(va.w);
            *(uint4*)((char*)As + lds_off(row, scolb)) = va;
            uint4 vb = *(const uint4*)(Wo + (size_t)row * 1024 + k0 + scole);
            *(uint4*)((char*)Bs + lds_off(row, scolb)) = vb;
        }
        __syncthreads();
#pragma unroll
        for (int kt = 0; kt < 4; ++kt) {
            const int cb = kt * 32 + (l >> 5) * 16;
            short8 af[2], bfr[2];
#pragma unroll
            for (int i = 0; i < 2; ++i) {
                af[i]  = *(const short8*)((char*)As + lds_off(wr + i * 32 + (l & 31), cb));
                bfr[i] = *(const short8*)((char*)Bs + lds_off(wc + i * 32 + (l & 31), cb));
            }
#pragma unroll
            for (int i = 0; i < 2; ++i)
#pragma unroll
                for (int j = 0; j < 2; ++j)
                    acc[i][j] = __builtin_amdgcn_mfma_f32_32x32x16_bf16(af[i], bfr[j], acc[i][j], 0, 0, 0);
        }
        __syncthreads();
    }

    // epilogue: remap rows (t,b)->(b,t), fp32 store
#pragma unroll
    for (int i = 0; i < 2; ++i)
#pragma unroll
        for (int j = 0; j < 2; ++j) {
            int n = wc + j * 32 + (l & 31);
            float bv = bias[n];
#pragma unroll
            for (int r = 0; r < 16; ++r) {
                int m = bm + wr + i * 32 + (r & 3) + 8 * (r >> 2) + 4 * (l >> 5);
                int tt = m >> 7, bb_ = m & 127;
                out[((size_t)bb_ * TT + tt) * NC + n] = acc[i][j][r] + bv;
            }
        }
}

// ---------------------------------------------------------------------------
// Fused attention (bf16 Q/K/V/ctx, fp32 math)
// ---------------------------------------------------------------------------
template <int S>
__global__ __launch_bounds__(256) void attn_kernel(
    const bf* __restrict__ Q, const bf* __restrict__ Km,
    const bf* __restrict__ Vm, bf* __restrict__ ctx)
{
    constexpr int RT = 16;
    int t0 = blockIdx.x * RT;
    int b = blockIdx.y;
    int tid = threadIdx.x;

    __shared__ __align__(16) float qs[RT][EE];
    __shared__ float ps[RT][S];
    __shared__ float red[RT][17];
    __shared__ float rowsum[RT];

#pragma unroll
    for (int i = 0; i < RT * EE / (256 * 8); ++i) {
        int x = (i * 256 + tid) * 8;
        int r = x / EE, e = x % EE;
        uint4 u = *(const uint4*)&Q[((size_t)(t0 + r) * BB + b) * EE + e];
        float f[8]; bf8exp(u, f);
#pragma unroll
        for (int q = 0; q < 8; ++q) qs[r][e + q] = f[q];
    }
    __syncthreads();

    if constexpr (S >= 256) {
        int s = tid;
        float acc[RT] = {};
        const uint4* kp = (const uint4*)&Km[((size_t)b * S + s) * EE];
        for (int e8 = 0; e8 < EE / 8; ++e8) {
            float kf[8]; bf8exp(kp[e8], kf);
#pragma unroll
            for (int r = 0; r < RT; ++r) {
                float a = 0.f;
#pragma unroll
                for (int q = 0; q < 8; ++q) a += qs[r][e8 * 8 + q] * kf[q];
                acc[r] += a;
            }
        }
#pragma unroll
        for (int r = 0; r < RT; ++r) ps[r][s] = acc[r];
    } else {
        constexpr int KS = 256 / S;
        constexpr int EC = EE / KS;
        __shared__ float pp[KS][RT][S];
        int s = tid & (S - 1);
        int kq = tid / S;
        float acc[RT] = {};
        const uint4* kp = (const uint4*)&Km[((size_t)b * S + s) * EE + kq * EC];
        for (int e8 = 0; e8 < EC / 8; ++e8) {
            float kf[8]; bf8exp(kp[e8], kf);
#pragma unroll
            for (int r = 0; r < RT; ++r) {
                float a = 0.f;
#pragma unroll
                for (int q = 0; q < 8; ++q) a += qs[r][kq * EC + e8 * 8 + q] * kf[q];
                acc[r] += a;
            }
        }
#pragma unroll
        for (int r = 0; r < RT; ++r) pp[kq][r][s] = acc[r];
        __syncthreads();
        for (int x = tid; x < RT * S; x += 256) {
            int r = x / S, ss = x % S;
            float v = 0.f;
#pragma unroll
            for (int q = 0; q < KS; ++q) v += pp[q][r][ss];
            ps[r][ss] = v;
        }
    }
    __syncthreads();

    {
        int r = tid >> 4, l = tid & 15;
        float m = -1e30f;
        for (int s = l; s < S; s += 16) m = fmaxf(m, ps[r][s]);
        red[r][l] = m;
        __syncthreads();
        for (int w = 8; w >= 1; w >>= 1) {
            if (l < w) red[r][l] = fmaxf(red[r][l], red[r][l + w]);
            __syncthreads();
        }
        float mm = red[r][0];
        float sum = 0.f;
        for (int s = l; s < S; s += 16) {
            float e = expf(ps[r][s] - mm);
            ps[r][s] = e;
            sum += e;
        }
        __syncthreads();
        red[r][l] = sum;
        __syncthreads();
        for (int w = 8; w >= 1; w >>= 1) {
            if (l < w) red[r][l] += red[r][l + w];
            __syncthreads();
        }
        if (l == 0) rowsum[r] = red[r][0];
    }
    __syncthreads();

    {
        float acc0[RT] = {}, acc1[RT] = {};
        for (int s = 0; s < S; ++s) {
            float v0 = bfu(Vm[((size_t)b * S + s) * EE + tid]);
            float v1 = bfu(Vm[((size_t)b * S + s) * EE + tid + 256]);
#pragma unroll
            for (int r = 0; r < RT; ++r) {
                float p = ps[r][s];
                acc0[r] += p * v0;
                acc1[r] += p * v1;
            }
        }
#pragma unroll
        for (int r = 0; r < RT; ++r) {
            float inv = 1.f / rowsum[r];
            size_t row = (size_t)(t0 + r) * BB + b;
            ctx[row * EE + tid] = (bf)f2bf(acc0[r] * inv);
            ctx[row * EE + tid + 256] = (bf)f2bf(acc1[r] * inv);
        }
    }
}

// ---------------------------------------------------------------------------
extern "C" void kernel_launch(void* const* d_in, const int* in_sizes, int n_in,
                              void* d_out, int out_size, void* d_ws, size_t ws_size,
                              hipStream_t stream) {
    const float* char_enc = (const float*)d_in[0];
    const float* char_hn  = (const float*)d_in[1];
    const float* char_cn  = (const float*)d_in[2];
    const float* tag_enc  = (const float*)d_in[3];
    const float* tos      = (const float*)d_in[4];
    const float* Wih = (const float*)d_in[5];
    const float* Whh = (const float*)d_in[6];
    const float* bih = (const float*)d_in[7];
    const float* bhh = (const float*)d_in[8];
    const float* caWq = (const float*)d_in[9],  *caWk = (const float*)d_in[10], *caWv = (const float*)d_in[11];
    const float* cabq = (const float*)d_in[12], *cabk = (const float*)d_in[13], *cabv = (const float*)d_in[14];
    const float* caWo = (const float*)d_in[15], *cabo = (const float*)d_in[16];
    const float* taWq = (const float*)d_in[17], *taWk = (const float*)d_in[18], *taWv = (const float*)d_in[19];
    const float* tabq = (const float*)d_in[20], *tabk = (const float*)d_in[21], *tabv = (const float*)d_in[22];
    const float* taWo = (const float*)d_in[23], *tabo = (const float*)d_in[24];
    const float* outW = (const float*)d_in[25], *outb = (const float*)d_in[26];
    float* out = (float*)d_out;

    const size_t SZ  = (size_t)TT * BB * EE;       // 16,777,216 elements
    const size_t SZT = (size_t)BB * STAG * EE;     //  2,097,152 elements
    const size_t SLAB = (size_t)BB * EE;           // one t-slab of H2
    const size_t HEXT = SZ + SLAB;                 // (TT+1) slabs
    const size_t FLAGB = 131072;                   // flags [TT][NWG] ints

    const size_t NEED = FLAGB + HEXT * 2 + 4 * SZ * 2 + 2 * SZT * 2
                      + (size_t)NWG * NCOL * EE * 2 + (size_t)TT * BB * 8
                      + (8 * 262144 + 131072) * 2;
    if (ws_size < NEED) {
        diag_ws<<<dim3((out_size + 255) / 256), dim3(256), 0, stream>>>(
            out, (float)((double)ws_size / 1048576.0), out_size);
        return;
    }

    char* w = (char*)d_ws;
    int* flags = (int*)w;        w += FLAGB;
    bf* Hext = (bf*)w;           w += HEXT * 2;     // H2 layout
    bf* Kc = (bf*)w;             w += SZ * 2;       // after attn_c: occ
    bf* Vc = (bf*)w;             w += SZ * 2;       // after attn_c: oct
    bf* Qc = (bf*)w;             w += SZ * 2;       // first Aenc, then Q_c -> ctx_c
    bf* Qt = (bf*)w;             w += SZ * 2;       // first Atag, then Q_t -> ctx_t
    bf* Kt = (bf*)w;             w += SZT * 2;
    bf* Vt = (bf*)w;             w += SZT * 2;
    bf* Btg = (bf*)w;            w += (size_t)NWG * NCOL * EE * 2;
    int* xidx = (int*)w;         w += (size_t)TT * BB * 4;
    float* xval = (float*)w;     w += (size_t)TT * BB * 4;
    bf* Wbf = (bf*)w;            w += 8 * 262144 * 2;
    bf* WoutB = (bf*)w;          w += 131072 * 2;

    bf* Aenc = Qc;               // alias: dead before Q_c written
    bf* Atag = Qt;

    const bf* Hh = Hext + SLAB;                   // H[t] = H2 slab t+1
    const float QSCALE = 0.044194173824159216f;   // 1/sqrt(512)
    const int M = TT * BB;                        // 32768

    bf* WbcaK = Wbf + 0 * 262144; bf* WbcaV = Wbf + 1 * 262144;
    bf* WbcaQ = Wbf + 2 * 262144; bf* WbcaO = Wbf + 3 * 262144;
    bf* WbtaK = Wbf + 4 * 262144; bf* WbtaV = Wbf + 5 * 262144;
    bf* WbtaQ = Wbf + 6 * 262144; bf* WbtaO = Wbf + 7 * 262144;

    // ---- prep ----
    hipMemsetAsync(flags, 0, FLAGB, stream);
    h0_pack<<<dim3(256), dim3(256), 0, stream>>>(char_hn, Hext);
    bt_prep<<<dim3(512), dim3(256), 0, stream>>>(Whh, Btg);
    x_prep<<<dim3(128), dim3(256), 0, stream>>>(tos, xidx, xval);
    W8 w8; w8.p[0] = caWk; w8.p[1] = caWv; w8.p[2] = caWq; w8.p[3] = caWo;
    w8.p[4] = taWk; w8.p[5] = taWv; w8.p[6] = taWq; w8.p[7] = taWo;
    conv_w8<<<dim3(256, 8), dim3(256), 0, stream>>>(w8, Wbf);
    conv_f2b<<<dim3(128), dim3(256), 0, stream>>>(outW, WoutB, 131072);
    conv_f2b<<<dim3(16384), dim3(256), 0, stream>>>(char_enc, Aenc, (int)SZ);
    conv_f2b<<<dim3(2048), dim3(256), 0, stream>>>(tag_enc, Atag, (int)SZT);

    // ---- K/V projections (MFMA) ----
    gemm_mfma<false><<<dim3(4, 256), dim3(256), 0, stream>>>(Aenc, WbcaK, cabk, Kc, M, 1.f);
    gemm_mfma<false><<<dim3(4, 256), dim3(256), 0, stream>>>(Aenc, WbcaV, cabv, Vc, M, 1.f);
    gemm_mfma<false><<<dim3(4, 32), dim3(256), 0, stream>>>(Atag, WbtaK, tabk, Kt, BB * STAG, 1.f);
    gemm_mfma<false><<<dim3(4, 32), dim3(256), 0, stream>>>(Atag, WbtaV, tabv, Vt, BB * STAG, 1.f);

    // ---- persistent MFMA LSTM ----
    lstm_mfma<<<dim3(NWG), dim3(256), 0, stream>>>(Hext, Btg, Wih, bih, bhh,
                                                   char_cn, xidx, xval, flags);

    // ---- Q projections (scaled), A in H2 layout ----
    gemm_mfma<true><<<dim3(4, 256), dim3(256), 0, stream>>>(Hh, WbcaQ, cabq, Qc, M, QSCALE);
    gemm_mfma<true><<<dim3(4, 256), dim3(256), 0, stream>>>(Hh, WbtaQ, tabq, Qt, M, QSCALE);

    // ---- fused attention (ctx aliases Q) ----
    attn_kernel<256><<<dim3(TT / 16, BB), dim3(256), 0, stream>>>(Qc, Kc, Vc, Qc);
    attn_kernel<32><<<dim3(TT / 16, BB), dim3(256), 0, stream>>>(Qt, Kt, Vt, Qt);

    // ---- Wo projections: occ -> Kc buffer, oct -> Vc buffer ----
    gemm_mfma<false><<<dim3(4, 256), dim3(256), 0, stream>>>(Qc, WbcaO, cabo, Kc, M, 1.f);
    gemm_mfma<false><<<dim3(4, 256), dim3(256), 0, stream>>>(Qt, WbtaO, tabo, Vc, M, 1.f);

    // ---- output projection (MFMA, fused both halves + relu + remap) ----
    gemm_out<<<dim3(256), dim3(256), 0, stream>>>(Kc, Vc, WoutB, outb, out);
}

// Round 6
// 2857.440 us; speedup vs baseline: 3.0490x; 1.1992x over previous
//
#include <hip/hip_runtime.h>
#include <cstdint>

// Problem constants
#define BB 128   // batch
#define TT 256   // decode steps / T_CHAR
#define EE 512   // embed
#define NC 128   // n_chars
#define STAG 32  // T_TAG

// LSTM persistent-kernel geometry
#define NWG 64   // workgroups (<< 256 CUs -> co-residency guaranteed)
#define JC 8     // h-columns per WG
#define NCOL 32  // gate-columns per WG = 4*JC

using bf = unsigned short;  // bf16 storage
typedef __attribute__((ext_vector_type(8))) short short8;
typedef __attribute__((ext_vector_type(8))) unsigned short ushort8;
typedef __attribute__((ext_vector_type(16))) float f32x16;
typedef unsigned long long u64;

static __device__ __forceinline__ float bf_lo(uint32_t u) { return __uint_as_float(u << 16); }
static __device__ __forceinline__ float bf_hi(uint32_t u) { return __uint_as_float(u & 0xFFFF0000u); }
static __device__ __forceinline__ float bfu(bf x) { return __uint_as_float(((uint32_t)x) << 16); }
static __device__ __forceinline__ uint32_t f2bf(float f) {
    uint32_t u = __float_as_uint(f);
    return (u + 0x7FFFu + ((u >> 16) & 1u)) >> 16;  // RNE
}
static __device__ __forceinline__ float sigmoidf_(float x) { return 1.f / (1.f + expf(-x)); }

static __device__ __forceinline__ void bf8exp(const uint4 u, float* f) {
    f[0] = bf_lo(u.x); f[1] = bf_hi(u.x); f[2] = bf_lo(u.y); f[3] = bf_hi(u.y);
    f[4] = bf_lo(u.z); f[5] = bf_hi(u.z); f[6] = bf_lo(u.w); f[7] = bf_hi(u.w);
}

static __device__ __forceinline__ short8 u4_s8(uint4 u) {
    union { uint4 a; short8 b; } x; x.a = u; return x.b;
}

// relu on two packed bf16 (clear if sign bit set)
static __device__ __forceinline__ uint32_t relu2bf(uint32_t x) {
    uint32_t lo = x & 0xFFFFu, hi = x >> 16;
    lo = (lo & 0x8000u) ? 0u : lo;
    hi = (hi & 0x8000u) ? 0u : hi;
    return lo | (hi << 16);
}

// ---------------------------------------------------------------------------
__global__ void diag_ws(float* __restrict__ out, float v, int n) {
    int i = blockIdx.x * 256 + threadIdx.x;
    if (i < n) out[i] = v;
}

// ---------------------------------------------------------------------------
// conversions
// ---------------------------------------------------------------------------
__global__ void conv_f2b(const float* __restrict__ s, bf* __restrict__ d, int n) {
    int i = (blockIdx.x * 256 + threadIdx.x) * 4;
    if (i >= n) return;
    float4 v = *(const float4*)(s + i);
    ushort4 o = { (bf)f2bf(v.x), (bf)f2bf(v.y), (bf)f2bf(v.z), (bf)f2bf(v.w) };
    *(ushort4*)(d + i) = o;
}

struct W8 { const float* p[8]; };
__global__ void conv_w8(W8 ws, bf* __restrict__ d) {
    int m = blockIdx.y;
    int i = (blockIdx.x * 256 + threadIdx.x) * 4;    // grid.x = 256 -> 262144 elems
    float4 v = *(const float4*)(ws.p[m] + i);
    ushort4 o = { (bf)f2bf(v.x), (bf)f2bf(v.y), (bf)f2bf(v.z), (bf)f2bf(v.w) };
    *(ushort4*)(d + (size_t)m * 262144 + i) = o;
}

// ---------------------------------------------------------------------------
// Prep kernels for the persistent LSTM
// H2 layout: Hext[t][grp][b][8] with grp = col>>3  (full-line stores/loads)
// ---------------------------------------------------------------------------
__global__ void h0_pack(const float* __restrict__ hn, bf* __restrict__ Hext) {
    int id = blockIdx.x * 256 + threadIdx.x;       // 65536
    int b = id >> 9, e = id & 511;
    float v = (e < 256) ? hn[(size_t)b * 256 + e] : hn[(size_t)(BB + b) * 256 + (e - 256)];
    Hext[((size_t)(e >> 3) * BB + b) * 8 + (e & 7)] = (bf)f2bf(v);
}

// Btg[(g*NCOL + n)][k] = bf16(Whh[(n&3)*512 + g*JC + (n>>2)][k])
__global__ void bt_prep(const float* __restrict__ Whh, bf* __restrict__ Btg) {
    int id = blockIdx.x * 256 + threadIdx.x;       // 2048*64 = 131072; 8 elems each
    int row = id >> 6, chunk = (id & 63) * 8;
    int g = row >> 5, n = row & 31;
    int r = (n & 3) * 512 + g * JC + (n >> 2);
    const float* src = Whh + (size_t)r * 512 + chunk;
    ushort8 o;
#pragma unroll
    for (int i = 0; i < 8; ++i) o[i] = (bf)f2bf(src[i]);
    *(ushort8*)(Btg + (size_t)row * 512 + chunk) = o;
}

// one-hot extraction: xidx[t][b], xval[t][b]; step 0 is zeros
__global__ void x_prep(const float* __restrict__ tos, int* __restrict__ xidx,
                       float* __restrict__ xval) {
    int id = blockIdx.x * 256 + threadIdx.x;       // TT*BB = 32768
    int t = id >> 7, b = id & 127;
    int idx = 0; float val = 0.f;
    if (t > 0) {
        const float* row = tos + ((size_t)b * TT + t) * NC;
        for (int k = 0; k < NC; ++k) {
            float v = row[k];
            if (v != 0.f) { idx = k; val = v; }
        }
    }
    xidx[(size_t)t * BB + b] = idx;
    xval[(size_t)t * BB + b] = val;
}

// ---------------------------------------------------------------------------
// Persistent MFMA LSTM segment [tstart, tend). A-fragments: 32 batched
// global_load_dwordx4 sc0 sc1 (bypass L1/L2, coherent at L3) into registers,
// one vmcnt(0), then the MFMA burst. Barrier: one padded counter per step.
// BAR=0: system scope. BAR=1: agent fast-path (16 polls) + system fallback.
// c-state: loaded from cn (cinit=1) or Cst; stored to Cst at segment end.
// ---------------------------------------------------------------------------
template <int BAR>
__global__ __launch_bounds__(256, 1) void lstm_mfma(
    bf* __restrict__ Hext,           // H2: [TT+1][64][BB][8]; [0] prefilled
    const bf* __restrict__ Btg,      // [NWG*NCOL][EE]
    const float* __restrict__ Wih,   // [4EE][NC]
    const float* __restrict__ bih, const float* __restrict__ bhh,
    const float* __restrict__ cn,    // [2][BB][256]
    float* __restrict__ Cst,         // [NWG][BB][8] fp32 c carry
    int cinit,
    const int* __restrict__ xidx, const float* __restrict__ xval,
    int* ctr, int tstart, int tend)  // ctr[t*16], zeroed
{
    __shared__ float gates[BB][NCOL + 4];   // [128][36] fp32, padded
    __shared__ bf    wiht[NC][40];          // WihT slice [k][n], bf16, padded
    __shared__ float biass[NCOL];

    const int g = blockIdx.x, tid = threadIdx.x;

    // ---- prologue: stage WihT + bias, load c ----
    for (int x = tid; x < NCOL * NC; x += 256) {      // x = n*128 + k
        int n = x >> 7, k = x & 127;
        int r = (n & 3) * 512 + g * JC + (n >> 2);
        wiht[k][n] = (bf)f2bf(Wih[(size_t)r * NC + k]);
    }
    if (tid < NCOL) {
        int r = (tid & 3) * 512 + g * JC + (tid >> 2);
        biass[tid] = bih[r] + bhh[r];
    }
    const int b_own = tid >> 1, u_own = tid & 1;
    float creg[4];
    if (cinit) {
        int jbase = g * JC + u_own * 4;
        const float* csrc = (jbase < 256) ? (cn + (size_t)b_own * 256 + jbase)
                                          : (cn + (size_t)(BB + b_own) * 256 + (jbase - 256));
#pragma unroll
        for (int i = 0; i < 4; ++i) creg[i] = csrc[i];
    } else {
        const float* csrc = Cst + (((size_t)g * BB + b_own) * 8) + u_own * 4;
#pragma unroll
        for (int i = 0; i < 4; ++i) creg[i] = csrc[i];
    }
    __syncthreads();

    // MFMA lane geometry (32x32x16: A lane m=l&31, k=(l>>5)*8+e; B lane n=l&31)
    const int w = tid >> 6, l = tid & 63;
    const int arow = w * 32 + (l & 31);            // batch row
    const int khalf = l >> 5;                      // 0/1
    const bf* Bp = Btg + ((size_t)g * NCOL + (l & 31)) * EE + khalf * 8;
    u64* Hw = (u64*)Hext;
    const size_t SLABB = (size_t)BB * EE * 2;      // 131072 bytes per t-slab
    const size_t SLAB64 = (size_t)BB * EE / 4;     // 16384 u64 per t-slab

    for (int t = tstart; t < tend; ++t) {
        // x inputs (independent of gate GEMM; overlap with A loads)
        float xv = xval[(size_t)t * BB + b_own];
        int   xi = xidx[(size_t)t * BB + b_own];

        // ---- A-phase: issue all 32 bypass dwordx4 loads, then one wait ----
        const char* At = (const char*)Hext + (size_t)t * SLABB
                       + (size_t)arow * 16 + (size_t)khalf * 2048;
        uint4 areg[32];
#pragma unroll
        for (int kt = 0; kt < 32; ++kt) {
            asm volatile("global_load_dwordx4 %0, %1, off sc0 sc1"
                         : "=v"(areg[kt]) : "v"(At + (size_t)kt * 4096));
        }
        asm volatile("s_waitcnt vmcnt(0)" ::: "memory");
        __builtin_amdgcn_sched_barrier(0);

        f32x16 acc0, acc1;
#pragma unroll
        for (int i = 0; i < 16; ++i) { acc0[i] = 0.f; acc1[i] = 0.f; }
#pragma unroll
        for (int kt = 0; kt < 32; kt += 2) {
            short8 b0 = *(const short8*)(Bp + (size_t)kt * 16);
            short8 b1 = *(const short8*)(Bp + (size_t)(kt + 1) * 16);
            acc0 = __builtin_amdgcn_mfma_f32_32x32x16_bf16(u4_s8(areg[kt]), b0, acc0, 0, 0, 0);
            acc1 = __builtin_amdgcn_mfma_f32_32x32x16_bf16(u4_s8(areg[kt + 1]), b1, acc1, 0, 0, 0);
        }
#pragma unroll
        for (int r = 0; r < 16; ++r) {
            int row = (r & 3) + 8 * (r >> 2) + 4 * khalf;     // verified C/D map
            gates[w * 32 + row][l & 31] = acc0[r] + acc1[r];
        }
        __syncthreads();

        // ---- nonlinearity: thread owns (b_own, jj = u_own*4 + i) ----
        {
            ushort8 w0 = *(const ushort8*)&wiht[xi][u_own * 16];
            ushort8 w1 = *(const ushort8*)&wiht[xi][u_own * 16 + 8];
            union { ushort4 v; u64 u; } hout;
#pragma unroll
            for (int i = 0; i < 4; ++i) {
                float4 ga = *(const float4*)&gates[b_own][u_own * 16 + i * 4];
                float4 bb = *(const float4*)&biass[u_own * 16 + i * 4];
                float xw0, xw1, xw2, xw3;
                if (i < 2) {
                    xw0 = bfu(w0[i * 4 + 0]); xw1 = bfu(w0[i * 4 + 1]);
                    xw2 = bfu(w0[i * 4 + 2]); xw3 = bfu(w0[i * 4 + 3]);
                } else {
                    xw0 = bfu(w1[(i - 2) * 4 + 0]); xw1 = bfu(w1[(i - 2) * 4 + 1]);
                    xw2 = bfu(w1[(i - 2) * 4 + 2]); xw3 = bfu(w1[(i - 2) * 4 + 3]);
                }
                float a0 = ga.x + bb.x + xv * xw0;   // i
                float a1 = ga.y + bb.y + xv * xw1;   // f
                float a2 = ga.z + bb.z + xv * xw2;   // g
                float a3 = ga.w + bb.w + xv * xw3;   // o
                float ig = sigmoidf_(a0);
                float fg = sigmoidf_(a1);
                float gg = tanhf(a2);
                float og = sigmoidf_(a3);
                creg[i] = fg * creg[i] + ig * gg;
                float hnew = og * tanhf(creg[i]);
                hout.v[i] = (bf)f2bf(hnew);
            }
            __hip_atomic_store(Hw + (size_t)(t + 1) * SLAB64 + (size_t)g * 256
                               + b_own * 2 + u_own, hout.u,
                               __ATOMIC_RELAXED, __HIP_MEMORY_SCOPE_AGENT);
        }

        if (t + 1 < tend) {
            // ---- grid barrier: one padded counter per step ----
            asm volatile("s_waitcnt vmcnt(0)" ::: "memory");   // h stores at L3
            __syncthreads();
            if (tid == 0) {
                int* cp = ctr + (size_t)(t + 1) * 16;
                if constexpr (BAR == 0) {
                    __hip_atomic_fetch_add(cp, 1, __ATOMIC_RELAXED, __HIP_MEMORY_SCOPE_SYSTEM);
                    while (__hip_atomic_load(cp, __ATOMIC_RELAXED,
                                             __HIP_MEMORY_SCOPE_SYSTEM) < NWG)
                        __builtin_amdgcn_s_sleep(1);
                } else {
                    __hip_atomic_fetch_add(cp, 1, __ATOMIC_RELAXED, __HIP_MEMORY_SCOPE_AGENT);
                    bool done = false;
#pragma unroll 1
                    for (int it = 0; it < 16 && !done; ++it) {      // fast path
                        done = __hip_atomic_load(cp, __ATOMIC_RELAXED,
                                                 __HIP_MEMORY_SCOPE_AGENT) >= NWG;
                        if (!done) __builtin_amdgcn_s_sleep(1);
                    }
#pragma unroll 1
                    while (!done) {                                  // safe fallback
                        done = __hip_atomic_load(cp, __ATOMIC_RELAXED,
                                                 __HIP_MEMORY_SCOPE_SYSTEM) >= NWG;
                        if (!done) __builtin_amdgcn_s_sleep(1);
                    }
                }
            }
            __syncthreads();
        }
    }

    // ---- epilogue: persist c for the next segment ----
    {
        float* cdst = Cst + (((size_t)g * BB + b_own) * 8) + u_own * 4;
#pragma unroll
        for (int i = 0; i < 4; ++i) cdst[i] = creg[i];
    }
}

// ---------------------------------------------------------------------------
// MFMA GEMM: C[M x 512] = bf16( alpha*(A @ W^T + bias) ). Tile 128x128, BK=64,
// 4 waves (2x2), XOR-swizzled LDS. AH2: A stored in H2 [t][grp][b][8] layout.
// ---------------------------------------------------------------------------
static __device__ __forceinline__ int lds_off(int row, int colbyte) {
    return row * 128 + (colbyte ^ ((row & 7) << 4));
}

template <bool AH2>
__global__ __launch_bounds__(256) void gemm_mfma(
    const bf* __restrict__ A, const bf* __restrict__ Wb,
    const float* __restrict__ bias, bf* __restrict__ C,
    int M, float alpha)
{
    __shared__ __align__(16) bf As[128 * 64];   // 16 KB, swizzled
    __shared__ __align__(16) bf Bs[128 * 64];   // 16 KB
    const int tid = threadIdx.x;
    const int bm = blockIdx.y * 128, bn = blockIdx.x * 128;
    const int w = tid >> 6, l = tid & 63;
    const int wr = (w >> 1) * 64, wc = (w & 1) * 64;

    f32x16 acc[2][2];
#pragma unroll
    for (int i = 0; i < 2; ++i)
#pragma unroll
        for (int j = 0; j < 2; ++j)
#pragma unroll
            for (int r = 0; r < 16; ++r) acc[i][j][r] = 0.f;

    const int srow = tid >> 3;          // 0..31
    const int scolb = (tid & 7) * 16;   // byte col
    const int scole = (tid & 7) * 8;    // elem col

    for (int k0 = 0; k0 < 512; k0 += 64) {
#pragma unroll
        for (int pass = 0; pass < 4; ++pass) {
            int row = pass * 32 + srow;
            const bf* ap;
            if constexpr (AH2) {
                int m = bm + row; int tt = m >> 7, bb_ = m & 127;
                int grp = (k0 + scole) >> 3;
                ap = A + ((((size_t)tt * 64 + grp) * BB + bb_) << 3);
            } else {
                ap = A + (size_t)(bm + row) * 512 + k0 + scole;
            }
            uint4 va = *(const uint4*)ap;
            *(uint4*)((char*)As + lds_off(row, scolb)) = va;
            uint4 vb = *(const uint4*)(Wb + (size_t)(bn + row) * 512 + k0 + scole);
            *(uint4*)((char*)Bs + lds_off(row, scolb)) = vb;
        }
        __syncthreads();
#pragma unroll
        for (int kt = 0; kt < 4; ++kt) {
            const int cb = kt * 32 + (l >> 5) * 16;
            short8 af[2], bfr[2];
#pragma unroll
            for (int i = 0; i < 2; ++i) {
                af[i]  = *(const short8*)((char*)As + lds_off(wr + i * 32 + (l & 31), cb));
                bfr[i] = *(const short8*)((char*)Bs + lds_off(wc + i * 32 + (l & 31), cb));
            }
#pragma unroll
            for (int i = 0; i < 2; ++i)
#pragma unroll
                for (int j = 0; j < 2; ++j)
                    acc[i][j] = __builtin_amdgcn_mfma_f32_32x32x16_bf16(af[i], bfr[j], acc[i][j], 0, 0, 0);
        }
        __syncthreads();
    }

#pragma unroll
    for (int i = 0; i < 2; ++i)
#pragma unroll
        for (int j = 0; j < 2; ++j) {
            int n = bn + wc + j * 32 + (l & 31);
            float bv = bias ? bias[n] : 0.f;
#pragma unroll
            for (int r = 0; r < 16; ++r) {
                int m = bm + wr + i * 32 + (r & 3) + 8 * (r >> 2) + 4 * (l >> 5);
                C[(size_t)m * 512 + n] = (bf)f2bf((acc[i][j][r] + bv) * alpha);
            }
        }
}

// ---------------------------------------------------------------------------
// Output projection (MFMA): out[b][t][:] = relu(A1[m]) @ Wo[:, :512]^T
//   + relu(A2[m]) @ Wo[:, 512:]^T + bias,  m = t*BB + b. N = 128.
// ---------------------------------------------------------------------------
__global__ __launch_bounds__(256) void gemm_out(
    const bf* __restrict__ A1, const bf* __restrict__ A2,
    const bf* __restrict__ Wo,      // [128][1024] bf16
    const float* __restrict__ bias, float* __restrict__ out)
{
    __shared__ __align__(16) bf As[128 * 64];
    __shared__ __align__(16) bf Bs[128 * 64];
    const int tid = threadIdx.x;
    const int bm = blockIdx.x * 128;
    const int w = tid >> 6, l = tid & 63;
    const int wr = (w >> 1) * 64, wc = (w & 1) * 64;

    f32x16 acc[2][2];
#pragma unroll
    for (int i = 0; i < 2; ++i)
#pragma unroll
        for (int j = 0; j < 2; ++j)
#pragma unroll
            for (int r = 0; r < 16; ++r) acc[i][j][r] = 0.f;

    const int srow = tid >> 3;
    const int scolb = (tid & 7) * 16;
    const int scole = (tid & 7) * 8;

    for (int k0 = 0; k0 < 1024; k0 += 64) {
        const bf* Asrc = (k0 < 512) ? A1 : A2;
        const int kk = k0 & 511;
#pragma unroll
        for (int pass = 0; pass < 4; ++pass) {
            int row = pass * 32 + srow;
            uint4 va = *(const uint4*)(Asrc + (size_t)(bm + row) * 512 + kk + scole);
            va.x = relu2bf(va.x); va.y = relu2bf(va.y);
            va.z = relu2bf(va.z); va.w = relu2bf(va.w);
            *(uint4*)((char*)As + lds_off(row, scolb)) = va;
            uint4 vb = *(const uint4*)(Wo + (size_t)row * 1024 + k0 + scole);
            *(uint4*)((char*)Bs + lds_off(row, scolb)) = vb;
        }
        __syncthreads();
#pragma unroll
        for (int kt = 0; kt < 4; ++kt) {
            const int cb = kt * 32 + (l >> 5) * 16;
            short8 af[2], bfr[2];
#pragma unroll
            for (int i = 0; i < 2; ++i) {
                af[i]  = *(const short8*)((char*)As + lds_off(wr + i * 32 + (l & 31), cb));
                bfr[i] = *(const short8*)((char*)Bs + lds_off(wc + i * 32 + (l & 31), cb));
            }
#pragma unroll
            for (int i = 0; i < 2; ++i)
#pragma unroll
                for (int j = 0; j < 2; ++j)
                    acc[i][j] = __builtin_amdgcn_mfma_f32_32x32x16_bf16(af[i], bfr[j], acc[i][j], 0, 0, 0);
        }
        __syncthreads();
    }

    // epilogue: remap rows (t,b)->(b,t), fp32 store
#pragma unroll
    for (int i = 0; i < 2; ++i)
#pragma unroll
        for (int j = 0; j < 2; ++j) {
            int n = wc + j * 32 + (l & 31);
            float bv = bias[n];
#pragma unroll
            for (int r = 0; r < 16; ++r) {
                int m = bm + wr + i * 32 + (r & 3) + 8 * (r >> 2) + 4 * (l >> 5);
                int tt = m >> 7, bb_ = m & 127;
                out[((size_t)bb_ * TT + tt) * NC + n] = acc[i][j][r] + bv;
            }
        }
}

// ---------------------------------------------------------------------------
// Fused attention (bf16 Q/K/V/ctx, fp32 math)
// ---------------------------------------------------------------------------
template <int S>
__global__ __launch_bounds__(256) void attn_kernel(
    const bf* __restrict__ Q, const bf* __restrict__ Km,
    const bf* __restrict__ Vm, bf* __restrict__ ctx)
{
    constexpr int RT = 16;
    int t0 = blockIdx.x * RT;
    int b = blockIdx.y;
    int tid = threadIdx.x;

    __shared__ __align__(16) float qs[RT][EE];
    __shared__ float ps[RT][S];
    __shared__ float red[RT][17];
    __shared__ float rowsum[RT];

#pragma unroll
    for (int i = 0; i < RT * EE / (256 * 8); ++i) {
        int x = (i * 256 + tid) * 8;
        int r = x / EE, e = x % EE;
        uint4 u = *(const uint4*)&Q[((size_t)(t0 + r) * BB + b) * EE + e];
        float f[8]; bf8exp(u, f);
#pragma unroll
        for (int q = 0; q < 8; ++q) qs[r][e + q] = f[q];
    }
    __syncthreads();

    if constexpr (S >= 256) {
        int s = tid;
        float acc[RT] = {};
        const uint4* kp = (const uint4*)&Km[((size_t)b * S + s) * EE];
        for (int e8 = 0; e8 < EE / 8; ++e8) {
            float kf[8]; bf8exp(kp[e8], kf);
#pragma unroll
            for (int r = 0; r < RT; ++r) {
                float a = 0.f;
#pragma unroll
                for (int q = 0; q < 8; ++q) a += qs[r][e8 * 8 + q] * kf[q];
                acc[r] += a;
            }
        }
#pragma unroll
        for (int r = 0; r < RT; ++r) ps[r][s] = acc[r];
    } else {
        constexpr int KS = 256 / S;
        constexpr int EC = EE / KS;
        __shared__ float pp[KS][RT][S];
        int s = tid & (S - 1);
        int kq = tid / S;
        float acc[RT] = {};
        const uint4* kp = (const uint4*)&Km[((size_t)b * S + s) * EE + kq * EC];
        for (int e8 = 0; e8 < EC / 8; ++e8) {
            float kf[8]; bf8exp(kp[e8], kf);
#pragma unroll
            for (int r = 0; r < RT; ++r) {
                float a = 0.f;
#pragma unroll
                for (int q = 0; q < 8; ++q) a += qs[r][kq * EC + e8 * 8 + q] * kf[q];
                acc[r] += a;
            }
        }
#pragma unroll
        for (int r = 0; r < RT; ++r) pp[kq][r][s] = acc[r];
        __syncthreads();
        for (int x = tid; x < RT * S; x += 256) {
            int r = x / S, ss = x % S;
            float v = 0.f;
#pragma unroll
            for (int q = 0; q < KS; ++q) v += pp[q][r][ss];
            ps[r][ss] = v;
        }
    }
    __syncthreads();

    {
        int r = tid >> 4, l = tid & 15;
        float m = -1e30f;
        for (int s = l; s < S; s += 16) m = fmaxf(m, ps[r][s]);
        red[r][l] = m;
        __syncthreads();
        for (int w = 8; w >= 1; w >>= 1) {
            if (l < w) red[r][l] = fmaxf(red[r][l], red[r][l + w]);
            __syncthreads();
        }
        float mm = red[r][0];
        float sum = 0.f;
        for (int s = l; s < S; s += 16) {
            float e = expf(ps[r][s] - mm);
            ps[r][s] = e;
            sum += e;
        }
        __syncthreads();
        red[r][l] = sum;
        __syncthreads();
        for (int w = 8; w >= 1; w >>= 1) {
            if (l < w) red[r][l] += red[r][l + w];
            __syncthreads();
        }
        if (l == 0) rowsum[r] = red[r][0];
    }
    __syncthreads();

    {
        float acc0[RT] = {}, acc1[RT] = {};
        for (int s = 0; s < S; ++s) {
            float v0 = bfu(Vm[((size_t)b * S + s) * EE + tid]);
            float v1 = bfu(Vm[((size_t)b * S + s) * EE + tid + 256]);
#pragma unroll
            for (int r = 0; r < RT; ++r) {
                float p = ps[r][s];
                acc0[r] += p * v0;
                acc1[r] += p * v1;
            }
        }
#pragma unroll
        for (int r = 0; r < RT; ++r) {
            float inv = 1.f / rowsum[r];
            size_t row = (size_t)(t0 + r) * BB + b;
            ctx[row * EE + tid] = (bf)f2bf(acc0[r] * inv);
            ctx[row * EE + tid + 256] = (bf)f2bf(acc1[r] * inv);
        }
    }
}

// ---------------------------------------------------------------------------
extern "C" void kernel_launch(void* const* d_in, const int* in_sizes, int n_in,
                              void* d_out, int out_size, void* d_ws, size_t ws_size,
                              hipStream_t stream) {
    const float* char_enc = (const float*)d_in[0];
    const float* char_hn  = (const float*)d_in[1];
    const float* char_cn  = (const float*)d_in[2];
    const float* tag_enc  = (const float*)d_in[3];
    const float* tos      = (const float*)d_in[4];
    const float* Wih = (const float*)d_in[5];
    const float* Whh = (const float*)d_in[6];
    const float* bih = (const float*)d_in[7];
    const float* bhh = (const float*)d_in[8];
    const float* caWq = (const float*)d_in[9],  *caWk = (const float*)d_in[10], *caWv = (const float*)d_in[11];
    const float* cabq = (const float*)d_in[12], *cabk = (const float*)d_in[13], *cabv = (const float*)d_in[14];
    const float* caWo = (const float*)d_in[15], *cabo = (const float*)d_in[16];
    const float* taWq = (const float*)d_in[17], *taWk = (const float*)d_in[18], *taWv = (const float*)d_in[19];
    const float* tabq = (const float*)d_in[20], *tabk = (const float*)d_in[21], *tabv = (const float*)d_in[22];
    const float* taWo = (const float*)d_in[23], *tabo = (const float*)d_in[24];
    const float* outW = (const float*)d_in[25], *outb = (const float*)d_in[26];
    float* out = (float*)d_out;

    const size_t SZ  = (size_t)TT * BB * EE;       // 16,777,216 elements
    const size_t SZT = (size_t)BB * STAG * EE;     //  2,097,152 elements
    const size_t SLAB = (size_t)BB * EE;           // one t-slab of H2
    const size_t HEXT = SZ + SLAB;                 // (TT+1) slabs
    const size_t FLAGB = 131072;                   // 2x ctr[TT*16] ints

    const size_t NEED = FLAGB + HEXT * 2 + 4 * SZ * 2 + 2 * SZT * 2
                      + (size_t)NWG * NCOL * EE * 2 + (size_t)TT * BB * 8
                      + (8 * 262144 + 131072) * 2 + (size_t)NWG * BB * 8 * 4;
    if (ws_size < NEED) {
        diag_ws<<<dim3((out_size + 255) / 256), dim3(256), 0, stream>>>(
            out, (float)((double)ws_size / 1048576.0), out_size);
        return;
    }

    char* w = (char*)d_ws;
    int* ctrA = (int*)w;         w += FLAGB;       // ctrA: [TT][16] ints
    int* ctrB = ctrA + TT * 16;
    bf* Hext = (bf*)w;           w += HEXT * 2;    // H2 layout
    bf* Kc = (bf*)w;             w += SZ * 2;      // after attn_c: occ
    bf* Vc = (bf*)w;             w += SZ * 2;      // after attn_c: oct
    bf* Qc = (bf*)w;             w += SZ * 2;      // first Aenc, then Q_c -> ctx_c
    bf* Qt = (bf*)w;             w += SZ * 2;      // first Atag, then Q_t -> ctx_t
    bf* Kt = (bf*)w;             w += SZT * 2;
    bf* Vt = (bf*)w;             w += SZT * 2;
    bf* Btg = (bf*)w;            w += (size_t)NWG * NCOL * EE * 2;
    int* xidx = (int*)w;         w += (size_t)TT * BB * 4;
    float* xval = (float*)w;     w += (size_t)TT * BB * 4;
    bf* Wbf = (bf*)w;            w += 8 * 262144 * 2;
    bf* WoutB = (bf*)w;          w += 131072 * 2;
    float* Cst = (float*)w;      w += (size_t)NWG * BB * 8 * 4;

    bf* Aenc = Qc;               // alias: dead before Q_c written
    bf* Atag = Qt;

    const bf* Hh = Hext + SLAB;                   // H[t] = H2 slab t+1
    const float QSCALE = 0.044194173824159216f;   // 1/sqrt(512)
    const int M = TT * BB;                        // 32768

    bf* WbcaK = Wbf + 0 * 262144; bf* WbcaV = Wbf + 1 * 262144;
    bf* WbcaQ = Wbf + 2 * 262144; bf* WbcaO = Wbf + 3 * 262144;
    bf* WbtaK = Wbf + 4 * 262144; bf* WbtaV = Wbf + 5 * 262144;
    bf* WbtaQ = Wbf + 6 * 262144; bf* WbtaO = Wbf + 7 * 262144;

    // ---- prep ----
    hipMemsetAsync(ctrA, 0, FLAGB, stream);
    h0_pack<<<dim3(256), dim3(256), 0, stream>>>(char_hn, Hext);
    bt_prep<<<dim3(512), dim3(256), 0, stream>>>(Whh, Btg);
    x_prep<<<dim3(128), dim3(256), 0, stream>>>(tos, xidx, xval);
    W8 w8; w8.p[0] = caWk; w8.p[1] = caWv; w8.p[2] = caWq; w8.p[3] = caWo;
    w8.p[4] = taWk; w8.p[5] = taWv; w8.p[6] = taWq; w8.p[7] = taWo;
    conv_w8<<<dim3(256, 8), dim3(256), 0, stream>>>(w8, Wbf);
    conv_f2b<<<dim3(128), dim3(256), 0, stream>>>(outW, WoutB, 131072);
    conv_f2b<<<dim3(16384), dim3(256), 0, stream>>>(char_enc, Aenc, (int)SZ);
    conv_f2b<<<dim3(2048), dim3(256), 0, stream>>>(tag_enc, Atag, (int)SZT);

    // ---- K/V projections (MFMA) ----
    gemm_mfma<false><<<dim3(4, 256), dim3(256), 0, stream>>>(Aenc, WbcaK, cabk, Kc, M, 1.f);
    gemm_mfma<false><<<dim3(4, 256), dim3(256), 0, stream>>>(Aenc, WbcaV, cabv, Vc, M, 1.f);
    gemm_mfma<false><<<dim3(4, 32), dim3(256), 0, stream>>>(Atag, WbtaK, tabk, Kt, BB * STAG, 1.f);
    gemm_mfma<false><<<dim3(4, 32), dim3(256), 0, stream>>>(Atag, WbtaV, tabv, Vt, BB * STAG, 1.f);

    // ---- persistent MFMA LSTM: scope A/B across the two halves ----
    lstm_mfma<0><<<dim3(NWG), dim3(256), 0, stream>>>(Hext, Btg, Wih, bih, bhh,
        char_cn, Cst, 1, xidx, xval, ctrA, 0, 128);
    lstm_mfma<1><<<dim3(NWG), dim3(256), 0, stream>>>(Hext, Btg, Wih, bih, bhh,
        char_cn, Cst, 0, xidx, xval, ctrB, 128, 256);

    // ---- Q projections (scaled), A in H2 layout ----
    gemm_mfma<true><<<dim3(4, 256), dim3(256), 0, stream>>>(Hh, WbcaQ, cabq, Qc, M, QSCALE);
    gemm_mfma<true><<<dim3(4, 256), dim3(256), 0, stream>>>(Hh, WbtaQ, tabq, Qt, M, QSCALE);

    // ---- fused attention (ctx aliases Q) ----
    attn_kernel<256><<<dim3(TT / 16, BB), dim3(256), 0, stream>>>(Qc, Kc, Vc, Qc);
    attn_kernel<32><<<dim3(TT / 16, BB), dim3(256), 0, stream>>>(Qt, Kt, Vt, Qt);

    // ---- Wo projections: occ -> Kc buffer, oct -> Vc buffer ----
    gemm_mfma<false><<<dim3(4, 256), dim3(256), 0, stream>>>(Qc, WbcaO, cabo, Kc, M, 1.f);
    gemm_mfma<false><<<dim3(4, 256), dim3(256), 0, stream>>>(Qt, WbtaO, tabo, Vc, M, 1.f);

    // ---- output projection (MFMA, fused both halves + relu + remap) ----
    gemm_out<<<dim3(256), dim3(256), 0, stream>>>(Kc, Vc, WoutB, outb, out);
}

// Round 7
// 1849.963 us; speedup vs baseline: 4.7095x; 1.5446x over previous
//
#include <hip/hip_runtime.h>
#include <cstdint>

// Problem constants
#define BB 128   // batch
#define TT 256   // decode steps / T_CHAR
#define EE 512   // embed
#define NC 128   // n_chars
#define STAG 32  // T_TAG

// LSTM persistent-kernel geometry: 2D split
#define NWG 64   // = SB * SC
#define SB 4     // batch splits  (32 rows each)
#define SC 16    // column splits (128 gate cols / 32 h-cols each)

using bf = unsigned short;  // bf16 storage
typedef __attribute__((ext_vector_type(8))) short short8;
typedef __attribute__((ext_vector_type(8))) unsigned short ushort8;
typedef __attribute__((ext_vector_type(16))) float f32x16;
typedef unsigned long long u64;

static __device__ __forceinline__ float bf_lo(uint32_t u) { return __uint_as_float(u << 16); }
static __device__ __forceinline__ float bf_hi(uint32_t u) { return __uint_as_float(u & 0xFFFF0000u); }
static __device__ __forceinline__ float bfu(bf x) { return __uint_as_float(((uint32_t)x) << 16); }
static __device__ __forceinline__ uint32_t f2bf(float f) {
    uint32_t u = __float_as_uint(f);
    return (u + 0x7FFFu + ((u >> 16) & 1u)) >> 16;  // RNE
}
static __device__ __forceinline__ float sigmoidf_(float x) { return 1.f / (1.f + expf(-x)); }

static __device__ __forceinline__ void bf8exp(const uint4 u, float* f) {
    f[0] = bf_lo(u.x); f[1] = bf_hi(u.x); f[2] = bf_lo(u.y); f[3] = bf_hi(u.y);
    f[4] = bf_lo(u.z); f[5] = bf_hi(u.z); f[6] = bf_lo(u.w); f[7] = bf_hi(u.w);
}

static __device__ __forceinline__ short8 u4_s8(uint4 u) {
    union { uint4 a; short8 b; } x; x.a = u; return x.b;
}

// relu on two packed bf16 (clear if sign bit set)
static __device__ __forceinline__ uint32_t relu2bf(uint32_t x) {
    uint32_t lo = x & 0xFFFFu, hi = x >> 16;
    lo = (lo & 0x8000u) ? 0u : lo;
    hi = (hi & 0x8000u) ? 0u : hi;
    return lo | (hi << 16);
}

// ---------------------------------------------------------------------------
__global__ void diag_ws(float* __restrict__ out, float v, int n) {
    int i = blockIdx.x * 256 + threadIdx.x;
    if (i < n) out[i] = v;
}

// ---------------------------------------------------------------------------
// conversions
// ---------------------------------------------------------------------------
__global__ void conv_f2b(const float* __restrict__ s, bf* __restrict__ d, int n) {
    int i = (blockIdx.x * 256 + threadIdx.x) * 4;
    if (i >= n) return;
    float4 v = *(const float4*)(s + i);
    ushort4 o = { (bf)f2bf(v.x), (bf)f2bf(v.y), (bf)f2bf(v.z), (bf)f2bf(v.w) };
    *(ushort4*)(d + i) = o;
}

struct W8 { const float* p[8]; };
__global__ void conv_w8(W8 ws, bf* __restrict__ d) {
    int m = blockIdx.y;
    int i = (blockIdx.x * 256 + threadIdx.x) * 4;    // grid.x = 256 -> 262144 elems
    float4 v = *(const float4*)(ws.p[m] + i);
    ushort4 o = { (bf)f2bf(v.x), (bf)f2bf(v.y), (bf)f2bf(v.z), (bf)f2bf(v.w) };
    *(ushort4*)(d + (size_t)m * 262144 + i) = o;
}

// ---------------------------------------------------------------------------
// Prep kernels for the persistent LSTM
// H2 layout: Hext[t][grp][b][8] with grp = col>>3  (full-line stores/loads)
// ---------------------------------------------------------------------------
__global__ void h0_pack(const float* __restrict__ hn, bf* __restrict__ Hext) {
    int id = blockIdx.x * 256 + threadIdx.x;       // 65536
    int b = id >> 9, e = id & 511;
    float v = (e < 256) ? hn[(size_t)b * 256 + e] : hn[(size_t)(BB + b) * 256 + (e - 256)];
    Hext[((size_t)(e >> 3) * BB + b) * 8 + (e & 7)] = (bf)f2bf(v);
}

// Btg2[(cg*128 + n)][k] = bf16(Whh[(n&3)*512 + cg*32 + (n>>2)][k]), cg<16, n<128
__global__ void bt_prep2(const float* __restrict__ Whh, bf* __restrict__ Btg2) {
    int id = blockIdx.x * 256 + threadIdx.x;       // 2048*64 = 131072; 8 elems each
    int row = id >> 6, chunk = (id & 63) * 8;
    int cg = row >> 7, n = row & 127;
    int r = (n & 3) * 512 + cg * 32 + (n >> 2);
    const float* src = Whh + (size_t)r * 512 + chunk;
    ushort8 o;
#pragma unroll
    for (int i = 0; i < 8; ++i) o[i] = (bf)f2bf(src[i]);
    *(ushort8*)(Btg2 + (size_t)row * 512 + chunk) = o;
}

// one-hot extraction: xidx[t][b], xval[t][b]; step 0 is zeros
__global__ void x_prep(const float* __restrict__ tos, int* __restrict__ xidx,
                       float* __restrict__ xval) {
    int id = blockIdx.x * 256 + threadIdx.x;       // TT*BB = 32768
    int t = id >> 7, b = id & 127;
    int idx = 0; float val = 0.f;
    if (t > 0) {
        const float* row = tos + ((size_t)b * TT + t) * NC;
        for (int k = 0; k < NC; ++k) {
            float v = row[k];
            if (v != 0.f) { idx = k; val = v; }
        }
    }
    xidx[(size_t)t * BB + b] = idx;
    xval[(size_t)t * BB + b] = val;
}

// ---------------------------------------------------------------------------
// Persistent MFMA LSTM, 2D split. WG g = bh*SC + cg owns batch rows
// [bh*32, bh*32+32) x h-cols [cg*32, cg*32+32) (128 gate cols).
// Whh slice lives in REGISTERS (128 VGPR/lane, loaded once). A (h_t) staged
// 32 KB -> LDS in exact MFMA fragment layout via batched bypass loads.
// Barrier: per-step padded flag/WG + wave-gather poll, system scope.
// ---------------------------------------------------------------------------
__global__ __launch_bounds__(256, 1) void lstm_mfma(
    bf* __restrict__ Hext,           // H2: [TT+1][64][BB][8]; [0] prefilled
    const bf* __restrict__ Btg2,     // [SC*128][512]
    const float* __restrict__ Wih,   // [2048][128]
    const float* __restrict__ bih, const float* __restrict__ bhh,
    const float* __restrict__ cn,    // [2][128][256]
    const int* __restrict__ xidx, const float* __restrict__ xval,
    char* __restrict__ flags)        // [TT][64 * 128B], zeroed
{
    __shared__ __align__(16) bf Alds[32 * 512];   // 32 KB, fragment layout
    __shared__ float gates[32][132];              // 16.9 KB, 528B rows (16B-aligned)
    __shared__ bf wiht[NC][128];                  // 32 KB: WihT slice [k][n]
    __shared__ float biass[128];

    const int g = blockIdx.x, tid = threadIdx.x;
    const int bh = g >> 4, cg = g & 15;

    // ---- prologue: WihT slice + bias ----
    for (int x = tid; x < 128 * NC; x += 256) {   // x = n*128 + k
        int n = x >> 7, k = x & 127;
        int r = (n & 3) * 512 + cg * 32 + (n >> 2);
        wiht[k][n] = (bf)f2bf(Wih[(size_t)r * NC + k]);
    }
    if (tid < 128) {
        int r = (tid & 3) * 512 + cg * 32 + (tid >> 2);
        biass[tid] = bih[r] + bhh[r];
    }

    // c-state: thread (b_loc = tid>>3, u = tid&7) owns h-cols cg*32+u*4 .. +3
    const int b_loc = tid >> 3, u = tid & 7;
    const int b_glob = bh * 32 + b_loc;
    float creg[4];
    {
        int j0 = cg * 32 + u * 4;
        const float* csrc = (cg < 8) ? (cn + (size_t)b_glob * 256 + j0)
                                     : (cn + (size_t)(BB + b_glob) * 256 + (j0 - 256));
#pragma unroll
        for (int i = 0; i < 4; ++i) creg[i] = csrc[i];
    }

    // ---- wave geometry: wave wv owns gate-col tile [wv*32, wv*32+32) ----
    const int wv = tid >> 6, l = tid & 63;

    // B preload into registers: 32 k-steps x short8 = 128 VGPR, kept all run
    short8 breg[32];
    {
        const bf* bsrc = Btg2 + ((size_t)(cg * 128 + wv * 32 + (l & 31)) * 512)
                       + (l >> 5) * 8;
#pragma unroll
        for (int kt = 0; kt < 32; ++kt) breg[kt] = *(const short8*)(bsrc + kt * 16);
    }
    __syncthreads();

    // staging map: thread handles chunks (sb = tid&31, grp = sg0 + 8i)
    const int sb = tid & 31, sg0 = tid >> 5;
    const int dst_lane = sb | ((sg0 & 1) << 5);
    bf* dstbase = Alds + (size_t)(sg0 >> 1) * 512 + dst_lane * 8;   // + i*2048

    u64* Hw = (u64*)Hext;
    const size_t SLABB = (size_t)BB * EE * 2;      // bytes per t-slab
    const size_t SLAB64 = (size_t)BB * EE / 4;     // u64 per t-slab
    const size_t hst_off = (size_t)(cg * 4 + (u >> 1)) * 256 + b_glob * 2 + (u & 1);
    const bf* ards = Alds + l * 8;

    for (int t = 0; t < TT; ++t) {
        // ---- stage A: 8 batched bypass dwordx4 loads -> LDS (frag layout) ----
        const char* At = (const char*)Hext + (size_t)t * SLABB
                       + (size_t)sg0 * 2048 + (size_t)(bh * 32 + sb) * 16;
        uint4 areg[8];
#pragma unroll
        for (int i = 0; i < 8; ++i) {
            asm volatile("global_load_dwordx4 %0, %1, off sc0 sc1"
                         : "=v"(areg[i]) : "v"(At + (size_t)i * 16384));
        }
        float xv = xval[(size_t)t * BB + b_glob];
        int   xi = xidx[(size_t)t * BB + b_glob];
        asm volatile("s_waitcnt vmcnt(0)" ::: "memory");
        __builtin_amdgcn_sched_barrier(0);
#pragma unroll
        for (int i = 0; i < 8; ++i)
            *(uint4*)(dstbase + (size_t)i * 2048) = areg[i];
        __syncthreads();

        // ---- gates tile: 32 rows x 32 cols per wave, K=512 ----
        f32x16 acc0, acc1;
#pragma unroll
        for (int i = 0; i < 16; ++i) { acc0[i] = 0.f; acc1[i] = 0.f; }
#pragma unroll
        for (int kt = 0; kt < 32; kt += 2) {
            short8 a0 = *(const short8*)(ards + (size_t)kt * 512);
            short8 a1 = *(const short8*)(ards + (size_t)(kt + 1) * 512);
            acc0 = __builtin_amdgcn_mfma_f32_32x32x16_bf16(a0, breg[kt], acc0, 0, 0, 0);
            acc1 = __builtin_amdgcn_mfma_f32_32x32x16_bf16(a1, breg[kt + 1], acc1, 0, 0, 0);
        }
#pragma unroll
        for (int r = 0; r < 16; ++r) {
            int m = (r & 3) + 8 * (r >> 2) + 4 * (l >> 5);   // verified C/D map
            gates[m][wv * 32 + (l & 31)] = acc0[r] + acc1[r];
        }
        __syncthreads();

        // ---- nonlinearity: thread owns (b_loc, 4 h-cols) ----
        {
            union { ushort4 v; u64 uu; } hout;
#pragma unroll
            for (int i = 0; i < 4; ++i) {
                int nb = (u * 4 + i) * 4;          // gate-col base (q=0..3)
                float4 ga  = *(const float4*)&gates[b_loc][nb];
                float4 bb4 = *(const float4*)&biass[nb];
                ushort4 xw = *(const ushort4*)&wiht[xi][nb];
                float a0 = ga.x + bb4.x + xv * bfu(xw.x);   // i
                float a1 = ga.y + bb4.y + xv * bfu(xw.y);   // f
                float a2 = ga.z + bb4.z + xv * bfu(xw.z);   // g
                float a3 = ga.w + bb4.w + xv * bfu(xw.w);   // o
                float ig = sigmoidf_(a0);
                float fg = sigmoidf_(a1);
                float gg = tanhf(a2);
                float og = sigmoidf_(a3);
                creg[i] = fg * creg[i] + ig * gg;
                float hnew = og * tanhf(creg[i]);
                hout.v[i] = (bf)f2bf(hnew);
            }
            __hip_atomic_store(Hw + (size_t)(t + 1) * SLAB64 + hst_off, hout.uu,
                               __ATOMIC_RELAXED, __HIP_MEMORY_SCOPE_AGENT);
        }

        if (t + 1 < TT) {
            // ---- one-hop barrier: own-flag store + wave-gather poll ----
            asm volatile("s_waitcnt vmcnt(0)" ::: "memory");   // h stores drained
            __syncthreads();
            char* fb = flags + (size_t)(t + 1) * 8192;
            if (tid == 0)
                __hip_atomic_store((int*)(fb + (size_t)g * 128), 1,
                                   __ATOMIC_RELAXED, __HIP_MEMORY_SCOPE_SYSTEM);
            if (tid < 64) {
                const int* fp = (const int*)(fb + (size_t)tid * 128);
                while (true) {
                    int v = __hip_atomic_load(fp, __ATOMIC_RELAXED,
                                              __HIP_MEMORY_SCOPE_SYSTEM);
                    if (__all(v != 0)) break;
                    __builtin_amdgcn_s_sleep(1);
                }
            }
            asm volatile("" ::: "memory");
            __syncthreads();
        }
    }
}

// ---------------------------------------------------------------------------
// MFMA GEMM: C[M x 512] = bf16( alpha*(A @ W^T + bias) ). Tile 128x128, BK=64,
// 4 waves (2x2), XOR-swizzled LDS. AH2: A stored in H2 [t][grp][b][8] layout.
// ---------------------------------------------------------------------------
static __device__ __forceinline__ int lds_off(int row, int colbyte) {
    return row * 128 + (colbyte ^ ((row & 7) << 4));
}

template <bool AH2>
__global__ __launch_bounds__(256) void gemm_mfma(
    const bf* __restrict__ A, const bf* __restrict__ Wb,
    const float* __restrict__ bias, bf* __restrict__ C,
    int M, float alpha)
{
    __shared__ __align__(16) bf As[128 * 64];   // 16 KB, swizzled
    __shared__ __align__(16) bf Bs[128 * 64];   // 16 KB
    const int tid = threadIdx.x;
    const int bm = blockIdx.y * 128, bn = blockIdx.x * 128;
    const int w = tid >> 6, l = tid & 63;
    const int wr = (w >> 1) * 64, wc = (w & 1) * 64;

    f32x16 acc[2][2];
#pragma unroll
    for (int i = 0; i < 2; ++i)
#pragma unroll
        for (int j = 0; j < 2; ++j)
#pragma unroll
            for (int r = 0; r < 16; ++r) acc[i][j][r] = 0.f;

    const int srow = tid >> 3;          // 0..31
    const int scolb = (tid & 7) * 16;   // byte col
    const int scole = (tid & 7) * 8;    // elem col

    for (int k0 = 0; k0 < 512; k0 += 64) {
#pragma unroll
        for (int pass = 0; pass < 4; ++pass) {
            int row = pass * 32 + srow;
            const bf* ap;
            if constexpr (AH2) {
                int m = bm + row; int tt = m >> 7, bb_ = m & 127;
                int grp = (k0 + scole) >> 3;
                ap = A + ((((size_t)tt * 64 + grp) * BB + bb_) << 3);
            } else {
                ap = A + (size_t)(bm + row) * 512 + k0 + scole;
            }
            uint4 va = *(const uint4*)ap;
            *(uint4*)((char*)As + lds_off(row, scolb)) = va;
            uint4 vb = *(const uint4*)(Wb + (size_t)(bn + row) * 512 + k0 + scole);
            *(uint4*)((char*)Bs + lds_off(row, scolb)) = vb;
        }
        __syncthreads();
#pragma unroll
        for (int kt = 0; kt < 4; ++kt) {
            const int cb = kt * 32 + (l >> 5) * 16;
            short8 af[2], bfr[2];
#pragma unroll
            for (int i = 0; i < 2; ++i) {
                af[i]  = *(const short8*)((char*)As + lds_off(wr + i * 32 + (l & 31), cb));
                bfr[i] = *(const short8*)((char*)Bs + lds_off(wc + i * 32 + (l & 31), cb));
            }
#pragma unroll
            for (int i = 0; i < 2; ++i)
#pragma unroll
                for (int j = 0; j < 2; ++j)
                    acc[i][j] = __builtin_amdgcn_mfma_f32_32x32x16_bf16(af[i], bfr[j], acc[i][j], 0, 0, 0);
        }
        __syncthreads();
    }

#pragma unroll
    for (int i = 0; i < 2; ++i)
#pragma unroll
        for (int j = 0; j < 2; ++j) {
            int n = bn + wc + j * 32 + (l & 31);
            float bv = bias ? bias[n] : 0.f;
#pragma unroll
            for (int r = 0; r < 16; ++r) {
                int m = bm + wr + i * 32 + (r & 3) + 8 * (r >> 2) + 4 * (l >> 5);
                C[(size_t)m * 512 + n] = (bf)f2bf((acc[i][j][r] + bv) * alpha);
            }
        }
}

// ---------------------------------------------------------------------------
// Output projection (MFMA): out[b][t][:] = relu(A1[m]) @ Wo[:, :512]^T
//   + relu(A2[m]) @ Wo[:, 512:]^T + bias,  m = t*BB + b. N = 128.
// ---------------------------------------------------------------------------
__global__ __launch_bounds__(256) void gemm_out(
    const bf* __restrict__ A1, const bf* __restrict__ A2,
    const bf* __restrict__ Wo,      // [128][1024] bf16
    const float* __restrict__ bias, float* __restrict__ out)
{
    __shared__ __align__(16) bf As[128 * 64];
    __shared__ __align__(16) bf Bs[128 * 64];
    const int tid = threadIdx.x;
    const int bm = blockIdx.x * 128;
    const int w = tid >> 6, l = tid & 63;
    const int wr = (w >> 1) * 64, wc = (w & 1) * 64;

    f32x16 acc[2][2];
#pragma unroll
    for (int i = 0; i < 2; ++i)
#pragma unroll
        for (int j = 0; j < 2; ++j)
#pragma unroll
            for (int r = 0; r < 16; ++r) acc[i][j][r] = 0.f;

    const int srow = tid >> 3;
    const int scolb = (tid & 7) * 16;
    const int scole = (tid & 7) * 8;

    for (int k0 = 0; k0 < 1024; k0 += 64) {
        const bf* Asrc = (k0 < 512) ? A1 : A2;
        const int kk = k0 & 511;
#pragma unroll
        for (int pass = 0; pass < 4; ++pass) {
            int row = pass * 32 + srow;
            uint4 va = *(const uint4*)(Asrc + (size_t)(bm + row) * 512 + kk + scole);
            va.x = relu2bf(va.x); va.y = relu2bf(va.y);
            va.z = relu2bf(va.z); va.w = relu2bf(va.w);
            *(uint4*)((char*)As + lds_off(row, scolb)) = va;
            uint4 vb = *(const uint4*)(Wo + (size_t)row * 1024 + k0 + scole);
            *(uint4*)((char*)Bs + lds_off(row, scolb)) = vb;
        }
        __syncthreads();
#pragma unroll
        for (int kt = 0; kt < 4; ++kt) {
            const int cb = kt * 32 + (l >> 5) * 16;
            short8 af[2], bfr[2];
#pragma unroll
            for (int i = 0; i < 2; ++i) {
                af[i]  = *(const short8*)((char*)As + lds_off(wr + i * 32 + (l & 31), cb));
                bfr[i] = *(const short8*)((char*)Bs + lds_off(wc + i * 32 + (l & 31), cb));
            }
#pragma unroll
            for (int i = 0; i < 2; ++i)
#pragma unroll
                for (int j = 0; j < 2; ++j)
                    acc[i][j] = __builtin_amdgcn_mfma_f32_32x32x16_bf16(af[i], bfr[j], acc[i][j], 0, 0, 0);
        }
        __syncthreads();
    }

    // epilogue: remap rows (t,b)->(b,t), fp32 store
#pragma unroll
    for (int i = 0; i < 2; ++i)
#pragma unroll
        for (int j = 0; j < 2; ++j) {
            int n = wc + j * 32 + (l & 31);
            float bv = bias[n];
#pragma unroll
            for (int r = 0; r < 16; ++r) {
                int m = bm + wr + i * 32 + (r & 3) + 8 * (r >> 2) + 4 * (l >> 5);
                int tt = m >> 7, bb_ = m & 127;
                out[((size_t)bb_ * TT + tt) * NC + n] = acc[i][j][r] + bv;
            }
        }
}

// ---------------------------------------------------------------------------
// Fused attention (bf16 Q/K/V/ctx, fp32 math)
// ---------------------------------------------------------------------------
template <int S>
__global__ __launch_bounds__(256) void attn_kernel(
    const bf* __restrict__ Q, const bf* __restrict__ Km,
    const bf* __restrict__ Vm, bf* __restrict__ ctx)
{
    constexpr int RT = 16;
    int t0 = blockIdx.x * RT;
    int b = blockIdx.y;
    int tid = threadIdx.x;

    __shared__ __align__(16) float qs[RT][EE];
    __shared__ float ps[RT][S];
    __shared__ float red[RT][17];
    __shared__ float rowsum[RT];

#pragma unroll
    for (int i = 0; i < RT * EE / (256 * 8); ++i) {
        int x = (i * 256 + tid) * 8;
        int r = x / EE, e = x % EE;
        uint4 u = *(const uint4*)&Q[((size_t)(t0 + r) * BB + b) * EE + e];
        float f[8]; bf8exp(u, f);
#pragma unroll
        for (int q = 0; q < 8; ++q) qs[r][e + q] = f[q];
    }
    __syncthreads();

    if constexpr (S >= 256) {
        int s = tid;
        float acc[RT] = {};
        const uint4* kp = (const uint4*)&Km[((size_t)b * S + s) * EE];
        for (int e8 = 0; e8 < EE / 8; ++e8) {
            float kf[8]; bf8exp(kp[e8], kf);
#pragma unroll
            for (int r = 0; r < RT; ++r) {
                float a = 0.f;
#pragma unroll
                for (int q = 0; q < 8; ++q) a += qs[r][e8 * 8 + q] * kf[q];
                acc[r] += a;
            }
        }
#pragma unroll
        for (int r = 0; r < RT; ++r) ps[r][s] = acc[r];
    } else {
        constexpr int KS = 256 / S;
        constexpr int EC = EE / KS;
        __shared__ float pp[KS][RT][S];
        int s = tid & (S - 1);
        int kq = tid / S;
        float acc[RT] = {};
        const uint4* kp = (const uint4*)&Km[((size_t)b * S + s) * EE + kq * EC];
        for (int e8 = 0; e8 < EC / 8; ++e8) {
            float kf[8]; bf8exp(kp[e8], kf);
#pragma unroll
            for (int r = 0; r < RT; ++r) {
                float a = 0.f;
#pragma unroll
                for (int q = 0; q < 8; ++q) a += qs[r][kq * EC + e8 * 8 + q] * kf[q];
                acc[r] += a;
            }
        }
#pragma unroll
        for (int r = 0; r < RT; ++r) pp[kq][r][s] = acc[r];
        __syncthreads();
        for (int x = tid; x < RT * S; x += 256) {
            int r = x / S, ss = x % S;
            float v = 0.f;
#pragma unroll
            for (int q = 0; q < KS; ++q) v += pp[q][r][ss];
            ps[r][ss] = v;
        }
    }
    __syncthreads();

    {
        int r = tid >> 4, l = tid & 15;
        float m = -1e30f;
        for (int s = l; s < S; s += 16) m = fmaxf(m, ps[r][s]);
        red[r][l] = m;
        __syncthreads();
        for (int w = 8; w >= 1; w >>= 1) {
            if (l < w) red[r][l] = fmaxf(red[r][l], red[r][l + w]);
            __syncthreads();
        }
        float mm = red[r][0];
        float sum = 0.f;
        for (int s = l; s < S; s += 16) {
            float e = expf(ps[r][s] - mm);
            ps[r][s] = e;
            sum += e;
        }
        __syncthreads();
        red[r][l] = sum;
        __syncthreads();
        for (int w = 8; w >= 1; w >>= 1) {
            if (l < w) red[r][l] += red[r][l + w];
            __syncthreads();
        }
        if (l == 0) rowsum[r] = red[r][0];
    }
    __syncthreads();

    {
        float acc0[RT] = {}, acc1[RT] = {};
        for (int s = 0; s < S; ++s) {
            float v0 = bfu(Vm[((size_t)b * S + s) * EE + tid]);
            float v1 = bfu(Vm[((size_t)b * S + s) * EE + tid + 256]);
#pragma unroll
            for (int r = 0; r < RT; ++r) {
                float p = ps[r][s];
                acc0[r] += p * v0;
                acc1[r] += p * v1;
            }
        }
#pragma unroll
        for (int r = 0; r < RT; ++r) {
            float inv = 1.f / rowsum[r];
            size_t row = (size_t)(t0 + r) * BB + b;
            ctx[row * EE + tid] = (bf)f2bf(acc0[r] * inv);
            ctx[row * EE + tid + 256] = (bf)f2bf(acc1[r] * inv);
        }
    }
}

// ---------------------------------------------------------------------------
extern "C" void kernel_launch(void* const* d_in, const int* in_sizes, int n_in,
                              void* d_out, int out_size, void* d_ws, size_t ws_size,
                              hipStream_t stream) {
    const float* char_enc = (const float*)d_in[0];
    const float* char_hn  = (const float*)d_in[1];
    const float* char_cn  = (const float*)d_in[2];
    const float* tag_enc  = (const float*)d_in[3];
    const float* tos      = (const float*)d_in[4];
    const float* Wih = (const float*)d_in[5];
    const float* Whh = (const float*)d_in[6];
    const float* bih = (const float*)d_in[7];
    const float* bhh = (const float*)d_in[8];
    const float* caWq = (const float*)d_in[9],  *caWk = (const float*)d_in[10], *caWv = (const float*)d_in[11];
    const float* cabq = (const float*)d_in[12], *cabk = (const float*)d_in[13], *cabv = (const float*)d_in[14];
    const float* caWo = (const float*)d_in[15], *cabo = (const float*)d_in[16];
    const float* taWq = (const float*)d_in[17], *taWk = (const float*)d_in[18], *taWv = (const float*)d_in[19];
    const float* tabq = (const float*)d_in[20], *tabk = (const float*)d_in[21], *tabv = (const float*)d_in[22];
    const float* taWo = (const float*)d_in[23], *tabo = (const float*)d_in[24];
    const float* outW = (const float*)d_in[25], *outb = (const float*)d_in[26];
    float* out = (float*)d_out;

    const size_t SZ  = (size_t)TT * BB * EE;       // 16,777,216 elements
    const size_t SZT = (size_t)BB * STAG * EE;     //  2,097,152 elements
    const size_t SLAB = (size_t)BB * EE;           // one t-slab of H2
    const size_t HEXT = SZ + SLAB;                 // (TT+1) slabs
    const size_t FLAGB = (size_t)TT * NWG * 128;   // 2 MB: per-step padded flags

    const size_t NEED = FLAGB + HEXT * 2 + 4 * SZ * 2 + 2 * SZT * 2
                      + (size_t)SC * 128 * EE * 2 + (size_t)TT * BB * 8
                      + (8 * 262144 + 131072) * 2;
    if (ws_size < NEED) {
        diag_ws<<<dim3((out_size + 255) / 256), dim3(256), 0, stream>>>(
            out, (float)((double)ws_size / 1048576.0), out_size);
        return;
    }

    char* w = (char*)d_ws;
    char* flags = w;             w += FLAGB;
    bf* Hext = (bf*)w;           w += HEXT * 2;    // H2 layout
    bf* Kc = (bf*)w;             w += SZ * 2;      // after attn_c: occ
    bf* Vc = (bf*)w;             w += SZ * 2;      // after attn_c: oct
    bf* Qc = (bf*)w;             w += SZ * 2;      // first Aenc, then Q_c -> ctx_c
    bf* Qt = (bf*)w;             w += SZ * 2;      // first Atag, then Q_t -> ctx_t
    bf* Kt = (bf*)w;             w += SZT * 2;
    bf* Vt = (bf*)w;             w += SZT * 2;
    bf* Btg2 = (bf*)w;           w += (size_t)SC * 128 * EE * 2;
    int* xidx = (int*)w;         w += (size_t)TT * BB * 4;
    float* xval = (float*)w;     w += (size_t)TT * BB * 4;
    bf* Wbf = (bf*)w;            w += 8 * 262144 * 2;
    bf* WoutB = (bf*)w;          w += 131072 * 2;

    bf* Aenc = Qc;               // alias: dead before Q_c written
    bf* Atag = Qt;

    const bf* Hh = Hext + SLAB;                   // H[t] = H2 slab t+1
    const float QSCALE = 0.044194173824159216f;   // 1/sqrt(512)
    const int M = TT * BB;                        // 32768

    bf* WbcaK = Wbf + 0 * 262144; bf* WbcaV = Wbf + 1 * 262144;
    bf* WbcaQ = Wbf + 2 * 262144; bf* WbcaO = Wbf + 3 * 262144;
    bf* WbtaK = Wbf + 4 * 262144; bf* WbtaV = Wbf + 5 * 262144;
    bf* WbtaQ = Wbf + 6 * 262144; bf* WbtaO = Wbf + 7 * 262144;

    // ---- prep ----
    hipMemsetAsync(flags, 0, FLAGB, stream);
    h0_pack<<<dim3(256), dim3(256), 0, stream>>>(char_hn, Hext);
    bt_prep2<<<dim3(512), dim3(256), 0, stream>>>(Whh, Btg2);
    x_prep<<<dim3(128), dim3(256), 0, stream>>>(tos, xidx, xval);
    W8 w8; w8.p[0] = caWk; w8.p[1] = caWv; w8.p[2] = caWq; w8.p[3] = caWo;
    w8.p[4] = taWk; w8.p[5] = taWv; w8.p[6] = taWq; w8.p[7] = taWo;
    conv_w8<<<dim3(256, 8), dim3(256), 0, stream>>>(w8, Wbf);
    conv_f2b<<<dim3(128), dim3(256), 0, stream>>>(outW, WoutB, 131072);
    conv_f2b<<<dim3(16384), dim3(256), 0, stream>>>(char_enc, Aenc, (int)SZ);
    conv_f2b<<<dim3(2048), dim3(256), 0, stream>>>(tag_enc, Atag, (int)SZT);

    // ---- K/V projections (MFMA) ----
    gemm_mfma<false><<<dim3(4, 256), dim3(256), 0, stream>>>(Aenc, WbcaK, cabk, Kc, M, 1.f);
    gemm_mfma<false><<<dim3(4, 256), dim3(256), 0, stream>>>(Aenc, WbcaV, cabv, Vc, M, 1.f);
    gemm_mfma<false><<<dim3(4, 32), dim3(256), 0, stream>>>(Atag, WbtaK, tabk, Kt, BB * STAG, 1.f);
    gemm_mfma<false><<<dim3(4, 32), dim3(256), 0, stream>>>(Atag, WbtaV, tabv, Vt, BB * STAG, 1.f);

    // ---- persistent MFMA LSTM (single dispatch, 2D split) ----
    lstm_mfma<<<dim3(NWG), dim3(256), 0, stream>>>(Hext, Btg2, Wih, bih, bhh,
                                                   char_cn, xidx, xval, flags);

    // ---- Q projections (scaled), A in H2 layout ----
    gemm_mfma<true><<<dim3(4, 256), dim3(256), 0, stream>>>(Hh, WbcaQ, cabq, Qc, M, QSCALE);
    gemm_mfma<true><<<dim3(4, 256), dim3(256), 0, stream>>>(Hh, WbtaQ, tabq, Qt, M, QSCALE);

    // ---- fused attention (ctx aliases Q) ----
    attn_kernel<256><<<dim3(TT / 16, BB), dim3(256), 0, stream>>>(Qc, Kc, Vc, Qc);
    attn_kernel<32><<<dim3(TT / 16, BB), dim3(256), 0, stream>>>(Qt, Kt, Vt, Qt);

    // ---- Wo projections: occ -> Kc buffer, oct -> Vc buffer ----
    gemm_mfma<false><<<dim3(4, 256), dim3(256), 0, stream>>>(Qc, WbcaO, cabo, Kc, M, 1.f);
    gemm_mfma<false><<<dim3(4, 256), dim3(256), 0, stream>>>(Qt, WbtaO, tabo, Vc, M, 1.f);

    // ---- output projection (MFMA, fused both halves + relu + remap) ----
    gemm_out<<<dim3(256), dim3(256), 0, stream>>>(Kc, Vc, WoutB, outb, out);
}

// Round 8
// 1716.012 us; speedup vs baseline: 5.0771x; 1.0781x over previous
//
#include <hip/hip_runtime.h>
#include <cstdint>

// Problem constants
#define BB 128   // batch
#define TT 256   // decode steps / T_CHAR
#define EE 512   // embed
#define NC 128   // n_chars
#define STAG 32  // T_TAG

// LSTM persistent-kernel geometry: 2D split
#define NWG 64   // = SB * SC lstm blocks
#define SB 4     // batch splits  (32 rows each)
#define SC 16    // column splits (32 h-cols / 128 gate cols each)
#define NKV 2304 // worker blocks: 1024 charK + 1024 charV + 128 tagK + 128 tagV

using bf = unsigned short;  // bf16 storage
typedef __attribute__((ext_vector_type(8))) short short8;
typedef __attribute__((ext_vector_type(8))) unsigned short ushort8;
typedef __attribute__((ext_vector_type(16))) float f32x16;
typedef unsigned long long u64;

static __device__ __forceinline__ float bf_lo(uint32_t u) { return __uint_as_float(u << 16); }
static __device__ __forceinline__ float bf_hi(uint32_t u) { return __uint_as_float(u & 0xFFFF0000u); }
static __device__ __forceinline__ float bfu(bf x) { return __uint_as_float(((uint32_t)x) << 16); }
static __device__ __forceinline__ uint32_t f2bf(float f) {
    uint32_t u = __float_as_uint(f);
    return (u + 0x7FFFu + ((u >> 16) & 1u)) >> 16;  // RNE
}
static __device__ __forceinline__ float sigmoidf_(float x) { return 1.f / (1.f + expf(-x)); }

static __device__ __forceinline__ void bf8exp(const uint4 u, float* f) {
    f[0] = bf_lo(u.x); f[1] = bf_hi(u.x); f[2] = bf_lo(u.y); f[3] = bf_hi(u.y);
    f[4] = bf_lo(u.z); f[5] = bf_hi(u.z); f[6] = bf_lo(u.w); f[7] = bf_hi(u.w);
}

static __device__ __forceinline__ uint4 pack8bf(float4 a, float4 b) {
    uint4 o;
    o.x = (f2bf(a.y) << 16) | f2bf(a.x);
    o.y = (f2bf(a.w) << 16) | f2bf(a.z);
    o.z = (f2bf(b.y) << 16) | f2bf(b.x);
    o.w = (f2bf(b.w) << 16) | f2bf(b.z);
    return o;
}

// relu on two packed bf16 (clear if sign bit set)
static __device__ __forceinline__ uint32_t relu2bf(uint32_t x) {
    uint32_t lo = x & 0xFFFFu, hi = x >> 16;
    lo = (lo & 0x8000u) ? 0u : lo;
    hi = (hi & 0x8000u) ? 0u : hi;
    return lo | (hi << 16);
}

// ---------------------------------------------------------------------------
__global__ void diag_ws(float* __restrict__ out, float v, int n) {
    int i = blockIdx.x * 256 + threadIdx.x;
    if (i < n) out[i] = v;
}

// ---------------------------------------------------------------------------
// conversions
// ---------------------------------------------------------------------------
__global__ void conv_f2b(const float* __restrict__ s, bf* __restrict__ d, int n) {
    int i = (blockIdx.x * 256 + threadIdx.x) * 4;
    if (i >= n) return;
    float4 v = *(const float4*)(s + i);
    ushort4 o = { (bf)f2bf(v.x), (bf)f2bf(v.y), (bf)f2bf(v.z), (bf)f2bf(v.w) };
    *(ushort4*)(d + i) = o;
}

struct W8 { const float* p[8]; };
__global__ void conv_w8(W8 ws, bf* __restrict__ d) {
    int m = blockIdx.y;
    int i = (blockIdx.x * 256 + threadIdx.x) * 4;    // grid.x = 256 -> 262144 elems
    float4 v = *(const float4*)(ws.p[m] + i);
    ushort4 o = { (bf)f2bf(v.x), (bf)f2bf(v.y), (bf)f2bf(v.z), (bf)f2bf(v.w) };
    *(ushort4*)(d + (size_t)m * 262144 + i) = o;
}

// ---------------------------------------------------------------------------
// Prep kernels for the persistent LSTM
// H2 layout: Hext[t][grp][b][8] with grp = col>>3  (full-line stores/loads)
// ---------------------------------------------------------------------------
__global__ void h0_pack(const float* __restrict__ hn, bf* __restrict__ Hext) {
    int id = blockIdx.x * 256 + threadIdx.x;       // 65536
    int b = id >> 9, e = id & 511;
    float v = (e < 256) ? hn[(size_t)b * 256 + e] : hn[(size_t)(BB + b) * 256 + (e - 256)];
    Hext[((size_t)(e >> 3) * BB + b) * 8 + (e & 7)] = (bf)f2bf(v);
}

// Btg2[(cg*128 + n)][k] = bf16(Whh[(n&3)*512 + cg*32 + (n>>2)][k]), cg<16, n<128
__global__ void bt_prep2(const float* __restrict__ Whh, bf* __restrict__ Btg2) {
    int id = blockIdx.x * 256 + threadIdx.x;       // 2048*64 = 131072; 8 elems each
    int row = id >> 6, chunk = (id & 63) * 8;
    int cg = row >> 7, n = row & 127;
    int r = (n & 3) * 512 + cg * 32 + (n >> 2);
    const float* src = Whh + (size_t)r * 512 + chunk;
    ushort8 o;
#pragma unroll
    for (int i = 0; i < 8; ++i) o[i] = (bf)f2bf(src[i]);
    *(ushort8*)(Btg2 + (size_t)row * 512 + chunk) = o;
}

// one-hot extraction: xidx[t][b], xval[t][b]; step 0 is zeros
__global__ void x_prep(const float* __restrict__ tos, int* __restrict__ xidx,
                       float* __restrict__ xval) {
    int id = blockIdx.x * 256 + threadIdx.x;       // TT*BB = 32768
    int t = id >> 7, b = id & 127;
    int idx = 0; float val = 0.f;
    if (t > 0) {
        const float* row = tos + ((size_t)b * TT + t) * NC;
        for (int k = 0; k < NC; ++k) {
            float v = row[k];
            if (v != 0.f) { idx = k; val = v; }
        }
    }
    xidx[(size_t)t * BB + b] = idx;
    xval[(size_t)t * BB + b] = val;
}

// ---------------------------------------------------------------------------
// shared LDS offset swizzle for the tiled GEMMs
// ---------------------------------------------------------------------------
static __device__ __forceinline__ int lds_off(int row, int colbyte) {
    return row * 128 + (colbyte ^ ((row & 7) << 4));
}

// Worker GEMM body (used inside the fused kernel): C[bm:+128, bn:+128] =
// bf16(A_f32 @ Wb^T + bias), A fp32 converted on stage. K = 512.
static __device__ __forceinline__ void worker_gemm(
    const float* __restrict__ Af, const bf* __restrict__ Wb,
    const float* __restrict__ bias, bf* __restrict__ C,
    int bm, int bn, char* smem)
{
    bf* As = (bf*)smem;
    bf* Bs = (bf*)(smem + 16384);
    const int tid = threadIdx.x;
    const int w = tid >> 6, l = tid & 63;
    const int wr = (w >> 1) * 64, wc = (w & 1) * 64;

    f32x16 acc[2][2];
#pragma unroll
    for (int i = 0; i < 2; ++i)
#pragma unroll
        for (int j = 0; j < 2; ++j)
#pragma unroll
            for (int r = 0; r < 16; ++r) acc[i][j][r] = 0.f;

    const int srow = tid >> 3;          // 0..31
    const int scolb = (tid & 7) * 16;   // byte col
    const int scole = (tid & 7) * 8;    // elem col

    for (int k0 = 0; k0 < 512; k0 += 64) {
#pragma unroll
        for (int pass = 0; pass < 4; ++pass) {
            int row = pass * 32 + srow;
            const float* ap = Af + (size_t)(bm + row) * 512 + k0 + scole;
            float4 v0 = *(const float4*)ap;
            float4 v1 = *(const float4*)(ap + 4);
            *(uint4*)(smem + lds_off(row, scolb)) = pack8bf(v0, v1);
            uint4 vb = *(const uint4*)(Wb + (size_t)(bn + row) * 512 + k0 + scole);
            *(uint4*)((char*)Bs + lds_off(row, scolb)) = vb;
        }
        __syncthreads();
#pragma unroll
        for (int kt = 0; kt < 4; ++kt) {
            const int cb = kt * 32 + (l >> 5) * 16;
            short8 af[2], bfr[2];
#pragma unroll
            for (int i = 0; i < 2; ++i) {
                af[i]  = *(const short8*)((char*)As + lds_off(wr + i * 32 + (l & 31), cb));
                bfr[i] = *(const short8*)((char*)Bs + lds_off(wc + i * 32 + (l & 31), cb));
            }
#pragma unroll
            for (int i = 0; i < 2; ++i)
#pragma unroll
                for (int j = 0; j < 2; ++j)
                    acc[i][j] = __builtin_amdgcn_mfma_f32_32x32x16_bf16(af[i], bfr[j], acc[i][j], 0, 0, 0);
        }
        __syncthreads();
    }

#pragma unroll
    for (int i = 0; i < 2; ++i)
#pragma unroll
        for (int j = 0; j < 2; ++j) {
            int n = bn + wc + j * 32 + (l & 31);
            float bv = bias[n];
#pragma unroll
            for (int r = 0; r < 16; ++r) {
                int m = bm + wr + i * 32 + (r & 3) + 8 * (r >> 2) + 4 * (l >> 5);
                C[(size_t)m * 512 + n] = (bf)f2bf(acc[i][j][r] + bv);
            }
        }
}

// ---------------------------------------------------------------------------
// Fused persistent LSTM + K/V-projection workers.
// Blocks 0..63: LSTM (2D split bh x cg; barrier groups = 16 WGs sharing bh).
// Blocks 64..: workers computing the 4 step-invariant K/V GEMMs (A fp32
// converted on stage; fully independent of the LSTM chain).
// ---------------------------------------------------------------------------
struct KVArgs {
    const float *Ac, *At;                  // char_enc, tag_enc (fp32)
    const bf *WcK, *WcV, *WtK, *WtV;       // bf16 weights
    const float *bcK, *bcV, *btK, *btV;    // biases
    bf *Kc, *Vc, *Kt, *Vt;                 // outputs
};

__global__ __launch_bounds__(256, 1) void lstm_fused(
    bf* __restrict__ Hext,           // H2: [TT+1][64][BB][8]; [0] prefilled
    const bf* __restrict__ Btg2,     // [SC*128][512]
    const float* __restrict__ Wih,   // [2048][128]
    const float* __restrict__ bih, const float* __restrict__ bhh,
    const float* __restrict__ cn,    // [2][128][256]
    const int* __restrict__ xidx, const float* __restrict__ xval,
    char* __restrict__ flags,        // [TT][SB][16*128B], zeroed
    KVArgs kv)
{
    // LSTM: [0,32KB) Alds (overlaid by gates after MFMA) | [32K,64K) wiht | [64K,+512) biass
    // Worker: [0,16K) As | [16K,32K) Bs
    __shared__ __align__(16) char smem[66048];

    const int gb = blockIdx.x, tid = threadIdx.x;

    if (gb >= NWG) {
        // ---------------- worker path ----------------
        int w = gb - NWG;
        if (w < 2048) {
            int v = w >> 10, t = w & 1023;
            worker_gemm(kv.Ac, v ? kv.WcV : kv.WcK, v ? kv.bcV : kv.bcK,
                        v ? kv.Vc : kv.Kc, (t >> 2) * 128, (t & 3) * 128, smem);
        } else {
            int w2 = w - 2048;
            int v = w2 >> 7, t = w2 & 127;
            worker_gemm(kv.At, v ? kv.WtV : kv.WtK, v ? kv.btV : kv.btK,
                        v ? kv.Vt : kv.Kt, (t >> 2) * 128, (t & 3) * 128, smem);
        }
        return;
    }

    // ---------------- LSTM path ----------------
    bf*    Alds   = (bf*)smem;                    // 32 KB (frag layout)
    float* gatesf = (float*)smem;                 // overlay: [32][132] fp32
    bf*    wihtp  = (bf*)(smem + 32768);          // [128][128]
    float* biass  = (float*)(smem + 65536);       // [128]

    const int g = gb;
    const int bh = g >> 4, cg = g & 15;

    // ---- prologue: WihT slice + bias ----
    for (int x = tid; x < 128 * NC; x += 256) {   // x = n*128 + k
        int n = x >> 7, k = x & 127;
        int r = (n & 3) * 512 + cg * 32 + (n >> 2);
        wihtp[k * 128 + n] = (bf)f2bf(Wih[(size_t)r * NC + k]);
    }
    if (tid < 128) {
        int r = (tid & 3) * 512 + cg * 32 + (tid >> 2);
        biass[tid] = bih[r] + bhh[r];
    }

    // c-state: thread (b_loc = tid>>3, u = tid&7) owns h-cols cg*32+u*4 .. +3
    const int b_loc = tid >> 3, u = tid & 7;
    const int b_glob = bh * 32 + b_loc;
    float creg[4];
    {
        int j0 = cg * 32 + u * 4;
        const float* csrc = (cg < 8) ? (cn + (size_t)b_glob * 256 + j0)
                                     : (cn + (size_t)(BB + b_glob) * 256 + (j0 - 256));
#pragma unroll
        for (int i = 0; i < 4; ++i) creg[i] = csrc[i];
    }

    // ---- wave geometry: wave wv owns gate-col tile [wv*32, wv*32+32) ----
    const int wv = tid >> 6, l = tid & 63;

    // B preload into registers: 32 k-steps x short8 = 128 VGPR, kept all run
    short8 breg[32];
    {
        const bf* bsrc = Btg2 + ((size_t)(cg * 128 + wv * 32 + (l & 31)) * 512)
                       + (l >> 5) * 8;
#pragma unroll
        for (int kt = 0; kt < 32; ++kt) breg[kt] = *(const short8*)(bsrc + kt * 16);
    }
    __syncthreads();

    // staging map: thread handles chunks (sb = tid&31, grp = sg0 + 8i)
    const int sb = tid & 31, sg0 = tid >> 5;
    const int dst_lane = sb | ((sg0 & 1) << 5);
    bf* dstbase = Alds + (size_t)(sg0 >> 1) * 512 + dst_lane * 8;   // + i*2048

    u64* Hw = (u64*)Hext;
    const size_t SLABB = (size_t)BB * EE * 2;      // bytes per t-slab
    const size_t SLAB64 = (size_t)BB * EE / 4;     // u64 per t-slab
    const size_t hst_off = (size_t)(cg * 4 + (u >> 1)) * 256 + b_glob * 2 + (u & 1);
    const bf* ards = Alds + l * 8;

    for (int t = 0; t < TT; ++t) {
        // ---- stage A: 8 batched bypass dwordx4 loads -> LDS (frag layout) ----
        const char* At = (const char*)Hext + (size_t)t * SLABB
                       + (size_t)sg0 * 2048 + (size_t)(bh * 32 + sb) * 16;
        uint4 areg[8];
#pragma unroll
        for (int i = 0; i < 8; ++i) {
            asm volatile("global_load_dwordx4 %0, %1, off sc0 sc1"
                         : "=v"(areg[i]) : "v"(At + (size_t)i * 16384));
        }
        float xv = xval[(size_t)t * BB + b_glob];
        int   xi = xidx[(size_t)t * BB + b_glob];
        asm volatile("s_waitcnt vmcnt(0)" ::: "memory");
        __builtin_amdgcn_sched_barrier(0);
#pragma unroll
        for (int i = 0; i < 8; ++i)
            *(uint4*)(dstbase + (size_t)i * 2048) = areg[i];
        __syncthreads();

        // ---- gates tile: 32 rows x 32 cols per wave, K=512 ----
        f32x16 acc0, acc1;
#pragma unroll
        for (int i = 0; i < 16; ++i) { acc0[i] = 0.f; acc1[i] = 0.f; }
#pragma unroll
        for (int kt = 0; kt < 32; kt += 2) {
            short8 a0 = *(const short8*)(ards + (size_t)kt * 512);
            short8 a1 = *(const short8*)(ards + (size_t)(kt + 1) * 512);
            acc0 = __builtin_amdgcn_mfma_f32_32x32x16_bf16(a0, breg[kt], acc0, 0, 0, 0);
            acc1 = __builtin_amdgcn_mfma_f32_32x32x16_bf16(a1, breg[kt + 1], acc1, 0, 0, 0);
        }
        __syncthreads();   // Alds reads complete before gates overlay write
#pragma unroll
        for (int r = 0; r < 16; ++r) {
            int m = (r & 3) + 8 * (r >> 2) + 4 * (l >> 5);   // verified C/D map
            gatesf[m * 132 + wv * 32 + (l & 31)] = acc0[r] + acc1[r];
        }
        __syncthreads();

        // ---- nonlinearity: thread owns (b_loc, 4 h-cols) ----
        {
            union { ushort4 v; u64 uu; } hout;
#pragma unroll
            for (int i = 0; i < 4; ++i) {
                int nb = (u * 4 + i) * 4;          // gate-col base (q=0..3)
                float4 ga  = *(const float4*)&gatesf[b_loc * 132 + nb];
                float4 bb4 = *(const float4*)&biass[nb];
                ushort4 xw = *(const ushort4*)&wihtp[xi * 128 + nb];
                float a0 = ga.x + bb4.x + xv * bfu(xw.x);   // i
                float a1 = ga.y + bb4.y + xv * bfu(xw.y);   // f
                float a2 = ga.z + bb4.z + xv * bfu(xw.z);   // g
                float a3 = ga.w + bb4.w + xv * bfu(xw.w);   // o
                float ig = sigmoidf_(a0);
                float fg = sigmoidf_(a1);
                float gg = tanhf(a2);
                float og = sigmoidf_(a3);
                creg[i] = fg * creg[i] + ig * gg;
                float hnew = og * tanhf(creg[i]);
                hout.v[i] = (bf)f2bf(hnew);
            }
            __hip_atomic_store(Hw + (size_t)(t + 1) * SLAB64 + hst_off, hout.uu,
                               __ATOMIC_RELAXED, __HIP_MEMORY_SCOPE_AGENT);
        }

        if (t + 1 < TT) {
            // ---- group barrier (16 WGs sharing bh): flag + wave-gather poll ----
            asm volatile("s_waitcnt vmcnt(0)" ::: "memory");   // h stores drained
            __syncthreads();
            char* fb = flags + (size_t)(t + 1) * (SB * 2048) + (size_t)bh * 2048;
            if (tid == 0)
                __hip_atomic_store((int*)(fb + (size_t)cg * 128), 1,
                                   __ATOMIC_RELAXED, __HIP_MEMORY_SCOPE_SYSTEM);
            if (tid < 64) {
                const int* fp = (const int*)(fb + (size_t)(tid & 15) * 128);
                while (true) {
                    int v = __hip_atomic_load(fp, __ATOMIC_RELAXED,
                                              __HIP_MEMORY_SCOPE_SYSTEM);
                    if (__all(v != 0)) break;
                    __builtin_amdgcn_s_sleep(1);
                }
            }
            asm volatile("" ::: "memory");
            __syncthreads();
        }
    }
}

// ---------------------------------------------------------------------------
// MFMA GEMM: C[M x 512] = bf16( alpha*(A @ W^T + bias) ). Tile 128x128, BK=64,
// 4 waves (2x2), XOR-swizzled LDS. AH2: A stored in H2 [t][grp][b][8] layout.
// ---------------------------------------------------------------------------
template <bool AH2>
__global__ __launch_bounds__(256) void gemm_mfma(
    const bf* __restrict__ A, const bf* __restrict__ Wb,
    const float* __restrict__ bias, bf* __restrict__ C,
    int M, float alpha)
{
    __shared__ __align__(16) bf As[128 * 64];   // 16 KB, swizzled
    __shared__ __align__(16) bf Bs[128 * 64];   // 16 KB
    const int tid = threadIdx.x;
    const int bm = blockIdx.y * 128, bn = blockIdx.x * 128;
    const int w = tid >> 6, l = tid & 63;
    const int wr = (w >> 1) * 64, wc = (w & 1) * 64;

    f32x16 acc[2][2];
#pragma unroll
    for (int i = 0; i < 2; ++i)
#pragma unroll
        for (int j = 0; j < 2; ++j)
#pragma unroll
            for (int r = 0; r < 16; ++r) acc[i][j][r] = 0.f;

    const int srow = tid >> 3;          // 0..31
    const int scolb = (tid & 7) * 16;   // byte col
    const int scole = (tid & 7) * 8;    // elem col

    for (int k0 = 0; k0 < 512; k0 += 64) {
#pragma unroll
        for (int pass = 0; pass < 4; ++pass) {
            int row = pass * 32 + srow;
            const bf* ap;
            if constexpr (AH2) {
                int m = bm + row; int tt = m >> 7, bb_ = m & 127;
                int grp = (k0 + scole) >> 3;
                ap = A + ((((size_t)tt * 64 + grp) * BB + bb_) << 3);
            } else {
                ap = A + (size_t)(bm + row) * 512 + k0 + scole;
            }
            uint4 va = *(const uint4*)ap;
            *(uint4*)((char*)As + lds_off(row, scolb)) = va;
            uint4 vb = *(const uint4*)(Wb + (size_t)(bn + row) * 512 + k0 + scole);
            *(uint4*)((char*)Bs + lds_off(row, scolb)) = vb;
        }
        __syncthreads();
#pragma unroll
        for (int kt = 0; kt < 4; ++kt) {
            const int cb = kt * 32 + (l >> 5) * 16;
            short8 af[2], bfr[2];
#pragma unroll
            for (int i = 0; i < 2; ++i) {
                af[i]  = *(const short8*)((char*)As + lds_off(wr + i * 32 + (l & 31), cb));
                bfr[i] = *(const short8*)((char*)Bs + lds_off(wc + i * 32 + (l & 31), cb));
            }
#pragma unroll
            for (int i = 0; i < 2; ++i)
#pragma unroll
                for (int j = 0; j < 2; ++j)
                    acc[i][j] = __builtin_amdgcn_mfma_f32_32x32x16_bf16(af[i], bfr[j], acc[i][j], 0, 0, 0);
        }
        __syncthreads();
    }

#pragma unroll
    for (int i = 0; i < 2; ++i)
#pragma unroll
        for (int j = 0; j < 2; ++j) {
            int n = bn + wc + j * 32 + (l & 31);
            float bv = bias ? bias[n] : 0.f;
#pragma unroll
            for (int r = 0; r < 16; ++r) {
                int m = bm + wr + i * 32 + (r & 3) + 8 * (r >> 2) + 4 * (l >> 5);
                C[(size_t)m * 512 + n] = (bf)f2bf((acc[i][j][r] + bv) * alpha);
            }
        }
}

// ---------------------------------------------------------------------------
// Output projection (MFMA): out[b][t][:] = relu(A1[m]) @ Wo[:, :512]^T
//   + relu(A2[m]) @ Wo[:, 512:]^T + bias,  m = t*BB + b. N = 128.
// ---------------------------------------------------------------------------
__global__ __launch_bounds__(256) void gemm_out(
    const bf* __restrict__ A1, const bf* __restrict__ A2,
    const bf* __restrict__ Wo,      // [128][1024] bf16
    const float* __restrict__ bias, float* __restrict__ out)
{
    __shared__ __align__(16) bf As[128 * 64];
    __shared__ __align__(16) bf Bs[128 * 64];
    const int tid = threadIdx.x;
    const int bm = blockIdx.x * 128;
    const int w = tid >> 6, l = tid & 63;
    const int wr = (w >> 1) * 64, wc = (w & 1) * 64;

    f32x16 acc[2][2];
#pragma unroll
    for (int i = 0; i < 2; ++i)
#pragma unroll
        for (int j = 0; j < 2; ++j)
#pragma unroll
            for (int r = 0; r < 16; ++r) acc[i][j][r] = 0.f;

    const int srow = tid >> 3;
    const int scolb = (tid & 7) * 16;
    const int scole = (tid & 7) * 8;

    for (int k0 = 0; k0 < 1024; k0 += 64) {
        const bf* Asrc = (k0 < 512) ? A1 : A2;
        const int kk = k0 & 511;
#pragma unroll
        for (int pass = 0; pass < 4; ++pass) {
            int row = pass * 32 + srow;
            uint4 va = *(const uint4*)(Asrc + (size_t)(bm + row) * 512 + kk + scole);
            va.x = relu2bf(va.x); va.y = relu2bf(va.y);
            va.z = relu2bf(va.z); va.w = relu2bf(va.w);
            *(uint4*)((char*)As + lds_off(row, scolb)) = va;
            uint4 vb = *(const uint4*)(Wo + (size_t)row * 1024 + k0 + scole);
            *(uint4*)((char*)Bs + lds_off(row, scolb)) = vb;
        }
        __syncthreads();
#pragma unroll
        for (int kt = 0; kt < 4; ++kt) {
            const int cb = kt * 32 + (l >> 5) * 16;
            short8 af[2], bfr[2];
#pragma unroll
            for (int i = 0; i < 2; ++i) {
                af[i]  = *(const short8*)((char*)As + lds_off(wr + i * 32 + (l & 31), cb));
                bfr[i] = *(const short8*)((char*)Bs + lds_off(wc + i * 32 + (l & 31), cb));
            }
#pragma unroll
            for (int i = 0; i < 2; ++i)
#pragma unroll
                for (int j = 0; j < 2; ++j)
                    acc[i][j] = __builtin_amdgcn_mfma_f32_32x32x16_bf16(af[i], bfr[j], acc[i][j], 0, 0, 0);
        }
        __syncthreads();
    }

    // epilogue: remap rows (t,b)->(b,t), fp32 store
#pragma unroll
    for (int i = 0; i < 2; ++i)
#pragma unroll
        for (int j = 0; j < 2; ++j) {
            int n = wc + j * 32 + (l & 31);
            float bv = bias[n];
#pragma unroll
            for (int r = 0; r < 16; ++r) {
                int m = bm + wr + i * 32 + (r & 3) + 8 * (r >> 2) + 4 * (l >> 5);
                int tt = m >> 7, bb_ = m & 127;
                out[((size_t)bb_ * TT + tt) * NC + n] = acc[i][j][r] + bv;
            }
        }
}

// ---------------------------------------------------------------------------
// Fused attention (bf16 Q/K/V/ctx, fp32 math)
// ---------------------------------------------------------------------------
template <int S>
__global__ __launch_bounds__(256) void attn_kernel(
    const bf* __restrict__ Q, const bf* __restrict__ Km,
    const bf* __restrict__ Vm, bf* __restrict__ ctx)
{
    constexpr int RT = 16;
    int t0 = blockIdx.x * RT;
    int b = blockIdx.y;
    int tid = threadIdx.x;

    __shared__ __align__(16) float qs[RT][EE];
    __shared__ float ps[RT][S];
    __shared__ float red[RT][17];
    __shared__ float rowsum[RT];

#pragma unroll
    for (int i = 0; i < RT * EE / (256 * 8); ++i) {
        int x = (i * 256 + tid) * 8;
        int r = x / EE, e = x % EE;
        uint4 u = *(const uint4*)&Q[((size_t)(t0 + r) * BB + b) * EE + e];
        float f[8]; bf8exp(u, f);
#pragma unroll
        for (int q = 0; q < 8; ++q) qs[r][e + q] = f[q];
    }
    __syncthreads();

    if constexpr (S >= 256) {
        int s = tid;
        float acc[RT] = {};
        const uint4* kp = (const uint4*)&Km[((size_t)b * S + s) * EE];
        for (int e8 = 0; e8 < EE / 8; ++e8) {
            float kf[8]; bf8exp(kp[e8], kf);
#pragma unroll
            for (int r = 0; r < RT; ++r) {
                float a = 0.f;
#pragma unroll
                for (int q = 0; q < 8; ++q) a += qs[r][e8 * 8 + q] * kf[q];
                acc[r] += a;
            }
        }
#pragma unroll
        for (int r = 0; r < RT; ++r) ps[r][s] = acc[r];
    } else {
        constexpr int KS = 256 / S;
        constexpr int EC = EE / KS;
        __shared__ float pp[KS][RT][S];
        int s = tid & (S - 1);
        int kq = tid / S;
        float acc[RT] = {};
        const uint4* kp = (const uint4*)&Km[((size_t)b * S + s) * EE + kq * EC];
        for (int e8 = 0; e8 < EC / 8; ++e8) {
            float kf[8]; bf8exp(kp[e8], kf);
#pragma unroll
            for (int r = 0; r < RT; ++r) {
                float a = 0.f;
#pragma unroll
                for (int q = 0; q < 8; ++q) a += qs[r][kq * EC + e8 * 8 + q] * kf[q];
                acc[r] += a;
            }
        }
#pragma unroll
        for (int r = 0; r < RT; ++r) pp[kq][r][s] = acc[r];
        __syncthreads();
        for (int x = tid; x < RT * S; x += 256) {
            int r = x / S, ss = x % S;
            float v = 0.f;
#pragma unroll
            for (int q = 0; q < KS; ++q) v += pp[q][r][ss];
            ps[r][ss] = v;
        }
    }
    __syncthreads();

    {
        int r = tid >> 4, l = tid & 15;
        float m = -1e30f;
        for (int s = l; s < S; s += 16) m = fmaxf(m, ps[r][s]);
        red[r][l] = m;
        __syncthreads();
        for (int w = 8; w >= 1; w >>= 1) {
            if (l < w) red[r][l] = fmaxf(red[r][l], red[r][l + w]);
            __syncthreads();
        }
        float mm = red[r][0];
        float sum = 0.f;
        for (int s = l; s < S; s += 16) {
            float e = expf(ps[r][s] - mm);
            ps[r][s] = e;
            sum += e;
        }
        __syncthreads();
        red[r][l] = sum;
        __syncthreads();
        for (int w = 8; w >= 1; w >>= 1) {
            if (l < w) red[r][l] += red[r][l + w];
            __syncthreads();
        }
        if (l == 0) rowsum[r] = red[r][0];
    }
    __syncthreads();

    {
        float acc0[RT] = {}, acc1[RT] = {};
        for (int s = 0; s < S; ++s) {
            float v0 = bfu(Vm[((size_t)b * S + s) * EE + tid]);
            float v1 = bfu(Vm[((size_t)b * S + s) * EE + tid + 256]);
#pragma unroll
            for (int r = 0; r < RT; ++r) {
                float p = ps[r][s];
                acc0[r] += p * v0;
                acc1[r] += p * v1;
            }
        }
#pragma unroll
        for (int r = 0; r < RT; ++r) {
            float inv = 1.f / rowsum[r];
            size_t row = (size_t)(t0 + r) * BB + b;
            ctx[row * EE + tid] = (bf)f2bf(acc0[r] * inv);
            ctx[row * EE + tid + 256] = (bf)f2bf(acc1[r] * inv);
        }
    }
}

// ---------------------------------------------------------------------------
extern "C" void kernel_launch(void* const* d_in, const int* in_sizes, int n_in,
                              void* d_out, int out_size, void* d_ws, size_t ws_size,
                              hipStream_t stream) {
    const float* char_enc = (const float*)d_in[0];
    const float* char_hn  = (const float*)d_in[1];
    const float* char_cn  = (const float*)d_in[2];
    const float* tag_enc  = (const float*)d_in[3];
    const float* tos      = (const float*)d_in[4];
    const float* Wih = (const float*)d_in[5];
    const float* Whh = (const float*)d_in[6];
    const float* bih = (const float*)d_in[7];
    const float* bhh = (const float*)d_in[8];
    const float* caWq = (const float*)d_in[9],  *caWk = (const float*)d_in[10], *caWv = (const float*)d_in[11];
    const float* cabq = (const float*)d_in[12], *cabk = (const float*)d_in[13], *cabv = (const float*)d_in[14];
    const float* caWo = (const float*)d_in[15], *cabo = (const float*)d_in[16];
    const float* taWq = (const float*)d_in[17], *taWk = (const float*)d_in[18], *taWv = (const float*)d_in[19];
    const float* tabq = (const float*)d_in[20], *tabk = (const float*)d_in[21], *tabv = (const float*)d_in[22];
    const float* taWo = (const float*)d_in[23], *tabo = (const float*)d_in[24];
    const float* outW = (const float*)d_in[25], *outb = (const float*)d_in[26];
    float* out = (float*)d_out;

    const size_t SZ  = (size_t)TT * BB * EE;       // 16,777,216 elements
    const size_t SZT = (size_t)BB * STAG * EE;     //  2,097,152 elements
    const size_t SLAB = (size_t)BB * EE;           // one t-slab of H2
    const size_t HEXT = SZ + SLAB;                 // (TT+1) slabs
    const size_t FLAGB = (size_t)TT * SB * 2048;   // 2 MB: per-step group flags

    const size_t NEED = FLAGB + HEXT * 2 + 4 * SZ * 2 + 2 * SZT * 2
                      + (size_t)SC * 128 * EE * 2 + (size_t)TT * BB * 8
                      + (8 * 262144 + 131072) * 2;
    if (ws_size < NEED) {
        diag_ws<<<dim3((out_size + 255) / 256), dim3(256), 0, stream>>>(
            out, (float)((double)ws_size / 1048576.0), out_size);
        return;
    }

    char* w = (char*)d_ws;
    char* flags = w;             w += FLAGB;
    bf* Hext = (bf*)w;           w += HEXT * 2;    // H2 layout
    bf* Kc = (bf*)w;             w += SZ * 2;      // after attn_c: occ
    bf* Vc = (bf*)w;             w += SZ * 2;      // after attn_c: oct
    bf* Qc = (bf*)w;             w += SZ * 2;      // Q_c -> ctx_c (in place)
    bf* Qt = (bf*)w;             w += SZ * 2;      // Q_t -> ctx_t (in place)
    bf* Kt = (bf*)w;             w += SZT * 2;
    bf* Vt = (bf*)w;             w += SZT * 2;
    bf* Btg2 = (bf*)w;           w += (size_t)SC * 128 * EE * 2;
    int* xidx = (int*)w;         w += (size_t)TT * BB * 4;
    float* xval = (float*)w;     w += (size_t)TT * BB * 4;
    bf* Wbf = (bf*)w;            w += 8 * 262144 * 2;
    bf* WoutB = (bf*)w;          w += 131072 * 2;

    const bf* Hh = Hext + SLAB;                   // H[t] = H2 slab t+1
    const float QSCALE = 0.044194173824159216f;   // 1/sqrt(512)
    const int M = TT * BB;                        // 32768

    bf* WbcaK = Wbf + 0 * 262144; bf* WbcaV = Wbf + 1 * 262144;
    bf* WbcaQ = Wbf + 2 * 262144; bf* WbcaO = Wbf + 3 * 262144;
    bf* WbtaK = Wbf + 4 * 262144; bf* WbtaV = Wbf + 5 * 262144;
    bf* WbtaQ = Wbf + 6 * 262144; bf* WbtaO = Wbf + 7 * 262144;

    // ---- prep ----
    hipMemsetAsync(flags, 0, FLAGB, stream);
    h0_pack<<<dim3(256), dim3(256), 0, stream>>>(char_hn, Hext);
    bt_prep2<<<dim3(512), dim3(256), 0, stream>>>(Whh, Btg2);
    x_prep<<<dim3(128), dim3(256), 0, stream>>>(tos, xidx, xval);
    W8 w8; w8.p[0] = caWk; w8.p[1] = caWv; w8.p[2] = caWq; w8.p[3] = caWo;
    w8.p[4] = taWk; w8.p[5] = taWv; w8.p[6] = taWq; w8.p[7] = taWo;
    conv_w8<<<dim3(256, 8), dim3(256), 0, stream>>>(w8, Wbf);
    conv_f2b<<<dim3(128), dim3(256), 0, stream>>>(outW, WoutB, 131072);

    // ---- fused: persistent LSTM (blocks 0..63) + K/V projection workers ----
    KVArgs kv;
    kv.Ac = char_enc; kv.At = tag_enc;
    kv.WcK = WbcaK; kv.WcV = WbcaV; kv.WtK = WbtaK; kv.WtV = WbtaV;
    kv.bcK = cabk; kv.bcV = cabv; kv.btK = tabk; kv.btV = tabv;
    kv.Kc = Kc; kv.Vc = Vc; kv.Kt = Kt; kv.Vt = Vt;
    lstm_fused<<<dim3(NWG + NKV), dim3(256), 0, stream>>>(
        Hext, Btg2, Wih, bih, bhh, char_cn, xidx, xval, flags, kv);

    // ---- Q projections (scaled), A in H2 layout ----
    gemm_mfma<true><<<dim3(4, 256), dim3(256), 0, stream>>>(Hh, WbcaQ, cabq, Qc, M, QSCALE);
    gemm_mfma<true><<<dim3(4, 256), dim3(256), 0, stream>>>(Hh, WbtaQ, tabq, Qt, M, QSCALE);

    // ---- fused attention (ctx aliases Q) ----
    attn_kernel<256><<<dim3(TT / 16, BB), dim3(256), 0, stream>>>(Qc, Kc, Vc, Qc);
    attn_kernel<32><<<dim3(TT / 16, BB), dim3(256), 0, stream>>>(Qt, Kt, Vt, Qt);

    // ---- Wo projections: occ -> Kc buffer, oct -> Vc buffer ----
    gemm_mfma<false><<<dim3(4, 256), dim3(256), 0, stream>>>(Qc, WbcaO, cabo, Kc, M, 1.f);
    gemm_mfma<false><<<dim3(4, 256), dim3(256), 0, stream>>>(Qt, WbtaO, tabo, Vc, M, 1.f);

    // ---- output projection (MFMA, fused both halves + relu + remap) ----
    gemm_out<<<dim3(256), dim3(256), 0, stream>>>(Kc, Vc, WoutB, outb, out);
}

// Round 9
// 1560.727 us; speedup vs baseline: 5.5823x; 1.0995x over previous
//
#include <hip/hip_runtime.h>
#include <cstdint>

// Problem constants
#define BB 128   // batch
#define TT 256   // decode steps / T_CHAR
#define EE 512   // embed
#define NC 128   // n_chars
#define STAG 32  // T_TAG

// LSTM persistent-kernel geometry: 2D split
#define NWG 64   // = SB * SC lstm blocks
#define SB 4     // batch splits  (32 rows each)
#define SC 16    // column splits (32 h-cols / 128 gate cols each)
#define NKV 2304 // workers: 1024 charK + 1024 charV(T) + 128 tagK + 128 tagV(T)

using bf = unsigned short;  // bf16 storage
typedef __attribute__((ext_vector_type(8))) short short8;
typedef __attribute__((ext_vector_type(8))) unsigned short ushort8;
typedef __attribute__((ext_vector_type(16))) float f32x16;
typedef unsigned long long u64;

static __device__ __forceinline__ float bfu(bf x) { return __uint_as_float(((uint32_t)x) << 16); }
static __device__ __forceinline__ uint32_t f2bf(float f) {
    uint32_t u = __float_as_uint(f);
    return (u + 0x7FFFu + ((u >> 16) & 1u)) >> 16;  // RNE
}
static __device__ __forceinline__ float sigmoidf_(float x) { return 1.f / (1.f + expf(-x)); }

static __device__ __forceinline__ uint4 pack8bf(float4 a, float4 b) {
    uint4 o;
    o.x = (f2bf(a.y) << 16) | f2bf(a.x);
    o.y = (f2bf(a.w) << 16) | f2bf(a.z);
    o.z = (f2bf(b.y) << 16) | f2bf(b.x);
    o.w = (f2bf(b.w) << 16) | f2bf(b.z);
    return o;
}

// relu on two packed bf16 (clear if sign bit set)
static __device__ __forceinline__ uint32_t relu2bf(uint32_t x) {
    uint32_t lo = x & 0xFFFFu, hi = x >> 16;
    lo = (lo & 0x8000u) ? 0u : lo;
    hi = (hi & 0x8000u) ? 0u : hi;
    return lo | (hi << 16);
}

// ---------------------------------------------------------------------------
__global__ void diag_ws(float* __restrict__ out, float v, int n) {
    int i = blockIdx.x * 256 + threadIdx.x;
    if (i < n) out[i] = v;
}

// ---------------------------------------------------------------------------
// conversions
// ---------------------------------------------------------------------------
__global__ void conv_f2b(const float* __restrict__ s, bf* __restrict__ d, int n) {
    int i = (blockIdx.x * 256 + threadIdx.x) * 4;
    if (i >= n) return;
    float4 v = *(const float4*)(s + i);
    ushort4 o = { (bf)f2bf(v.x), (bf)f2bf(v.y), (bf)f2bf(v.z), (bf)f2bf(v.w) };
    *(ushort4*)(d + i) = o;
}

struct W8 { const float* p[8]; };
__global__ void conv_w8(W8 ws, bf* __restrict__ d) {
    int m = blockIdx.y;
    int i = (blockIdx.x * 256 + threadIdx.x) * 4;    // grid.x = 256 -> 262144 elems
    float4 v = *(const float4*)(ws.p[m] + i);
    ushort4 o = { (bf)f2bf(v.x), (bf)f2bf(v.y), (bf)f2bf(v.z), (bf)f2bf(v.w) };
    *(ushort4*)(d + (size_t)m * 262144 + i) = o;
}

// ---------------------------------------------------------------------------
// Prep kernels for the persistent LSTM
// H2 layout: Hext[t][grp][b][8] with grp = col>>3
// ---------------------------------------------------------------------------
__global__ void h0_pack(const float* __restrict__ hn, bf* __restrict__ Hext) {
    int id = blockIdx.x * 256 + threadIdx.x;       // 65536
    int b = id >> 9, e = id & 511;
    float v = (e < 256) ? hn[(size_t)b * 256 + e] : hn[(size_t)(BB + b) * 256 + (e - 256)];
    Hext[((size_t)(e >> 3) * BB + b) * 8 + (e & 7)] = (bf)f2bf(v);
}

// Btg2[(cg*128 + n)][k] = bf16(Whh[(n&3)*512 + cg*32 + (n>>2)][k]), cg<16, n<128
__global__ void bt_prep2(const float* __restrict__ Whh, bf* __restrict__ Btg2) {
    int id = blockIdx.x * 256 + threadIdx.x;       // 131072; 8 elems each
    int row = id >> 6, chunk = (id & 63) * 8;
    int cg = row >> 7, n = row & 127;
    int r = (n & 3) * 512 + cg * 32 + (n >> 2);
    const float* src = Whh + (size_t)r * 512 + chunk;
    ushort8 o;
#pragma unroll
    for (int i = 0; i < 8; ++i) o[i] = (bf)f2bf(src[i]);
    *(ushort8*)(Btg2 + (size_t)row * 512 + chunk) = o;
}

// one-hot extraction: xidx[t][b], xval[t][b]; step 0 is zeros
__global__ void x_prep(const float* __restrict__ tos, int* __restrict__ xidx,
                       float* __restrict__ xval) {
    int id = blockIdx.x * 256 + threadIdx.x;       // TT*BB = 32768
    int t = id >> 7, b = id & 127;
    int idx = 0; float val = 0.f;
    if (t > 0) {
        const float* row = tos + ((size_t)b * TT + t) * NC;
        for (int k = 0; k < NC; ++k) {
            float v = row[k];
            if (v != 0.f) { idx = k; val = v; }
        }
    }
    xidx[(size_t)t * BB + b] = idx;
    xval[(size_t)t * BB + b] = val;
}

// ---------------------------------------------------------------------------
// shared LDS offset swizzle for the tiled worker GEMM
// ---------------------------------------------------------------------------
static __device__ __forceinline__ int lds_off(int row, int colbyte) {
    return row * 128 + (colbyte ^ ((row & 7) << 4));
}

// Worker GEMM body: C = bf16(A_f32 @ Wb^T + bias). K = 512.
// MODE 0: C[m][512] row-major.  MODE 1: V^T char  C[(b*512+n)*256+s], m=b*256+s.
// MODE 2: V^T tag  C[(b*512+n)*32+s], m=b*32+s.
template <int MODE>
static __device__ __forceinline__ void worker_gemm(
    const float* __restrict__ Af, const bf* __restrict__ Wb,
    const float* __restrict__ bias, bf* __restrict__ C,
    int bm, int bn, char* smem)
{
    bf* As = (bf*)smem;
    bf* Bs = (bf*)(smem + 16384);
    const int tid = threadIdx.x;
    const int w = tid >> 6, l = tid & 63;
    const int wr = (w >> 1) * 64, wc = (w & 1) * 64;

    f32x16 acc[2][2];
#pragma unroll
    for (int i = 0; i < 2; ++i)
#pragma unroll
        for (int j = 0; j < 2; ++j)
#pragma unroll
            for (int r = 0; r < 16; ++r) acc[i][j][r] = 0.f;

    const int srow = tid >> 3;          // 0..31
    const int scolb = (tid & 7) * 16;   // byte col
    const int scole = (tid & 7) * 8;    // elem col

    for (int k0 = 0; k0 < 512; k0 += 64) {
#pragma unroll
        for (int pass = 0; pass < 4; ++pass) {
            int row = pass * 32 + srow;
            const float* ap = Af + (size_t)(bm + row) * 512 + k0 + scole;
            float4 v0 = *(const float4*)ap;
            float4 v1 = *(const float4*)(ap + 4);
            *(uint4*)((char*)As + lds_off(row, scolb)) = pack8bf(v0, v1);
            uint4 vb = *(const uint4*)(Wb + (size_t)(bn + row) * 512 + k0 + scole);
            *(uint4*)((char*)Bs + lds_off(row, scolb)) = vb;
        }
        __syncthreads();
#pragma unroll
        for (int kt = 0; kt < 4; ++kt) {
            const int cb = kt * 32 + (l >> 5) * 16;
            short8 af[2], bfr[2];
#pragma unroll
            for (int i = 0; i < 2; ++i) {
                af[i]  = *(const short8*)((char*)As + lds_off(wr + i * 32 + (l & 31), cb));
                bfr[i] = *(const short8*)((char*)Bs + lds_off(wc + i * 32 + (l & 31), cb));
            }
#pragma unroll
            for (int i = 0; i < 2; ++i)
#pragma unroll
                for (int j = 0; j < 2; ++j)
                    acc[i][j] = __builtin_amdgcn_mfma_f32_32x32x16_bf16(af[i], bfr[j], acc[i][j], 0, 0, 0);
        }
        __syncthreads();
    }

#pragma unroll
    for (int i = 0; i < 2; ++i)
#pragma unroll
        for (int j = 0; j < 2; ++j) {
            int n = bn + wc + j * 32 + (l & 31);
            float bv = bias[n];
#pragma unroll
            for (int r = 0; r < 16; ++r) {
                int m = bm + wr + i * 32 + (r & 3) + 8 * (r >> 2) + 4 * (l >> 5);
                bf v = (bf)f2bf(acc[i][j][r] + bv);
                if constexpr (MODE == 0) {
                    C[(size_t)m * 512 + n] = v;
                } else if constexpr (MODE == 1) {
                    int b = m >> 8, s = m & 255;
                    C[((size_t)b * 512 + n) * 256 + s] = v;
                } else {
                    int b = m >> 5, s = m & 31;
                    C[((size_t)b * 512 + n) * 32 + s] = v;
                }
            }
        }
}

// ---------------------------------------------------------------------------
// Fused persistent LSTM + K/V-projection workers (V written transposed).
// ---------------------------------------------------------------------------
struct KVArgs {
    const float *Ac, *At;                  // char_enc, tag_enc (fp32)
    const bf *WcK, *WcV, *WtK, *WtV;       // bf16 weights
    const float *bcK, *bcV, *btK, *btV;    // biases
    bf *Kc, *VcT, *Kt, *VtT;               // outputs (V transposed [b][e][s])
};

__global__ __launch_bounds__(256, 1) void lstm_fused(
    bf* __restrict__ Hext,           // H2: [TT+1][64][BB][8]; [0] prefilled
    const bf* __restrict__ Btg2,     // [SC*128][512]
    const float* __restrict__ Wih,   // [2048][128]
    const float* __restrict__ bih, const float* __restrict__ bhh,
    const float* __restrict__ cn,    // [2][128][256]
    const int* __restrict__ xidx, const float* __restrict__ xval,
    char* __restrict__ flags,        // [TT][SB][16*128B], zeroed
    KVArgs kv)
{
    __shared__ __align__(16) char smem[66048];

    const int gb = blockIdx.x, tid = threadIdx.x;

    if (gb >= NWG) {
        // ---------------- worker path ----------------
        int w = gb - NWG;
        if (w < 1024) {
            worker_gemm<0>(kv.Ac, kv.WcK, kv.bcK, kv.Kc, (w >> 2) * 128, (w & 3) * 128, smem);
        } else if (w < 2048) {
            int t = w - 1024;
            worker_gemm<1>(kv.Ac, kv.WcV, kv.bcV, kv.VcT, (t >> 2) * 128, (t & 3) * 128, smem);
        } else if (w < 2176) {
            int t = w - 2048;
            worker_gemm<0>(kv.At, kv.WtK, kv.btK, kv.Kt, (t >> 2) * 128, (t & 3) * 128, smem);
        } else {
            int t = w - 2176;
            worker_gemm<2>(kv.At, kv.WtV, kv.btV, kv.VtT, (t >> 2) * 128, (t & 3) * 128, smem);
        }
        return;
    }

    // ---------------- LSTM path ----------------
    bf*    Alds   = (bf*)smem;                    // 32 KB (frag layout)
    float* gatesf = (float*)smem;                 // overlay: [32][132] fp32
    bf*    wihtp  = (bf*)(smem + 32768);          // [128][128]
    float* biass  = (float*)(smem + 65536);       // [128]

    const int g = gb;
    const int bh = g >> 4, cg = g & 15;

    // ---- prologue: WihT slice + bias ----
    for (int x = tid; x < 128 * NC; x += 256) {   // x = n*128 + k
        int n = x >> 7, k = x & 127;
        int r = (n & 3) * 512 + cg * 32 + (n >> 2);
        wihtp[k * 128 + n] = (bf)f2bf(Wih[(size_t)r * NC + k]);
    }
    if (tid < 128) {
        int r = (tid & 3) * 512 + cg * 32 + (tid >> 2);
        biass[tid] = bih[r] + bhh[r];
    }

    const int b_loc = tid >> 3, u = tid & 7;
    const int b_glob = bh * 32 + b_loc;
    float creg[4];
    {
        int j0 = cg * 32 + u * 4;
        const float* csrc = (cg < 8) ? (cn + (size_t)b_glob * 256 + j0)
                                     : (cn + (size_t)(BB + b_glob) * 256 + (j0 - 256));
#pragma unroll
        for (int i = 0; i < 4; ++i) creg[i] = csrc[i];
    }

    const int wv = tid >> 6, l = tid & 63;

    // B preload into registers: 32 k-steps x short8 = 128 VGPR, kept all run
    short8 breg[32];
    {
        const bf* bsrc = Btg2 + ((size_t)(cg * 128 + wv * 32 + (l & 31)) * 512)
                       + (l >> 5) * 8;
#pragma unroll
        for (int kt = 0; kt < 32; ++kt) breg[kt] = *(const short8*)(bsrc + kt * 16);
    }
    __syncthreads();

    const int sb = tid & 31, sg0 = tid >> 5;
    const int dst_lane = sb | ((sg0 & 1) << 5);
    bf* dstbase = Alds + (size_t)(sg0 >> 1) * 512 + dst_lane * 8;   // + i*2048

    u64* Hw = (u64*)Hext;
    const size_t SLABB = (size_t)BB * EE * 2;      // bytes per t-slab
    const size_t SLAB64 = (size_t)BB * EE / 4;     // u64 per t-slab
    const size_t hst_off = (size_t)(cg * 4 + (u >> 1)) * 256 + b_glob * 2 + (u & 1);
    const bf* ards = Alds + l * 8;

    for (int t = 0; t < TT; ++t) {
        // ---- stage A: 8 batched bypass dwordx4 loads -> LDS (frag layout) ----
        const char* At = (const char*)Hext + (size_t)t * SLABB
                       + (size_t)sg0 * 2048 + (size_t)(bh * 32 + sb) * 16;
        uint4 areg[8];
#pragma unroll
        for (int i = 0; i < 8; ++i) {
            asm volatile("global_load_dwordx4 %0, %1, off sc0 sc1"
                         : "=v"(areg[i]) : "v"(At + (size_t)i * 16384));
        }
        float xv = xval[(size_t)t * BB + b_glob];
        int   xi = xidx[(size_t)t * BB + b_glob];
        asm volatile("s_waitcnt vmcnt(0)" ::: "memory");
        __builtin_amdgcn_sched_barrier(0);
#pragma unroll
        for (int i = 0; i < 8; ++i)
            *(uint4*)(dstbase + (size_t)i * 2048) = areg[i];
        __syncthreads();

        // ---- gates tile: 32 rows x 32 cols per wave, K=512 ----
        f32x16 acc0, acc1;
#pragma unroll
        for (int i = 0; i < 16; ++i) { acc0[i] = 0.f; acc1[i] = 0.f; }
#pragma unroll
        for (int kt = 0; kt < 32; kt += 2) {
            short8 a0 = *(const short8*)(ards + (size_t)kt * 512);
            short8 a1 = *(const short8*)(ards + (size_t)(kt + 1) * 512);
            acc0 = __builtin_amdgcn_mfma_f32_32x32x16_bf16(a0, breg[kt], acc0, 0, 0, 0);
            acc1 = __builtin_amdgcn_mfma_f32_32x32x16_bf16(a1, breg[kt + 1], acc1, 0, 0, 0);
        }
        __syncthreads();   // Alds reads complete before gates overlay write
#pragma unroll
        for (int r = 0; r < 16; ++r) {
            int m = (r & 3) + 8 * (r >> 2) + 4 * (l >> 5);   // verified C/D map
            gatesf[m * 132 + wv * 32 + (l & 31)] = acc0[r] + acc1[r];
        }
        __syncthreads();

        // ---- nonlinearity ----
        {
            union { ushort4 v; u64 uu; } hout;
#pragma unroll
            for (int i = 0; i < 4; ++i) {
                int nb = (u * 4 + i) * 4;          // gate-col base (q=0..3)
                float4 ga  = *(const float4*)&gatesf[b_loc * 132 + nb];
                float4 bb4 = *(const float4*)&biass[nb];
                ushort4 xw = *(const ushort4*)&wihtp[xi * 128 + nb];
                float a0 = ga.x + bb4.x + xv * bfu(xw.x);   // i
                float a1 = ga.y + bb4.y + xv * bfu(xw.y);   // f
                float a2 = ga.z + bb4.z + xv * bfu(xw.z);   // g
                float a3 = ga.w + bb4.w + xv * bfu(xw.w);   // o
                float ig = sigmoidf_(a0);
                float fg = sigmoidf_(a1);
                float gg = tanhf(a2);
                float og = sigmoidf_(a3);
                creg[i] = fg * creg[i] + ig * gg;
                float hnew = og * tanhf(creg[i]);
                hout.v[i] = (bf)f2bf(hnew);
            }
            __hip_atomic_store(Hw + (size_t)(t + 1) * SLAB64 + hst_off, hout.uu,
                               __ATOMIC_RELAXED, __HIP_MEMORY_SCOPE_AGENT);
        }

        if (t + 1 < TT) {
            asm volatile("s_waitcnt vmcnt(0)" ::: "memory");   // h stores drained
            __syncthreads();
            char* fb = flags + (size_t)(t + 1) * (SB * 2048) + (size_t)bh * 2048;
            if (tid == 0)
                __hip_atomic_store((int*)(fb + (size_t)cg * 128), 1,
                                   __ATOMIC_RELAXED, __HIP_MEMORY_SCOPE_SYSTEM);
            if (tid < 64) {
                const int* fp = (const int*)(fb + (size_t)(tid & 15) * 128);
                while (true) {
                    int v = __hip_atomic_load(fp, __ATOMIC_RELAXED,
                                              __HIP_MEMORY_SCOPE_SYSTEM);
                    if (__all(v != 0)) break;
                    __builtin_amdgcn_s_sleep(1);
                }
            }
            asm volatile("" ::: "memory");
            __syncthreads();
        }
    }
}

// ---------------------------------------------------------------------------
// Fused MFMA attention: per (b, 32-t tile):
//   ph1 Q = (H@Wq^T + bq)*QSCALE          (reads H2 layout directly)
//   ph2 S = Q@K^T   ph3 softmax -> P(bf16)
//   ph4 ctx = P@V   (V pre-transposed [b][e][s])
//   ph5 occ = ctx@Wo^T + bo  -> [m][512] bf16
// grid (TT/32, BB), block 256 (4 waves; wave wv owns out-cols [wv*128,+128)).
// ---------------------------------------------------------------------------
template <int S>
__global__ __launch_bounds__(256, 1) void attn_fused(
    const bf* __restrict__ Hext,    // H2 base; slab t+1 = h_t
    const bf* __restrict__ Wq, const float* __restrict__ bq,
    const bf* __restrict__ Km,      // [BB*S][512]
    const bf* __restrict__ VT,      // [BB][512][S]
    const bf* __restrict__ Wo, const float* __restrict__ bo,
    bf* __restrict__ occ)           // [TT*BB][512]
{
    constexpr int SP = S + 8;
    __shared__ __align__(16) bf    Qs[32][520];    // Q, later ctx (33.3 KB)
    __shared__ __align__(16) float scs[32][SP];    // scores fp32
    __shared__ __align__(16) bf    Ps[32][SP];     // P bf16

    const float QSCALE = 0.044194173824159216f;    // 1/sqrt(512)
    const int t0 = blockIdx.x * 32, b = blockIdx.y;
    const int tid = threadIdx.x, wv = tid >> 6, l = tid & 63;
    const int lm = l & 31, lh = l >> 5;

    // ---- phase 1: Q tile ----
    {
        f32x16 qa[4];
#pragma unroll
        for (int nt = 0; nt < 4; ++nt)
#pragma unroll
            for (int r = 0; r < 16; ++r) qa[nt][r] = 0.f;
#pragma unroll 4
        for (int kt = 0; kt < 32; ++kt) {
            short8 a = *(const short8*)(Hext
                + (((size_t)(t0 + lm + 1) * 64 + kt * 2 + lh) * 1024 + (size_t)b * 8));
#pragma unroll
            for (int nt = 0; nt < 4; ++nt) {
                int n = wv * 128 + nt * 32 + lm;
                short8 w = *(const short8*)(Wq + (size_t)n * 512 + kt * 16 + lh * 8);
                qa[nt] = __builtin_amdgcn_mfma_f32_32x32x16_bf16(a, w, qa[nt], 0, 0, 0);
            }
        }
#pragma unroll
        for (int nt = 0; nt < 4; ++nt) {
            int n = wv * 128 + nt * 32 + lm;
            float bv = bq[n];
#pragma unroll
            for (int r = 0; r < 16; ++r) {
                int m = (r & 3) + 8 * (r >> 2) + 4 * lh;
                Qs[m][n] = (bf)f2bf((qa[nt][r] + bv) * QSCALE);
            }
        }
    }
    __syncthreads();

    // ---- phase 2: scores = Q @ K^T ----
    {
        constexpr int NJ = (S == 256) ? 2 : 1;
        f32x16 sa[NJ];
#pragma unroll
        for (int j = 0; j < NJ; ++j)
#pragma unroll
            for (int r = 0; r < 16; ++r) sa[j][r] = 0.f;
#pragma unroll 4
        for (int kt = 0; kt < 32; ++kt) {
            short8 a = *(const short8*)&Qs[lm][kt * 16 + lh * 8];
#pragma unroll
            for (int j = 0; j < NJ; ++j) {
                int s = ((S == 256) ? (wv * 64 + j * 32) : 0) + lm;
                short8 k8 = *(const short8*)(Km + ((size_t)b * S + s) * 512 + kt * 16 + lh * 8);
                sa[j] = __builtin_amdgcn_mfma_f32_32x32x16_bf16(a, k8, sa[j], 0, 0, 0);
            }
        }
#pragma unroll
        for (int j = 0; j < NJ; ++j) {
            int s = ((S == 256) ? (wv * 64 + j * 32) : 0) + lm;
#pragma unroll
            for (int r = 0; r < 16; ++r) {
                int m = (r & 3) + 8 * (r >> 2) + 4 * lh;
                scs[m][s] = sa[j][r];     // S==32: all waves write same values (benign)
            }
        }
    }
    __syncthreads();

    // ---- phase 3: softmax rows (8 threads/row) ----
    {
        int r = tid >> 3, lg = tid & 7;
        float mx = -1e30f;
        for (int c = lg; c < S; c += 8) mx = fmaxf(mx, scs[r][c]);
#pragma unroll
        for (int d = 1; d < 8; d <<= 1) mx = fmaxf(mx, __shfl_xor(mx, d));
        float sum = 0.f;
        for (int c = lg; c < S; c += 8) {
            float e = expf(scs[r][c] - mx);
            scs[r][c] = e;
            sum += e;
        }
#pragma unroll
        for (int d = 1; d < 8; d <<= 1) sum += __shfl_xor(sum, d);
        float inv = 1.f / sum;
        for (int c = lg; c < S; c += 8) Ps[r][c] = (bf)f2bf(scs[r][c] * inv);
    }
    __syncthreads();

    // ---- phase 4: ctx = P @ V  (B from VT, n=e, k=s) ----
    {
        f32x16 ca[4];
#pragma unroll
        for (int nt = 0; nt < 4; ++nt)
#pragma unroll
            for (int r = 0; r < 16; ++r) ca[nt][r] = 0.f;
#pragma unroll
        for (int kt = 0; kt < S / 16; ++kt) {
            short8 a = *(const short8*)&Ps[lm][kt * 16 + lh * 8];
#pragma unroll
            for (int nt = 0; nt < 4; ++nt) {
                int n = wv * 128 + nt * 32 + lm;
                short8 v8 = *(const short8*)(VT + ((size_t)b * 512 + n) * S + kt * 16 + lh * 8);
                ca[nt] = __builtin_amdgcn_mfma_f32_32x32x16_bf16(a, v8, ca[nt], 0, 0, 0);
            }
        }
        __syncthreads();   // Qs reads (phase 2) long done; safe to overwrite
#pragma unroll
        for (int nt = 0; nt < 4; ++nt) {
            int n = wv * 128 + nt * 32 + lm;
#pragma unroll
            for (int r = 0; r < 16; ++r) {
                int m = (r & 3) + 8 * (r >> 2) + 4 * lh;
                Qs[m][n] = (bf)f2bf(ca[nt][r]);
            }
        }
    }
    __syncthreads();

    // ---- phase 5: occ = ctx @ Wo^T + bo ----
    {
        f32x16 oa[4];
#pragma unroll
        for (int nt = 0; nt < 4; ++nt)
#pragma unroll
            for (int r = 0; r < 16; ++r) oa[nt][r] = 0.f;
#pragma unroll 4
        for (int kt = 0; kt < 32; ++kt) {
            short8 a = *(const short8*)&Qs[lm][kt * 16 + lh * 8];
#pragma unroll
            for (int nt = 0; nt < 4; ++nt) {
                int n = wv * 128 + nt * 32 + lm;
                short8 w = *(const short8*)(Wo + (size_t)n * 512 + kt * 16 + lh * 8);
                oa[nt] = __builtin_amdgcn_mfma_f32_32x32x16_bf16(a, w, oa[nt], 0, 0, 0);
            }
        }
#pragma unroll
        for (int nt = 0; nt < 4; ++nt) {
            int n = wv * 128 + nt * 32 + lm;
            float bv = bo[n];
#pragma unroll
            for (int r = 0; r < 16; ++r) {
                int m = (r & 3) + 8 * (r >> 2) + 4 * lh;
                occ[((size_t)(t0 + m) * BB + b) * 512 + n] = (bf)f2bf(oa[nt][r] + bv);
            }
        }
    }
}

// ---------------------------------------------------------------------------
// Output projection (MFMA): out[b][t][:] = relu(A1[m]) @ Wo[:, :512]^T
//   + relu(A2[m]) @ Wo[:, 512:]^T + bias,  m = t*BB + b. N = 128.
// ---------------------------------------------------------------------------
__global__ __launch_bounds__(256) void gemm_out(
    const bf* __restrict__ A1, const bf* __restrict__ A2,
    const bf* __restrict__ Wo,      // [128][1024] bf16
    const float* __restrict__ bias, float* __restrict__ out)
{
    __shared__ __align__(16) bf As[128 * 64];
    __shared__ __align__(16) bf Bs[128 * 64];
    const int tid = threadIdx.x;
    const int bm = blockIdx.x * 128;
    const int w = tid >> 6, l = tid & 63;
    const int wr = (w >> 1) * 64, wc = (w & 1) * 64;

    f32x16 acc[2][2];
#pragma unroll
    for (int i = 0; i < 2; ++i)
#pragma unroll
        for (int j = 0; j < 2; ++j)
#pragma unroll
            for (int r = 0; r < 16; ++r) acc[i][j][r] = 0.f;

    const int srow = tid >> 3;
    const int scolb = (tid & 7) * 16;
    const int scole = (tid & 7) * 8;

    for (int k0 = 0; k0 < 1024; k0 += 64) {
        const bf* Asrc = (k0 < 512) ? A1 : A2;
        const int kk = k0 & 511;
#pragma unroll
        for (int pass = 0; pass < 4; ++pass) {
            int row = pass * 32 + srow;
            uint4 va = *(const uint4*)(Asrc + (size_t)(bm + row) * 512 + kk + scole);
            va.x = relu2bf(va.x); va.y = relu2bf(va.y);
            va.z = relu2bf(va.z); va.w = relu2bf(va.w);
            *(uint4*)((char*)As + lds_off(row, scolb)) = va;
            uint4 vb = *(const uint4*)(Wo + (size_t)row * 1024 + k0 + scole);
            *(uint4*)((char*)Bs + lds_off(row, scolb)) = vb;
        }
        __syncthreads();
#pragma unroll
        for (int kt = 0; kt < 4; ++kt) {
            const int cb = kt * 32 + (l >> 5) * 16;
            short8 af[2], bfr[2];
#pragma unroll
            for (int i = 0; i < 2; ++i) {
                af[i]  = *(const short8*)((char*)As + lds_off(wr + i * 32 + (l & 31), cb));
                bfr[i] = *(const short8*)((char*)Bs + lds_off(wc + i * 32 + (l & 31), cb));
            }
#pragma unroll
            for (int i = 0; i < 2; ++i)
#pragma unroll
                for (int j = 0; j < 2; ++j)
                    acc[i][j] = __builtin_amdgcn_mfma_f32_32x32x16_bf16(af[i], bfr[j], acc[i][j], 0, 0, 0);
        }
        __syncthreads();
    }

#pragma unroll
    for (int i = 0; i < 2; ++i)
#pragma unroll
        for (int j = 0; j < 2; ++j) {
            int n = wc + j * 32 + (l & 31);
            float bv = bias[n];
#pragma unroll
            for (int r = 0; r < 16; ++r) {
                int m = bm + wr + i * 32 + (r & 3) + 8 * (r >> 2) + 4 * (l >> 5);
                int tt = m >> 7, bb_ = m & 127;
                out[((size_t)bb_ * TT + tt) * NC + n] = acc[i][j][r] + bv;
            }
        }
}

// ---------------------------------------------------------------------------
extern "C" void kernel_launch(void* const* d_in, const int* in_sizes, int n_in,
                              void* d_out, int out_size, void* d_ws, size_t ws_size,
                              hipStream_t stream) {
    const float* char_enc = (const float*)d_in[0];
    const float* char_hn  = (const float*)d_in[1];
    const float* char_cn  = (const float*)d_in[2];
    const float* tag_enc  = (const float*)d_in[3];
    const float* tos      = (const float*)d_in[4];
    const float* Wih = (const float*)d_in[5];
    const float* Whh = (const float*)d_in[6];
    const float* bih = (const float*)d_in[7];
    const float* bhh = (const float*)d_in[8];
    const float* caWq = (const float*)d_in[9],  *caWk = (const float*)d_in[10], *caWv = (const float*)d_in[11];
    const float* cabq = (const float*)d_in[12], *cabk = (const float*)d_in[13], *cabv = (const float*)d_in[14];
    const float* caWo = (const float*)d_in[15], *cabo = (const float*)d_in[16];
    const float* taWq = (const float*)d_in[17], *taWk = (const float*)d_in[18], *taWv = (const float*)d_in[19];
    const float* tabq = (const float*)d_in[20], *tabk = (const float*)d_in[21], *tabv = (const float*)d_in[22];
    const float* taWo = (const float*)d_in[23], *tabo = (const float*)d_in[24];
    const float* outW = (const float*)d_in[25], *outb = (const float*)d_in[26];
    float* out = (float*)d_out;

    const size_t SZ  = (size_t)TT * BB * EE;       // 16,777,216 elements
    const size_t SZT = (size_t)BB * STAG * EE;     //  2,097,152 elements
    const size_t SLAB = (size_t)BB * EE;           // one t-slab of H2
    const size_t HEXT = SZ + SLAB;                 // (TT+1) slabs
    const size_t FLAGB = (size_t)TT * SB * 2048;   // 2 MB: per-step group flags

    const size_t NEED = FLAGB + HEXT * 2 + 4 * SZ * 2 + 2 * SZT * 2
                      + (size_t)SC * 128 * EE * 2 + (size_t)TT * BB * 8
                      + (8 * 262144 + 131072) * 2;
    if (ws_size < NEED) {
        diag_ws<<<dim3((out_size + 255) / 256), dim3(256), 0, stream>>>(
            out, (float)((double)ws_size / 1048576.0), out_size);
        return;
    }

    char* w = (char*)d_ws;
    char* flags = w;             w += FLAGB;
    bf* Hext = (bf*)w;           w += HEXT * 2;    // H2 layout
    bf* Kc = (bf*)w;             w += SZ * 2;      // K char [b*256+s][512]
    bf* VcT = (bf*)w;            w += SZ * 2;      // V char transposed [b][512][256]
    bf* Occ = (bf*)w;            w += SZ * 2;      // occ output of attn_c
    bf* Oct = (bf*)w;            w += SZ * 2;      // oct output of attn_t
    bf* Kt = (bf*)w;             w += SZT * 2;
    bf* VtT = (bf*)w;            w += SZT * 2;     // [b][512][32]
    bf* Btg2 = (bf*)w;           w += (size_t)SC * 128 * EE * 2;
    int* xidx = (int*)w;         w += (size_t)TT * BB * 4;
    float* xval = (float*)w;     w += (size_t)TT * BB * 4;
    bf* Wbf = (bf*)w;            w += 8 * 262144 * 2;
    bf* WoutB = (bf*)w;          w += 131072 * 2;

    bf* WbcaK = Wbf + 0 * 262144; bf* WbcaV = Wbf + 1 * 262144;
    bf* WbcaQ = Wbf + 2 * 262144; bf* WbcaO = Wbf + 3 * 262144;
    bf* WbtaK = Wbf + 4 * 262144; bf* WbtaV = Wbf + 5 * 262144;
    bf* WbtaQ = Wbf + 6 * 262144; bf* WbtaO = Wbf + 7 * 262144;

    // ---- prep ----
    hipMemsetAsync(flags, 0, FLAGB, stream);
    h0_pack<<<dim3(256), dim3(256), 0, stream>>>(char_hn, Hext);
    bt_prep2<<<dim3(512), dim3(256), 0, stream>>>(Whh, Btg2);
    x_prep<<<dim3(128), dim3(256), 0, stream>>>(tos, xidx, xval);
    W8 w8; w8.p[0] = caWk; w8.p[1] = caWv; w8.p[2] = caWq; w8.p[3] = caWo;
    w8.p[4] = taWk; w8.p[5] = taWv; w8.p[6] = taWq; w8.p[7] = taWo;
    conv_w8<<<dim3(256, 8), dim3(256), 0, stream>>>(w8, Wbf);
    conv_f2b<<<dim3(128), dim3(256), 0, stream>>>(outW, WoutB, 131072);

    // ---- fused: persistent LSTM + K/V projection workers (V transposed) ----
    KVArgs kv;
    kv.Ac = char_enc; kv.At = tag_enc;
    kv.WcK = WbcaK; kv.WcV = WbcaV; kv.WtK = WbtaK; kv.WtV = WbtaV;
    kv.bcK = cabk; kv.bcV = cabv; kv.btK = tabk; kv.btV = tabv;
    kv.Kc = Kc; kv.VcT = VcT; kv.Kt = Kt; kv.VtT = VtT;
    lstm_fused<<<dim3(NWG + NKV), dim3(256), 0, stream>>>(
        Hext, Btg2, Wih, bih, bhh, char_cn, xidx, xval, flags, kv);

    // ---- fused MFMA attention (Qproj + QK + softmax + PV + Wo) ----
    attn_fused<256><<<dim3(TT / 32, BB), dim3(256), 0, stream>>>(
        Hext, WbcaQ, cabq, Kc, VcT, WbcaO, cabo, Occ);
    attn_fused<32><<<dim3(TT / 32, BB), dim3(256), 0, stream>>>(
        Hext, WbtaQ, tabq, Kt, VtT, WbtaO, tabo, Oct);

    // ---- output projection (MFMA, fused both halves + relu + remap) ----
    gemm_out<<<dim3(256), dim3(256), 0, stream>>>(Occ, Oct, WoutB, outb, out);
}